// Round 2
// 927.356 us; speedup vs baseline: 1.1663x; 1.1663x over previous
//
#include <hip/hip_runtime.h>
#include <math.h>

typedef unsigned short u16;
typedef unsigned int u32;
typedef short bf16x8 __attribute__((ext_vector_type(8)));
typedef float f32x4 __attribute__((ext_vector_type(4)));

__device__ __forceinline__ float bf2f(u16 u) {
  union { unsigned int i; float f; } v;
  v.i = ((unsigned int)u) << 16;
  return v.f;
}
__device__ __forceinline__ u16 f2bf(float f) {
  union { float f; unsigned int i; } v;
  v.f = f;
  unsigned int u = v.i;
  return (u16)((u + 0x7fffu + ((u >> 16) & 1u)) >> 16);
}

// async global->LDS, 16B per lane. LDS dest = wave-uniform base + lane*16.
__device__ __forceinline__ void glds16(const u16* g, u16* l) {
  __builtin_amdgcn_global_load_lds(
      (const __attribute__((address_space(1))) void*)g,
      (__attribute__((address_space(3))) void*)l, 16, 0, 0);
}

// ---------------------------------------------------------------------------
// dtype probe: fp32(1) vs bf16(0) from bit statistics of x.
// ---------------------------------------------------------------------------
__global__ __launch_bounds__(256) void probe_dtype(const u32* __restrict__ xw,
                                                   int nwords, int* flag)
{
  const int tid = threadIdx.x;
  int cnt = 0;
  for (int i = tid; i < nwords; i += 256) {
    u32 w = xw[i];
    u32 e = (w >> 7) & 0xFFu;
    if (e >= 110u && e <= 140u) cnt++;
  }
#pragma unroll
  for (int off = 32; off >= 1; off >>= 1) cnt += __shfl_xor(cnt, off);
  __shared__ int s[4];
  if ((tid & 63) == 0) s[tid >> 6] = cnt;
  __syncthreads();
  if (tid == 0) {
    int tot = s[0] + s[1] + s[2] + s[3];
    flag[0] = (tot < nwords / 2) ? 1 : 0;
  }
}

// ---------------------------------------------------------------------------
// gemm128: 128x128 tile, BK=32, NT-only, all-bf16 inputs, glds staging.
// Double-buffered 2-phase pipeline: stage tile t+1 while computing tile t.
// Out[m,n] = scale * sum_k A[m,k] * B[n,k] + bias[n + z*sBiasZ]
// ---------------------------------------------------------------------------
__global__ __launch_bounds__(256) void gemm128(
    const u16* __restrict__ A, int lda, long sAz,
    const u16* __restrict__ B, int ldb, long sBz,
    const u16* __restrict__ bias, int sBiasZ,
    void* __restrict__ OutV, int ldo, long sOz, long oOff, int outMode,
    const int* __restrict__ flagp,
    float scale, int M, int Nn, int K)
{
  const int z = blockIdx.z;
  const u16* Ab = A + (long)z * sAz;
  const u16* Bb = B + (long)z * sBz;
  const int bm = blockIdx.y * 128;
  const int bn = blockIdx.x * 128;

  __shared__ u16 As[2][128 * 32];
  __shared__ u16 Bs[2][128 * 32];

  const int tid  = threadIdx.x;
  const int lane = tid & 63;
  const int wave = tid >> 6;
  const int wr = wave >> 1, wc = wave & 1;
  const int q = lane >> 4, l15 = lane & 15;

  f32x4 acc[4][4];
#pragma unroll
  for (int i = 0; i < 4; i++)
#pragma unroll
    for (int j = 0; j < 4; j++) acc[i][j] = (f32x4){0.f, 0.f, 0.f, 0.f};

  const int srow = tid >> 2;
  const int sc8  = (tid & 3) * 8;
  const u16* aptr = Ab + (long)(bm + srow) * lda + sc8;
  const u16* bptr = Bb + (long)(bn + srow) * ldb + sc8;

  auto stage = [&](int buf, int k0) {
    u16* asl = As[buf] + tid * 8;
    u16* bsl = Bs[buf] + tid * 8;
    glds16(aptr + k0, asl);
    glds16(aptr + (long)64 * lda + k0, asl + 256 * 8);
    glds16(bptr + k0, bsl);
    glds16(bptr + (long)64 * ldb + k0, bsl + 256 * 8);
  };
  auto compute = [&](int buf) {
    bf16x8 af[4], bfr[4];
#pragma unroll
    for (int mi = 0; mi < 4; mi++)
      af[mi] = *(const bf16x8*)(As[buf] + (wr * 64 + mi * 16 + l15) * 32 + q * 8);
#pragma unroll
    for (int nj = 0; nj < 4; nj++)
      bfr[nj] = *(const bf16x8*)(Bs[buf] + (wc * 64 + nj * 16 + l15) * 32 + q * 8);
#pragma unroll
    for (int mi = 0; mi < 4; mi++)
#pragma unroll
      for (int nj = 0; nj < 4; nj++)
        acc[mi][nj] = __builtin_amdgcn_mfma_f32_16x16x32_bf16(af[mi], bfr[nj], acc[mi][nj], 0, 0, 0);
  };

  // prologue: stage tile 0, drain, then pipeline.
  stage(0, 0);
  __syncthreads();           // emits s_waitcnt vmcnt(0) lgkmcnt(0) + s_barrier
  int cur = 0;
  for (int k0 = 32; k0 < K; k0 += 32) {
    stage(cur ^ 1, k0);      // next tile's loads fly during current compute
    compute(cur);
    __syncthreads();
    cur ^= 1;
  }
  compute(cur);

  const int flagv = (outMode == 2) ? *flagp : 0;
  const bool storeF32 = (outMode == 1) || (outMode == 2 && flagv);
  const u16* bz = bias ? bias + (long)z * sBiasZ : nullptr;
#pragma unroll
  for (int mi = 0; mi < 4; mi++) {
    const int r0 = bm + wr * 64 + mi * 16 + q * 4;
#pragma unroll
    for (int nj = 0; nj < 4; nj++) {
      const int col = bn + wc * 64 + nj * 16 + l15;
      const float bsv = bz ? bf2f(bz[col]) : 0.0f;
      if (storeF32) {
        float* Out = (float*)OutV + oOff + (long)z * sOz;
#pragma unroll
        for (int r = 0; r < 4; r++)
          Out[(long)(r0 + r) * ldo + col] = acc[mi][nj][r] * scale + bsv;
      } else {
        u16* Out = (u16*)OutV + oOff + (long)z * sOz;
#pragma unroll
        for (int r = 0; r < 4; r++)
          Out[(long)(r0 + r) * ldo + col] = f2bf(acc[mi][nj][r] * scale + bsv);
      }
    }
  }
}

// ---------------------------------------------------------------------------
// gemm_pv: PV-shaped NT GEMM. Out[m, bn+c] = sum_k P[m,k] * Vt[bn+c, k].
// BM=64, BN=96 (exact head width unit), BK=32, glds staging, bf16 out.
// Double-buffered 2-phase pipeline.
// grid = (hd/96, M/64, nheads); K = Mq. All dims: M%64, K%32, lds %8.
// ---------------------------------------------------------------------------
__global__ __launch_bounds__(256) void gemm_pv(
    const u16* __restrict__ P, int ldP, long sPz,
    const u16* __restrict__ Vt, int ldVt, long sVz,
    u16* __restrict__ Out, int ldo, long sOz, int K)
{
  const int z = blockIdx.z;
  const u16* Pz = P + (long)z * sPz;
  const u16* Vz = Vt + (long)z * sVz;
  u16* Oz = Out + (long)z * sOz;
  const int bm = blockIdx.y * 64;
  const int bn = blockIdx.x * 96;

  __shared__ u16 As[2][64 * 32];   // [64][32]
  __shared__ u16 Bs[2][96 * 32];   // [96][32] (rows = output cols)

  const int tid  = threadIdx.x;
  const int lane = tid & 63;
  const int wave = tid >> 6;
  const int wr = wave >> 1, wc = wave & 1;
  const int q = lane >> 4, l15 = lane & 15;

  f32x4 acc[2][3];
#pragma unroll
  for (int i = 0; i < 2; i++)
#pragma unroll
    for (int j = 0; j < 3; j++) acc[i][j] = (f32x4){0.f, 0.f, 0.f, 0.f};

  const int srow = lane >> 2;        // 0..15
  const int sc8  = (lane & 3) * 8;   // 0,8,16,24

  // A: 4 chunks of 16 rows; wave w stages chunk w.
  const u16* aRow = Pz + (long)(bm + wave * 16 + srow) * ldP + sc8;
  // B: 6 chunks of 16 rows; waves 0..2 stage chunks 2w, 2w+1.
  const u16* bRow0 = nullptr; const u16* bRow1 = nullptr;
  if (wave < 3) {
    bRow0 = Vz + (long)(bn + (2 * wave) * 16 + srow) * ldVt + sc8;
    bRow1 = Vz + (long)(bn + (2 * wave + 1) * 16 + srow) * ldVt + sc8;
  }

  auto stage = [&](int buf, int k0) {
    glds16(aRow + k0, As[buf] + wave * 512 + lane * 8);
    if (wave < 3) {
      glds16(bRow0 + k0, Bs[buf] + (2 * wave) * 512 + lane * 8);
      glds16(bRow1 + k0, Bs[buf] + (2 * wave + 1) * 512 + lane * 8);
    }
  };
  auto compute = [&](int buf) {
    bf16x8 af[2], bfr[3];
#pragma unroll
    for (int mi = 0; mi < 2; mi++)
      af[mi] = *(const bf16x8*)(As[buf] + (wr * 32 + mi * 16 + l15) * 32 + q * 8);
#pragma unroll
    for (int nj = 0; nj < 3; nj++)
      bfr[nj] = *(const bf16x8*)(Bs[buf] + (wc * 48 + nj * 16 + l15) * 32 + q * 8);
#pragma unroll
    for (int mi = 0; mi < 2; mi++)
#pragma unroll
      for (int nj = 0; nj < 3; nj++)
        acc[mi][nj] = __builtin_amdgcn_mfma_f32_16x16x32_bf16(af[mi], bfr[nj], acc[mi][nj], 0, 0, 0);
  };

  stage(0, 0);
  __syncthreads();
  int cur = 0;
  for (int k0 = 32; k0 < K; k0 += 32) {
    stage(cur ^ 1, k0);
    compute(cur);
    __syncthreads();
    cur ^= 1;
  }
  compute(cur);

#pragma unroll
  for (int mi = 0; mi < 2; mi++) {
    const int r0 = bm + wr * 32 + mi * 16 + q * 4;
#pragma unroll
    for (int nj = 0; nj < 3; nj++) {
      const int cl = bn + wc * 48 + nj * 16 + l15;
#pragma unroll
      for (int r = 0; r < 4; r++)
        Oz[(long)(r0 + r) * ldo + cl] = f2bf(acc[mi][nj][r]);
    }
  }
}

// ---------------------------------------------------------------------------
// Generic 64x64 MFMA bf16 GEMM (round-3 verified; fallback path only).
// ---------------------------------------------------------------------------
#define BM 64
#define BN 64
#define BK 32
#define LDSP (BK + 8)

__global__ __launch_bounds__(256) void gemm64(
    const void* __restrict__ Av, int lda, long sAz, int aExt,
    const void* __restrict__ Bv, int ldb, long sBz, int bNT, int bExt,
    const void* __restrict__ biasv,
    void* __restrict__ OutV, int ldo, long sOz, long oOff, int outMode,
    const int* __restrict__ flagp,
    float scale, int M, int Nn, int K)
{
  const int flagv = *flagp;
  const bool aF32 = aExt && flagv;
  const bool bF32 = bExt && flagv;

  const int z = blockIdx.z;
  const int bm = blockIdx.y * BM;
  const int bn = blockIdx.x * BN;

  __shared__ u16 As[BM][LDSP];
  __shared__ u16 Bs[BN][LDSP];

  const int tid  = threadIdx.x;
  const int lane = tid & 63;
  const int wave = tid >> 6;
  const int wr = wave >> 1;
  const int wc = wave & 1;
  const int q   = lane >> 4;
  const int l15 = lane & 15;

  f32x4 acc[2][2];
#pragma unroll
  for (int i = 0; i < 2; i++)
#pragma unroll
    for (int j = 0; j < 2; j++) acc[i][j] = (f32x4){0.f, 0.f, 0.f, 0.f};

  const int am  = tid >> 2;
  const int ach = (tid & 3) * 8;

  for (int k0 = 0; k0 < K; k0 += BK) {
    __syncthreads();
    if (aF32) {
      const float* src = (const float*)Av + (long)z * sAz + (long)(bm + am) * lda + (k0 + ach);
      f32x4 f0 = *(const f32x4*)src;
      f32x4 f1 = *(const f32x4*)(src + 4);
      u16 t[8] = {f2bf(f0[0]), f2bf(f0[1]), f2bf(f0[2]), f2bf(f0[3]),
                  f2bf(f1[0]), f2bf(f1[1]), f2bf(f1[2]), f2bf(f1[3])};
      *(uint4*)(&As[am][ach]) = *(const uint4*)t;
    } else {
      const u16* src = (const u16*)Av + (long)z * sAz + (long)(bm + am) * lda + (k0 + ach);
      *(uint4*)(&As[am][ach]) = *(const uint4*)src;
    }
    if (bNT) {
      if (bF32) {
        u16 t[8] = {0, 0, 0, 0, 0, 0, 0, 0};
        if (bn + am < Nn) {
          const float* src = (const float*)Bv + (long)z * sBz + (long)(bn + am) * ldb + (k0 + ach);
          f32x4 f0 = *(const f32x4*)src;
          f32x4 f1 = *(const f32x4*)(src + 4);
#pragma unroll
          for (int j = 0; j < 4; j++) { t[j] = f2bf(f0[j]); t[4 + j] = f2bf(f1[j]); }
        }
        *(uint4*)(&Bs[am][ach]) = *(const uint4*)t;
      } else {
        uint4 val = make_uint4(0u, 0u, 0u, 0u);
        if (bn + am < Nn)
          val = *(const uint4*)((const u16*)Bv + (long)z * sBz + (long)(bn + am) * ldb + (k0 + ach));
        *(uint4*)(&Bs[am][ach]) = val;
      }
    } else {
      const int kk = tid >> 3;
      const int n0 = (tid & 7) * 8;
      if (bn + n0 < Nn) {
        if (bF32) {
          const float* src = (const float*)Bv + (long)z * sBz + (long)(k0 + kk) * ldb + (bn + n0);
          f32x4 f0 = *(const f32x4*)src;
          f32x4 f1 = *(const f32x4*)(src + 4);
#pragma unroll
          for (int j = 0; j < 4; j++) {
            Bs[n0 + j][kk] = f2bf(f0[j]);
            Bs[n0 + 4 + j][kk] = f2bf(f1[j]);
          }
        } else {
          uint4 val = *(const uint4*)((const u16*)Bv + (long)z * sBz + (long)(k0 + kk) * ldb + (bn + n0));
          const u16* pv = (const u16*)&val;
#pragma unroll
          for (int j = 0; j < 8; j++) Bs[n0 + j][kk] = pv[j];
        }
      } else {
#pragma unroll
        for (int j = 0; j < 8; j++) Bs[n0 + j][kk] = 0;
      }
    }
    __syncthreads();

    bf16x8 af[2], bfr[2];
#pragma unroll
    for (int t = 0; t < 2; t++)
      af[t] = *(const bf16x8*)(&As[wr * 32 + t * 16 + l15][q * 8]);
#pragma unroll
    for (int t = 0; t < 2; t++)
      bfr[t] = *(const bf16x8*)(&Bs[wc * 32 + t * 16 + l15][q * 8]);
#pragma unroll
    for (int i = 0; i < 2; i++)
#pragma unroll
      for (int j = 0; j < 2; j++)
        acc[i][j] = __builtin_amdgcn_mfma_f32_16x16x32_bf16(af[i], bfr[j], acc[i][j], 0, 0, 0);
  }

#pragma unroll
  for (int i = 0; i < 2; i++) {
    const int r0 = bm + wr * 32 + i * 16 + q * 4;
#pragma unroll
    for (int j = 0; j < 2; j++) {
      const int col = bn + wc * 32 + j * 16 + l15;
      if (col >= Nn) continue;
      float bsv = 0.0f;
      if (biasv) bsv = flagv ? ((const float*)biasv)[col] : bf2f(((const u16*)biasv)[col]);
      const bool storeF32 = (outMode == 1) || (outMode == 2 && flagv);
      if (storeF32) {
        float* Out = (float*)OutV + oOff + (long)z * sOz;
#pragma unroll
        for (int r = 0; r < 4; r++)
          Out[(long)(r0 + r) * ldo + col] = acc[i][j][r] * scale + bsv;
      } else {
        u16* Out = (u16*)OutV + oOff + (long)z * sOz;
#pragma unroll
        for (int r = 0; r < 4; r++)
          Out[(long)(r0 + r) * ldo + col] = f2bf(acc[i][j][r] * scale + bsv);
      }
    }
  }
}

// ---------------------------------------------------------------------------
// Row softmax: fp32 scores row -> bf16 probabilities; P aliases S (in-place).
// ---------------------------------------------------------------------------
__global__ __launch_bounds__(256) void softmax_rows(
    float* S, int ldS, long sSz,
    u16* P, int ldP, long sPz, int ncols)
{
  const int row = blockIdx.x;
  const int z = blockIdx.y;
  float* s = S + (long)z * sSz + (long)row * ldS;
  u16*   p = P + (long)z * sPz + (long)row * ldP;
  const int tid = threadIdx.x;
  const int lane = tid & 63, wave = tid >> 6;

  float v[9];
  int cnt = 0;
  float mx = -1e30f;
  for (int c = tid; c < ncols; c += 256) {
    float t = s[c];
    v[cnt++] = t;
    mx = fmaxf(mx, t);
  }
#pragma unroll
  for (int off = 32; off >= 1; off >>= 1) mx = fmaxf(mx, __shfl_xor(mx, off));
  __shared__ float redm[4];
  __shared__ float reds[4];
  if (lane == 0) redm[wave] = mx;
  __syncthreads();
  mx = fmaxf(fmaxf(redm[0], redm[1]), fmaxf(redm[2], redm[3]));

  float sum = 0.f;
  for (int i = 0; i < cnt; i++) { v[i] = __expf(v[i] - mx); sum += v[i]; }
#pragma unroll
  for (int off = 32; off >= 1; off >>= 1) sum += __shfl_xor(sum, off);
  if (lane == 0) reds[wave] = sum;
  __syncthreads();
  sum = reds[0] + reds[1] + reds[2] + reds[3];
  const float inv = 1.0f / sum;

  cnt = 0;
  for (int c = tid; c < ncols; c += 256) p[c] = f2bf(v[cnt++] * inv);
}

// ---------------------------------------------------------------------------
// transpose_in: outp[j*inRows+i] = (bf16) tin[i*inCols+j]; tin dtype per flag
// ---------------------------------------------------------------------------
__global__ __launch_bounds__(256) void transpose_in(
    const void* __restrict__ tinv, u16* __restrict__ outp,
    const int* __restrict__ flagp, int inRows, int inCols)
{
  const bool f32 = *flagp != 0;
  __shared__ u16 tile[32][33];
  const int bx = blockIdx.x * 32;
  const int by = blockIdx.y * 32;
  const int tx = threadIdx.x & 31;
  const int ty = threadIdx.x >> 5;
#pragma unroll
  for (int k = 0; k < 4; k++) {
    const long idx = (long)(by + ty + k * 8) * inCols + bx + tx;
    tile[ty + k * 8][tx] = f32 ? f2bf(((const float*)tinv)[idx]) : ((const u16*)tinv)[idx];
  }
  __syncthreads();
#pragma unroll
  for (int k = 0; k < 4; k++) {
    const int j = bx + ty + k * 8;
    const int i = by + tx;
    outp[(long)j * inRows + i] = tile[tx][ty + k * 8];
  }
}

// ---------------------------------------------------------------------------
// transpose_v: bf16 strided transpose. dst[j*lddst+n] = src[n*ldsrc+j]
// rows%32==0, cols%32==0. grid(cols/32, rows/32).
// ---------------------------------------------------------------------------
__global__ __launch_bounds__(256) void transpose_v(
    const u16* __restrict__ src, int ldsrc,
    u16* __restrict__ dst, int lddst, int rows, int cols)
{
  __shared__ u16 tile[32][33];
  const int bx = blockIdx.x * 32;   // over cols (j)
  const int by = blockIdx.y * 32;   // over rows (n)
  const int tx = threadIdx.x & 31;
  const int ty = threadIdx.x >> 5;
#pragma unroll
  for (int k = 0; k < 4; k++)
    tile[ty + k * 8][tx] = src[(long)(by + ty + k * 8) * ldsrc + bx + tx];
  __syncthreads();
#pragma unroll
  for (int k = 0; k < 4; k++)
    dst[(long)(bx + ty + k * 8) * lddst + by + tx] = tile[tx][ty + k * 8];
}

// flat convert (n % 4 == 0)
__global__ __launch_bounds__(256) void cvt_flat(
    const void* __restrict__ src, u16* __restrict__ dst,
    const int* __restrict__ flagp, long n)
{
  const bool f32 = *flagp != 0;
  long i = ((long)blockIdx.x * 256 + threadIdx.x) * 4;
  if (i + 3 < n) {
    if (f32) {
      f32x4 v = *(const f32x4*)((const float*)src + i);
#pragma unroll
      for (int j = 0; j < 4; j++) dst[i + j] = f2bf(v[j]);
    } else {
      *(uint2*)(dst + i) = *(const uint2*)((const u16*)src + i);
    }
  }
}

struct P8 { const void* p[8]; };
__global__ __launch_bounds__(256) void cvt_bias(P8 s, u16* __restrict__ dst,
                                                const int* __restrict__ flagp)
{
  const bool f32 = *flagp != 0;
  const int sizes[8] = {2304, 2304, 6912, 6912, 2304, 2304, 768, 768};
  int gid = blockIdx.x * 256 + threadIdx.x;
  int seg = 0, off = gid;
  while (seg < 8 && off >= sizes[seg]) { off -= sizes[seg]; seg++; }
  if (seg >= 8) return;
  float v = f32 ? ((const float*)s.p[seg])[off] : bf2f(((const u16*)s.p[seg])[off]);
  dst[gid] = f2bf(v);
}

// final: out[j*inRows+i] += transposed bf16 tin; out dtype per flag
__global__ __launch_bounds__(256) void transpose_add_out(
    const u16* __restrict__ tin, void* outv, long oOff,
    const int* __restrict__ flagp, int inRows, int inCols)
{
  const bool f32 = *flagp != 0;
  __shared__ u16 tile[32][33];
  const int bx = blockIdx.x * 32;
  const int by = blockIdx.y * 32;
  const int tx = threadIdx.x & 31;
  const int ty = threadIdx.x >> 5;
#pragma unroll
  for (int k = 0; k < 4; k++)
    tile[ty + k * 8][tx] = tin[(long)(by + ty + k * 8) * inCols + bx + tx];
  __syncthreads();
#pragma unroll
  for (int k = 0; k < 4; k++) {
    const int j = bx + ty + k * 8;
    const int i = by + tx;
    const long idx = (long)j * inRows + i;
    const float val = bf2f(tile[tx][ty + k * 8]);
    if (f32) {
      float* o = (float*)outv + oOff;
      o[idx] = o[idx] + val;
    } else {
      u16* o = (u16*)outv + oOff;
      o[idx] = f2bf(bf2f(o[idx]) + val);
    }
  }
}

// ---------------------------------------------------------------------------
extern "C" void kernel_launch(void* const* d_in, const int* in_sizes, int n_in,
                              void* d_out, int out_size, void* d_ws, size_t ws_size,
                              hipStream_t stream)
{
  const int N = 2304, C = 768, HD = 96, HDC = 288;
  const size_t NC = (size_t)N * C;

  const void* x    = d_in[0];
  const void* y    = d_in[1];
  const void* Wqx  = d_in[2];  const void* bqx  = d_in[3];
  const void* Wqy  = d_in[4];  const void* bqy  = d_in[5];
  const void* Wqxc = d_in[6];  const void* bqxc = d_in[7];
  const void* Wqyc = d_in[8];  const void* bqyc = d_in[9];
  const void* Wpxc = d_in[10]; const void* bpxc = d_in[11];
  const void* Wpyc = d_in[12]; const void* bpyc = d_in[13];
  const void* Wax  = d_in[14]; const void* bax  = d_in[15];
  const void* Way  = d_in[16]; const void* bay  = d_in[17];

  char* base = (char*)d_ws;
  int* flag = (int*)base;
  size_t off = 256;
  auto alloc16 = [&](size_t elems) -> u16* {
    u16* p = (u16*)(base + off);
    off = (off + elems * 2 + 255) & ~(size_t)255;
    return p;
  };

  // ---- fat-path fixed layout (all alloc sizes are 256B multiples -> pairs
  // of same-size buffers allocated back-to-back are stride-contiguous, which
  // the Z=2 batched GEMM calls below rely on) ----
  u16* WqxT  = alloc16((size_t)2304 * 768);
  u16* WqyT  = alloc16((size_t)2304 * 768);
  u16* WqxcT = alloc16((size_t)6912 * 2304);
  u16* WqycT = alloc16((size_t)6912 * 2304);
  u16* WpxcT = alloc16((size_t)2304 * 2304);
  u16* WpycT = alloc16((size_t)2304 * 2304);
  u16* WaxT  = alloc16((size_t)768 * 768);
  u16* WayT  = alloc16((size_t)768 * 768);
  u16* biasB = alloc16(24576);
  u16* xb = alloc16(NC);
  u16* yb = alloc16(NC);
  u16* RT = alloc16(2 * NC);      // xt,yt -> attx,atty -> attxc,attyc
  u16* RQ1 = alloc16(3 * NC);     // qkvxs -> qkvxc
  u16* RQ2 = alloc16(3 * NC);     // qkvys -> qkvyc
  u16* RS = alloc16(2 * NC);      // xself, yself
  u16* VT = alloc16(NC);          // transposed V (reused sequentially 4x)
  size_t fixedEnd = off;
  float* Sbuf = (float*)(base + fixedEnd);
  size_t availS = ws_size > fixedEnd ? ws_size - fixedEnd : 0;

  const size_t spHead = (size_t)N * N * 4;
  const bool fat = ws_size >= fixedEnd + spHead;

  auto G64 = [&](const void* A, int lda, long sAz, int aExt,
                 const void* B, int ldb, long sBz, int bNT, int bExt,
                 const void* bias, void* Out, int ldo, long sOz, long oOff, int outMode,
                 float scale, int M, int Nn, int K, int Z) {
    dim3 grid((Nn + BN - 1) / BN, (M + BM - 1) / BM, Z);
    gemm64<<<grid, 256, 0, stream>>>(A, lda, sAz, aExt, B, ldb, sBz, bNT, bExt,
                                     bias, Out, ldo, sOz, oOff, outMode, flag,
                                     scale, M, Nn, K);
  };
  auto G128 = [&](const u16* A, int lda, long sAz,
                  const u16* B, int ldb, long sBz,
                  const u16* bias, int sBiasZ,
                  void* Out, int ldo, long sOz, long oOff, int outMode,
                  float scale, int M, int Nn, int K, int Z) {
    dim3 grid(Nn / 128, M / 128, Z);
    gemm128<<<grid, 256, 0, stream>>>(A, lda, sAz, B, ldb, sBz, bias, sBiasZ,
                                      Out, ldo, sOz, oOff, outMode, flag,
                                      scale, M, Nn, K);
  };

  probe_dtype<<<1, 256, 0, stream>>>((const u32*)x, 1024, flag);

  if (fat) {
    transpose_in<<<dim3(2304 / 32, 768 / 32),  256, 0, stream>>>(Wqx,  WqxT,  flag, 768,  2304);
    transpose_in<<<dim3(2304 / 32, 768 / 32),  256, 0, stream>>>(Wqy,  WqyT,  flag, 768,  2304);
    transpose_in<<<dim3(6912 / 32, 2304 / 32), 256, 0, stream>>>(Wqxc, WqxcT, flag, 2304, 6912);
    transpose_in<<<dim3(6912 / 32, 2304 / 32), 256, 0, stream>>>(Wqyc, WqycT, flag, 2304, 6912);
    transpose_in<<<dim3(2304 / 32, 2304 / 32), 256, 0, stream>>>(Wpxc, WpxcT, flag, 2304, 2304);
    transpose_in<<<dim3(2304 / 32, 2304 / 32), 256, 0, stream>>>(Wpyc, WpycT, flag, 2304, 2304);
    transpose_in<<<dim3(768 / 32, 768 / 32),   256, 0, stream>>>(Wax,  WaxT,  flag, 768,  768);
    transpose_in<<<dim3(768 / 32, 768 / 32),   256, 0, stream>>>(Way,  WayT,  flag, 768,  768);
    P8 bp; bp.p[0] = bqx; bp.p[1] = bqy; bp.p[2] = bqxc; bp.p[3] = bqyc;
    bp.p[4] = bpxc; bp.p[5] = bpyc; bp.p[6] = bax; bp.p[7] = bay;
    cvt_bias<<<96, 256, 0, stream>>>(bp, biasB, flag);
    const u16 *bqxB = biasB, *bqxcB = biasB + 4608,
              *bpxcB = biasB + 18432, *baxB = biasB + 23040;
    cvt_flat<<<(unsigned)(NC / 4 / 256), 256, 0, stream>>>(x, xb, flag, (long)NC);
    cvt_flat<<<(unsigned)(NC / 4 / 256), 256, 0, stream>>>(y, yb, flag, (long)NC);
    u16 *xt = RT, *yt = RT + NC;
    transpose_in<<<dim3(N / 32, C / 32), 256, 0, stream>>>(x, xt, flag, C, N);
    transpose_in<<<dim3(N / 32, C / 32), 256, 0, stream>>>(y, yt, flag, C, N);

    // attention: scores gemm128 NT -> softmax -> PV gemm_pv NT (Vt pre-transposed)
    auto attF = [&](const u16* qB, const u16* kB, const u16* vB, int ldq,
                    u16* att, int Mq, int hd, float scl) {
      // Vt[j, n] = V[n, j]; j over all 8*hd columns, ld = Mq
      transpose_v<<<dim3((8 * hd) / 32, Mq / 32), 256, 0, stream>>>(vB, ldq, VT, Mq, Mq, 8 * hd);
      const long perHead = (long)Mq * Mq * 4;
      int nb = (int)(availS / perHead);
      if (nb > 8) nb = 8;
      for (int h0 = 0; h0 < 8; h0 += nb) {
        const int zc = (8 - h0 < nb) ? 8 - h0 : nb;
        G128(qB + h0 * hd, ldq, hd, kB + h0 * hd, ldq, hd, nullptr, 0,
             Sbuf, Mq, (long)Mq * Mq, 0, 1, scl, Mq, Mq, hd, zc);
        softmax_rows<<<dim3(Mq, zc), 256, 0, stream>>>(Sbuf, Mq, (long)Mq * Mq,
            (u16*)Sbuf, 2 * Mq, (long)Mq * 2 * Mq, Mq);
        gemm_pv<<<dim3(hd / 96, Mq / 64, zc), 256, 0, stream>>>(
            (const u16*)Sbuf, 2 * Mq, (long)Mq * 2 * Mq,
            VT + (long)h0 * hd * Mq, Mq, (long)hd * Mq,
            att + (long)h0 * Mq * hd, hd, (long)Mq * hd, Mq);
      }
    };

    // ---- spatial phase ----
    // x and y batched via Z=2 (A stride NC, W stride NC, bias stride 3C, out stride 3NC)
    u16 *qkvxs = RQ1;
    G128(xt, C, (long)NC, WqxT, C, (long)NC, bqxB, 3 * C,
         qkvxs, 3 * C, 3 * (long)NC, 0, 0, 1.f, N, 3 * C, C, 2);

    u16 *qkvys = RQ2;
    u16 *attx = RT, *atty = RT + NC;
    const float sscale = 1.0f / sqrtf(96.0f);
    attF(qkvxs, qkvxs + C, qkvxs + 2 * C, 3 * C, attx, N, HD, sscale);
    attF(qkvys, qkvys + C, qkvys + 2 * C, 3 * C, atty, N, HD, sscale);

    u16 *xself = RS;
    G128(attx, C, (long)NC, WaxT, C, (long)768 * 768, baxB, C,
         xself, C, (long)NC, 0, 0, 1.f, N, C, C, 2);

    // ---- channel phase ----
    u16 *qkvxc = RQ1, *qkvyc = RQ2;
    G128(xb, N, (long)NC, WqxcT, N, (long)6912 * 2304, bqxcB, 3 * N,
         qkvxc, 3 * N, 3 * (long)NC, 0, 0, 1.f, C, 3 * N, N, 2);

    u16 *attxc = RT, *attyc = RT + NC;
    const float cscale = 1.0f / sqrtf(288.0f);
    attF(qkvxc, qkvyc + N, qkvyc + 2 * N, 3 * N, attxc, C, HDC, cscale);
    attF(qkvyc, qkvxc + N, qkvxc + 2 * N, 3 * N, attyc, C, HDC, cscale);

    G128(attxc, N, (long)NC, WpxcT, N, (long)2304 * 2304, bpxcB, N,
         d_out, N, (long)NC, 0, 2, 1.f, C, N, N, 2);

    transpose_add_out<<<dim3(C / 32, N / 32), 256, 0, stream>>>(xself, d_out, 0, flag, N, C);
    transpose_add_out<<<dim3(C / 32, N / 32), 256, 0, stream>>>(RS + NC, d_out, (long)NC, flag, N, C);
    return;
  }

  // ================= fallback: round-3 verified path =================
  {
    char* b2 = (char*)d_ws;
    u16* RA = (u16*)(b2 + 256);
    u16* RB = RA + 3 * NC;
    u16* RD = RB + 3 * NC;
    u16* RE = RD + 2 * NC;
    const size_t offSsp = 256 + (size_t)(8 * NC) * 2;
    float* Ssp = (float*)(b2 + offSsp);
    const size_t availSp = ws_size > offSsp ? ws_size - offSsp : 0;
    const size_t offSch = 256 + (size_t)(10 * NC) * 2;
    float* Sch = (float*)(b2 + offSch);
    const size_t availCh = ws_size > offSch ? ws_size - offSch : 0;

    u16 *xt = RD, *yt = RD + NC;
    u16 *qkvxs = RA, *qkvys = RB;
    u16 *attx = RD, *atty = RD + NC;
    u16 *xself = RE, *yself = RE + NC;
    u16 *qkvxc = RA, *qkvyc = RB;
    u16 *attxc = RD, *attyc = RD + NC;

    auto attention = [&](const u16* qB, const u16* kB, const u16* vB, int ldq,
                         u16* att, int Mq, int hd, float scl,
                         float* S, size_t availBytes) {
      const long perHead = (long)Mq * Mq * 4;
      int nb = (int)(availBytes / perHead);
      if (nb > 8) nb = 8;
      if (nb >= 1) {
        for (int h0 = 0; h0 < 8; h0 += nb) {
          const int zc = (8 - h0 < nb) ? 8 - h0 : nb;
          G64(qB + h0 * hd, ldq, hd, 0, kB + h0 * hd, ldq, hd, 1, 0, nullptr,
              S, Mq, (long)Mq * Mq, 0, 1, scl, Mq, Mq, hd, zc);
          softmax_rows<<<dim3(Mq, zc), 256, 0, stream>>>(S, Mq, (long)Mq * Mq,
              (u16*)S, 2 * Mq, (long)Mq * 2 * Mq, Mq);
          G64((const u16*)S, 2 * Mq, (long)Mq * 2 * Mq, 0, vB + h0 * hd, ldq, hd, 0, 0,
              nullptr, att + (long)h0 * Mq * hd, hd, (long)Mq * hd, 0, 0,
              1.f, Mq, hd, Mq, zc);
        }
      } else {
        long rows = (long)(availBytes / ((size_t)Mq * 4)) & ~63L;
        if (rows < 64) rows = 64;
        if (rows > Mq) rows = Mq;
        for (int h = 0; h < 8; h++) {
          for (int m0 = 0; m0 < Mq; m0 += (int)rows) {
            const int mr = (Mq - m0 < rows) ? (int)(Mq - m0) : (int)rows;
            G64(qB + (long)m0 * ldq + h * hd, ldq, 0, 0, kB + h * hd, ldq, 0, 1, 0,
                nullptr, S, Mq, 0, 0, 1, scl, mr, Mq, hd, 1);
            softmax_rows<<<dim3(mr, 1), 256, 0, stream>>>(S, Mq, 0, (u16*)S, 2 * Mq, 0, Mq);
            G64((const u16*)S, 2 * Mq, 0, 0, vB + h * hd, ldq, 0, 0, 0, nullptr,
                att + (long)h * Mq * hd + (long)m0 * hd, hd, 0, 0, 0, 1.f, mr, hd, Mq, 1);
          }
        }
      }
    };

    transpose_in<<<dim3(N / 32, C / 32), 256, 0, stream>>>(x, xt, flag, C, N);
    transpose_in<<<dim3(N / 32, C / 32), 256, 0, stream>>>(y, yt, flag, C, N);

    G64(xt, C, 0, 0, Wqx, 3 * C, 0, 0, 1, bqx, qkvxs, 3 * C, 0, 0, 0, 1.f, N, 3 * C, C, 1);
    G64(yt, C, 0, 0, Wqy, 3 * C, 0, 0, 1, bqy, qkvys, 3 * C, 0, 0, 0, 1.f, N, 3 * C, C, 1);

    const float sscale = 1.0f / sqrtf(96.0f);
    attention(qkvxs, qkvxs + C, qkvxs + 2 * C, 3 * C, attx, N, HD, sscale, Ssp, availSp);
    attention(qkvys, qkvys + C, qkvys + 2 * C, 3 * C, atty, N, HD, sscale, Ssp, availSp);

    G64(attx, C, 0, 0, Wax, C, 0, 0, 1, bax, xself, C, 0, 0, 0, 1.f, N, C, C, 1);
    G64(atty, C, 0, 0, Way, C, 0, 0, 1, bay, yself, C, 0, 0, 0, 1.f, N, C, C, 1);

    G64(x, N, 0, 1, Wqxc, 3 * N, 0, 0, 1, bqxc, qkvxc, 3 * N, 0, 0, 0, 1.f, C, 3 * N, N, 1);
    G64(y, N, 0, 1, Wqyc, 3 * N, 0, 0, 1, bqyc, qkvyc, 3 * N, 0, 0, 0, 1.f, C, 3 * N, N, 1);

    const float cscale = 1.0f / sqrtf(288.0f);
    attention(qkvxc, qkvyc + N, qkvyc + 2 * N, 3 * N, attxc, C, HDC, cscale, Sch, availCh);
    attention(qkvyc, qkvxc + N, qkvxc + 2 * N, 3 * N, attyc, C, HDC, cscale, Sch, availCh);

    G64(attxc, N, 0, 0, Wpxc, N, 0, 0, 1, bpxc, d_out, N, 0, 0, 2, 1.f, C, N, N, 1);
    G64(attyc, N, 0, 0, Wpyc, N, 0, 0, 1, bpyc, d_out, N, 0, (long)NC, 2, 1.f, C, N, N, 1);

    transpose_add_out<<<dim3(C / 32, N / 32), 256, 0, stream>>>(xself, d_out, 0, flag, N, C);
    transpose_add_out<<<dim3(C / 32, N / 32), 256, 0, stream>>>(yself, d_out, (long)NC, flag, N, C);
  }
}

// Round 3
// 803.896 us; speedup vs baseline: 1.3455x; 1.1536x over previous
//
#include <hip/hip_runtime.h>
#include <math.h>

typedef unsigned short u16;
typedef unsigned int u32;
typedef short bf16x8 __attribute__((ext_vector_type(8)));
typedef float f32x4 __attribute__((ext_vector_type(4)));

__device__ __forceinline__ float bf2f(u16 u) {
  union { unsigned int i; float f; } v;
  v.i = ((unsigned int)u) << 16;
  return v.f;
}
__device__ __forceinline__ u16 f2bf(float f) {
  union { float f; unsigned int i; } v;
  v.f = f;
  unsigned int u = v.i;
  return (u16)((u + 0x7fffu + ((u >> 16) & 1u)) >> 16);
}

// async global->LDS, 16B per lane. LDS dest = wave-uniform base + lane*16.
__device__ __forceinline__ void glds16(const u16* g, u16* l) {
  __builtin_amdgcn_global_load_lds(
      (const __attribute__((address_space(1))) void*)g,
      (__attribute__((address_space(3))) void*)l, 16, 0, 0);
}

// ---------------------------------------------------------------------------
// dtype probe: fp32(1) vs bf16(0) from bit statistics of x.
// ---------------------------------------------------------------------------
__global__ __launch_bounds__(256) void probe_dtype(const u32* __restrict__ xw,
                                                   int nwords, int* flag)
{
  const int tid = threadIdx.x;
  int cnt = 0;
  for (int i = tid; i < nwords; i += 256) {
    u32 w = xw[i];
    u32 e = (w >> 7) & 0xFFu;
    if (e >= 110u && e <= 140u) cnt++;
  }
#pragma unroll
  for (int off = 32; off >= 1; off >>= 1) cnt += __shfl_xor(cnt, off);
  __shared__ int s[4];
  if ((tid & 63) == 0) s[tid >> 6] = cnt;
  __syncthreads();
  if (tid == 0) {
    int tot = s[0] + s[1] + s[2] + s[3];
    flag[0] = (tot < nwords / 2) ? 1 : 0;
  }
}

// ---------------------------------------------------------------------------
// gemm128: 128x128 tile, BK=32, NT-only, all-bf16 inputs, glds staging.
// Double-buffered 2-phase pipeline: stage tile t+1 while computing tile t.
// Out[m,n] = scale * sum_k A[m,k] * B[n,k] + bias[n + z*sBiasZ]
// ---------------------------------------------------------------------------
__global__ __launch_bounds__(256) void gemm128(
    const u16* __restrict__ A, int lda, long sAz,
    const u16* __restrict__ B, int ldb, long sBz,
    const u16* __restrict__ bias, int sBiasZ,
    void* __restrict__ OutV, int ldo, long sOz, long oOff, int outMode,
    const int* __restrict__ flagp,
    float scale, int M, int Nn, int K)
{
  const int z = blockIdx.z;
  const u16* Ab = A + (long)z * sAz;
  const u16* Bb = B + (long)z * sBz;
  const int bm = blockIdx.y * 128;
  const int bn = blockIdx.x * 128;

  __shared__ u16 As[2][128 * 32];
  __shared__ u16 Bs[2][128 * 32];

  const int tid  = threadIdx.x;
  const int lane = tid & 63;
  const int wave = tid >> 6;
  const int wr = wave >> 1, wc = wave & 1;
  const int q = lane >> 4, l15 = lane & 15;

  f32x4 acc[4][4];
#pragma unroll
  for (int i = 0; i < 4; i++)
#pragma unroll
    for (int j = 0; j < 4; j++) acc[i][j] = (f32x4){0.f, 0.f, 0.f, 0.f};

  const int srow = tid >> 2;
  const int sc8  = (tid & 3) * 8;
  const u16* aptr = Ab + (long)(bm + srow) * lda + sc8;
  const u16* bptr = Bb + (long)(bn + srow) * ldb + sc8;

  auto stage = [&](int buf, int k0) {
    u16* asl = As[buf] + tid * 8;
    u16* bsl = Bs[buf] + tid * 8;
    glds16(aptr + k0, asl);
    glds16(aptr + (long)64 * lda + k0, asl + 256 * 8);
    glds16(bptr + k0, bsl);
    glds16(bptr + (long)64 * ldb + k0, bsl + 256 * 8);
  };
  auto compute = [&](int buf) {
    bf16x8 af[4], bfr[4];
#pragma unroll
    for (int mi = 0; mi < 4; mi++)
      af[mi] = *(const bf16x8*)(As[buf] + (wr * 64 + mi * 16 + l15) * 32 + q * 8);
#pragma unroll
    for (int nj = 0; nj < 4; nj++)
      bfr[nj] = *(const bf16x8*)(Bs[buf] + (wc * 64 + nj * 16 + l15) * 32 + q * 8);
#pragma unroll
    for (int mi = 0; mi < 4; mi++)
#pragma unroll
      for (int nj = 0; nj < 4; nj++)
        acc[mi][nj] = __builtin_amdgcn_mfma_f32_16x16x32_bf16(af[mi], bfr[nj], acc[mi][nj], 0, 0, 0);
  };

  // prologue: stage tile 0, drain, then pipeline.
  stage(0, 0);
  __syncthreads();           // emits s_waitcnt vmcnt(0) lgkmcnt(0) + s_barrier
  int cur = 0;
  for (int k0 = 32; k0 < K; k0 += 32) {
    stage(cur ^ 1, k0);      // next tile's loads fly during current compute
    compute(cur);
    __syncthreads();
    cur ^= 1;
  }
  compute(cur);

  const int flagv = (outMode == 2) ? *flagp : 0;
  const bool storeF32 = (outMode == 1) || (outMode == 2 && flagv);
  const u16* bz = bias ? bias + (long)z * sBiasZ : nullptr;
#pragma unroll
  for (int mi = 0; mi < 4; mi++) {
    const int r0 = bm + wr * 64 + mi * 16 + q * 4;
#pragma unroll
    for (int nj = 0; nj < 4; nj++) {
      const int col = bn + wc * 64 + nj * 16 + l15;
      const float bsv = bz ? bf2f(bz[col]) : 0.0f;
      if (storeF32) {
        float* Out = (float*)OutV + oOff + (long)z * sOz;
#pragma unroll
        for (int r = 0; r < 4; r++)
          Out[(long)(r0 + r) * ldo + col] = acc[mi][nj][r] * scale + bsv;
      } else {
        u16* Out = (u16*)OutV + oOff + (long)z * sOz;
#pragma unroll
        for (int r = 0; r < 4; r++)
          Out[(long)(r0 + r) * ldo + col] = f2bf(acc[mi][nj][r] * scale + bsv);
      }
    }
  }
}

// ---------------------------------------------------------------------------
// flash96: fused spatial attention, hd=96. One block = 64 q-rows of one
// (tensor, head). Q staged once; loop over K/V tiles of 64 keys with
// reg-staged prefetch; online softmax per 16-row wave (row stats reduced
// via shfl_xor over the 16-lane column group of the MFMA C-layout:
// col=lane&15, row=(lane>>4)*4+r); P goes through a padded LDS tile to be
// re-read as MFMA A-fragments; V consumed from pre-transposed VT.
// grid = (Mq/64, 8 heads, 2 tensors). S never touches global memory.
// ---------------------------------------------------------------------------
__global__ __launch_bounds__(256) void flash96(
    const u16* __restrict__ QKV, long sTz,   // q at col h*96; k at col 768+h*96
    const u16* __restrict__ VTb, long sVz,   // Vt [768][Mq] per tensor
    u16* __restrict__ Out, long sOz,         // att + h*Mq*96 + m*96 + d
    int ldq, int Mq, float scl)
{
  const int bm = blockIdx.x * 64;
  const int h  = blockIdx.y;
  const int t  = blockIdx.z;
  const u16* qB  = QKV + (long)t * sTz;
  const u16* kB  = qB + 768;
  const u16* vtB = VTb + (long)t * sVz + (long)(h * 96) * Mq;
  u16* oB = Out + (long)t * sOz + (long)h * Mq * 96;

  // padded rows: Q/K 104 elems (208B -> 2-way banks), Vt/P 72 elems (144B)
  __shared__ u16 Qs[64 * 104];
  __shared__ u16 Ks[64 * 104];
  __shared__ u16 Vs[96 * 72];
  __shared__ u16 Ps[4 * 16 * 72];

  const int tid = threadIdx.x;
  const int lane = tid & 63, wave = tid >> 6;
  const int q8 = (lane >> 4) * 8, l15 = lane & 15;
  const int g4 = (lane >> 4) * 4;
  const int qr0 = wave * 16;

  // ---- stage Q once (64x96) ----
#pragma unroll
  for (int i = 0; i < 3; i++) {
    const int c = tid + 256 * i;
    const int row = c / 12, col0 = (c % 12) * 8;
    uint4 v = *(const uint4*)(qB + (long)(bm + row) * ldq + h * 96 + col0);
    *(uint4*)(&Qs[row * 104 + col0]) = v;
  }

  f32x4 accO[6];
#pragma unroll
  for (int dj = 0; dj < 6; dj++) accO[dj] = (f32x4){0.f, 0.f, 0.f, 0.f};
  float m_r[4] = {-1e30f, -1e30f, -1e30f, -1e30f};
  float l_r[4] = {0.f, 0.f, 0.f, 0.f};

  uint4 kreg[3], vreg[3];
  auto loadKV = [&](int k0) {
#pragma unroll
    for (int i = 0; i < 3; i++) {
      const int c = tid + 256 * i;
      const int kr = c / 12, kc = (c % 12) * 8;
      kreg[i] = *(const uint4*)(kB + (long)(k0 + kr) * ldq + h * 96 + kc);
      const int vr = c / 8, vc = (c % 8) * 8;
      vreg[i] = *(const uint4*)(vtB + (long)vr * Mq + k0 + vc);
    }
  };
  auto writeKV = [&]() {
#pragma unroll
    for (int i = 0; i < 3; i++) {
      const int c = tid + 256 * i;
      const int kr = c / 12, kc = (c % 12) * 8;
      *(uint4*)(&Ks[kr * 104 + kc]) = kreg[i];
      const int vr = c / 8, vc = (c % 8) * 8;
      *(uint4*)(&Vs[vr * 72 + vc]) = vreg[i];
    }
  };

  loadKV(0);
  const int nt = Mq / 64;
  for (int kt = 0; kt < nt; kt++) {
    __syncthreads();                 // readers of previous K/V tile done
    writeKV();
    __syncthreads();                 // tile visible to all waves
    if (kt + 1 < nt) loadKV((kt + 1) * 64);  // prefetch flies under compute

    // ---- S = Q K^T (16q x 64k per wave), K-dim 96 = 3 steps ----
    f32x4 accS[4];
#pragma unroll
    for (int nj = 0; nj < 4; nj++) accS[nj] = (f32x4){0.f, 0.f, 0.f, 0.f};
    bf16x8 aq[3];
#pragma unroll
    for (int ks = 0; ks < 3; ks++)
      aq[ks] = *(const bf16x8*)(&Qs[(qr0 + l15) * 104 + ks * 32 + q8]);
#pragma unroll
    for (int nj = 0; nj < 4; nj++)
#pragma unroll
      for (int ks = 0; ks < 3; ks++) {
        bf16x8 bk = *(const bf16x8*)(&Ks[(nj * 16 + l15) * 104 + ks * 32 + q8]);
        accS[nj] = __builtin_amdgcn_mfma_f32_16x16x32_bf16(aq[ks], bk, accS[nj], 0, 0, 0);
      }

    // ---- online softmax (rows wave-local; cols across 16-lane group) ----
    float tm[4];
#pragma unroll
    for (int r = 0; r < 4; r++)
      tm[r] = fmaxf(fmaxf(accS[0][r], accS[1][r]),
                    fmaxf(accS[2][r], accS[3][r])) * scl;
#pragma unroll
    for (int off = 1; off <= 8; off <<= 1)
#pragma unroll
      for (int r = 0; r < 4; r++)
        tm[r] = fmaxf(tm[r], __shfl_xor(tm[r], off));
    float alpha[4];
#pragma unroll
    for (int r = 0; r < 4; r++) {
      const float mn = fmaxf(m_r[r], tm[r]);
      alpha[r] = __expf(m_r[r] - mn);
      m_r[r] = mn;
    }
    float ps[4][4];
    float rs[4] = {0.f, 0.f, 0.f, 0.f};
#pragma unroll
    for (int nj = 0; nj < 4; nj++)
#pragma unroll
      for (int r = 0; r < 4; r++) {
        const float p = __expf(accS[nj][r] * scl - m_r[r]);
        ps[nj][r] = p;
        rs[r] += p;
      }
#pragma unroll
    for (int off = 1; off <= 8; off <<= 1)
#pragma unroll
      for (int r = 0; r < 4; r++)
        rs[r] += __shfl_xor(rs[r], off);
#pragma unroll
    for (int r = 0; r < 4; r++) l_r[r] = l_r[r] * alpha[r] + rs[r];
#pragma unroll
    for (int dj = 0; dj < 6; dj++)
#pragma unroll
      for (int r = 0; r < 4; r++) accO[dj][r] *= alpha[r];

    // ---- P -> LDS (bf16), wave-private tile [16][72] ----
    u16* pw = Ps + wave * (16 * 72);
#pragma unroll
    for (int nj = 0; nj < 4; nj++)
#pragma unroll
      for (int r = 0; r < 4; r++)
        pw[(g4 + r) * 72 + nj * 16 + l15] = f2bf(ps[nj][r]);
    asm volatile("s_waitcnt lgkmcnt(0)" ::: "memory");

    // ---- O += P @ V (keys dim 64 = 2 steps; 96 d = 6 frags) ----
#pragma unroll
    for (int ks = 0; ks < 2; ks++) {
      bf16x8 ap = *(const bf16x8*)(&pw[l15 * 72 + ks * 32 + q8]);
#pragma unroll
      for (int dj = 0; dj < 6; dj++) {
        bf16x8 bv = *(const bf16x8*)(&Vs[(dj * 16 + l15) * 72 + ks * 32 + q8]);
        accO[dj] = __builtin_amdgcn_mfma_f32_16x16x32_bf16(ap, bv, accO[dj], 0, 0, 0);
      }
    }
  }

  // ---- epilogue: normalize, store bf16 ----
#pragma unroll
  for (int r = 0; r < 4; r++) {
    const float inv = 1.0f / l_r[r];
    const long rowb = (long)(bm + qr0 + g4 + r) * 96;
#pragma unroll
    for (int dj = 0; dj < 6; dj++)
      oB[rowb + dj * 16 + l15] = f2bf(accO[dj][r] * inv);
  }
}

// ---------------------------------------------------------------------------
// gemm_pv: PV-shaped NT GEMM. Out[m, bn+c] = sum_k P[m,k] * Vt[bn+c, k].
// BM=64, BN=96 (exact head width unit), BK=32, glds staging, bf16 out.
// Double-buffered 2-phase pipeline.
// grid = (hd/96, M/64, nheads); K = Mq. All dims: M%64, K%32, lds %8.
// ---------------------------------------------------------------------------
__global__ __launch_bounds__(256) void gemm_pv(
    const u16* __restrict__ P, int ldP, long sPz,
    const u16* __restrict__ Vt, int ldVt, long sVz,
    u16* __restrict__ Out, int ldo, long sOz, int K)
{
  const int z = blockIdx.z;
  const u16* Pz = P + (long)z * sPz;
  const u16* Vz = Vt + (long)z * sVz;
  u16* Oz = Out + (long)z * sOz;
  const int bm = blockIdx.y * 64;
  const int bn = blockIdx.x * 96;

  __shared__ u16 As[2][64 * 32];   // [64][32]
  __shared__ u16 Bs[2][96 * 32];   // [96][32] (rows = output cols)

  const int tid  = threadIdx.x;
  const int lane = tid & 63;
  const int wave = tid >> 6;
  const int wr = wave >> 1, wc = wave & 1;
  const int q = lane >> 4, l15 = lane & 15;

  f32x4 acc[2][3];
#pragma unroll
  for (int i = 0; i < 2; i++)
#pragma unroll
    for (int j = 0; j < 3; j++) acc[i][j] = (f32x4){0.f, 0.f, 0.f, 0.f};

  const int srow = lane >> 2;        // 0..15
  const int sc8  = (lane & 3) * 8;   // 0,8,16,24

  // A: 4 chunks of 16 rows; wave w stages chunk w.
  const u16* aRow = Pz + (long)(bm + wave * 16 + srow) * ldP + sc8;
  // B: 6 chunks of 16 rows; waves 0..2 stage chunks 2w, 2w+1.
  const u16* bRow0 = nullptr; const u16* bRow1 = nullptr;
  if (wave < 3) {
    bRow0 = Vz + (long)(bn + (2 * wave) * 16 + srow) * ldVt + sc8;
    bRow1 = Vz + (long)(bn + (2 * wave + 1) * 16 + srow) * ldVt + sc8;
  }

  auto stage = [&](int buf, int k0) {
    glds16(aRow + k0, As[buf] + wave * 512 + lane * 8);
    if (wave < 3) {
      glds16(bRow0 + k0, Bs[buf] + (2 * wave) * 512 + lane * 8);
      glds16(bRow1 + k0, Bs[buf] + (2 * wave + 1) * 512 + lane * 8);
    }
  };
  auto compute = [&](int buf) {
    bf16x8 af[2], bfr[3];
#pragma unroll
    for (int mi = 0; mi < 2; mi++)
      af[mi] = *(const bf16x8*)(As[buf] + (wr * 32 + mi * 16 + l15) * 32 + q * 8);
#pragma unroll
    for (int nj = 0; nj < 3; nj++)
      bfr[nj] = *(const bf16x8*)(Bs[buf] + (wc * 48 + nj * 16 + l15) * 32 + q * 8);
#pragma unroll
    for (int mi = 0; mi < 2; mi++)
#pragma unroll
      for (int nj = 0; nj < 3; nj++)
        acc[mi][nj] = __builtin_amdgcn_mfma_f32_16x16x32_bf16(af[mi], bfr[nj], acc[mi][nj], 0, 0, 0);
  };

  stage(0, 0);
  __syncthreads();
  int cur = 0;
  for (int k0 = 32; k0 < K; k0 += 32) {
    stage(cur ^ 1, k0);
    compute(cur);
    __syncthreads();
    cur ^= 1;
  }
  compute(cur);

#pragma unroll
  for (int mi = 0; mi < 2; mi++) {
    const int r0 = bm + wr * 32 + mi * 16 + q * 4;
#pragma unroll
    for (int nj = 0; nj < 3; nj++) {
      const int cl = bn + wc * 48 + nj * 16 + l15;
#pragma unroll
      for (int r = 0; r < 4; r++)
        Oz[(long)(r0 + r) * ldo + cl] = f2bf(acc[mi][nj][r]);
    }
  }
}

// ---------------------------------------------------------------------------
// Generic 64x64 MFMA bf16 GEMM (round-3 verified; fallback path only).
// ---------------------------------------------------------------------------
#define BM 64
#define BN 64
#define BK 32
#define LDSP (BK + 8)

__global__ __launch_bounds__(256) void gemm64(
    const void* __restrict__ Av, int lda, long sAz, int aExt,
    const void* __restrict__ Bv, int ldb, long sBz, int bNT, int bExt,
    const void* __restrict__ biasv,
    void* __restrict__ OutV, int ldo, long sOz, long oOff, int outMode,
    const int* __restrict__ flagp,
    float scale, int M, int Nn, int K)
{
  const int flagv = *flagp;
  const bool aF32 = aExt && flagv;
  const bool bF32 = bExt && flagv;

  const int z = blockIdx.z;
  const int bm = blockIdx.y * BM;
  const int bn = blockIdx.x * BN;

  __shared__ u16 As[BM][LDSP];
  __shared__ u16 Bs[BN][LDSP];

  const int tid  = threadIdx.x;
  const int lane = tid & 63;
  const int wave = tid >> 6;
  const int wr = wave >> 1;
  const int wc = wave & 1;
  const int q   = lane >> 4;
  const int l15 = lane & 15;

  f32x4 acc[2][2];
#pragma unroll
  for (int i = 0; i < 2; i++)
#pragma unroll
    for (int j = 0; j < 2; j++) acc[i][j] = (f32x4){0.f, 0.f, 0.f, 0.f};

  const int am  = tid >> 2;
  const int ach = (tid & 3) * 8;

  for (int k0 = 0; k0 < K; k0 += BK) {
    __syncthreads();
    if (aF32) {
      const float* src = (const float*)Av + (long)z * sAz + (long)(bm + am) * lda + (k0 + ach);
      f32x4 f0 = *(const f32x4*)src;
      f32x4 f1 = *(const f32x4*)(src + 4);
      u16 t[8] = {f2bf(f0[0]), f2bf(f0[1]), f2bf(f0[2]), f2bf(f0[3]),
                  f2bf(f1[0]), f2bf(f1[1]), f2bf(f1[2]), f2bf(f1[3])};
      *(uint4*)(&As[am][ach]) = *(const uint4*)t;
    } else {
      const u16* src = (const u16*)Av + (long)z * sAz + (long)(bm + am) * lda + (k0 + ach);
      *(uint4*)(&As[am][ach]) = *(const uint4*)src;
    }
    if (bNT) {
      if (bF32) {
        u16 t[8] = {0, 0, 0, 0, 0, 0, 0, 0};
        if (bn + am < Nn) {
          const float* src = (const float*)Bv + (long)z * sBz + (long)(bn + am) * ldb + (k0 + ach);
          f32x4 f0 = *(const f32x4*)src;
          f32x4 f1 = *(const f32x4*)(src + 4);
#pragma unroll
          for (int j = 0; j < 4; j++) { t[j] = f2bf(f0[j]); t[4 + j] = f2bf(f1[j]); }
        }
        *(uint4*)(&Bs[am][ach]) = *(const uint4*)t;
      } else {
        uint4 val = make_uint4(0u, 0u, 0u, 0u);
        if (bn + am < Nn)
          val = *(const uint4*)((const u16*)Bv + (long)z * sBz + (long)(bn + am) * ldb + (k0 + ach));
        *(uint4*)(&Bs[am][ach]) = val;
      }
    } else {
      const int kk = tid >> 3;
      const int n0 = (tid & 7) * 8;
      if (bn + n0 < Nn) {
        if (bF32) {
          const float* src = (const float*)Bv + (long)z * sBz + (long)(k0 + kk) * ldb + (bn + n0);
          f32x4 f0 = *(const f32x4*)src;
          f32x4 f1 = *(const f32x4*)(src + 4);
#pragma unroll
          for (int j = 0; j < 4; j++) {
            Bs[n0 + j][kk] = f2bf(f0[j]);
            Bs[n0 + 4 + j][kk] = f2bf(f1[j]);
          }
        } else {
          uint4 val = *(const uint4*)((const u16*)Bv + (long)z * sBz + (long)(k0 + kk) * ldb + (bn + n0));
          const u16* pv = (const u16*)&val;
#pragma unroll
          for (int j = 0; j < 8; j++) Bs[n0 + j][kk] = pv[j];
        }
      } else {
#pragma unroll
        for (int j = 0; j < 8; j++) Bs[n0 + j][kk] = 0;
      }
    }
    __syncthreads();

    bf16x8 af[2], bfr[2];
#pragma unroll
    for (int t = 0; t < 2; t++)
      af[t] = *(const bf16x8*)(&As[wr * 32 + t * 16 + l15][q * 8]);
#pragma unroll
    for (int t = 0; t < 2; t++)
      bfr[t] = *(const bf16x8*)(&Bs[wc * 32 + t * 16 + l15][q * 8]);
#pragma unroll
    for (int i = 0; i < 2; i++)
#pragma unroll
      for (int j = 0; j < 2; j++)
        acc[i][j] = __builtin_amdgcn_mfma_f32_16x16x32_bf16(af[i], bfr[j], acc[i][j], 0, 0, 0);
  }

#pragma unroll
  for (int i = 0; i < 2; i++) {
    const int r0 = bm + wr * 32 + i * 16 + q * 4;
#pragma unroll
    for (int j = 0; j < 2; j++) {
      const int col = bn + wc * 32 + j * 16 + l15;
      if (col >= Nn) continue;
      float bsv = 0.0f;
      if (biasv) bsv = flagv ? ((const float*)biasv)[col] : bf2f(((const u16*)biasv)[col]);
      const bool storeF32 = (outMode == 1) || (outMode == 2 && flagv);
      if (storeF32) {
        float* Out = (float*)OutV + oOff + (long)z * sOz;
#pragma unroll
        for (int r = 0; r < 4; r++)
          Out[(long)(r0 + r) * ldo + col] = acc[i][j][r] * scale + bsv;
      } else {
        u16* Out = (u16*)OutV + oOff + (long)z * sOz;
#pragma unroll
        for (int r = 0; r < 4; r++)
          Out[(long)(r0 + r) * ldo + col] = f2bf(acc[i][j][r] * scale + bsv);
      }
    }
  }
}

// ---------------------------------------------------------------------------
// Row softmax: fp32 scores row -> bf16 probabilities; P aliases S (in-place).
// ---------------------------------------------------------------------------
__global__ __launch_bounds__(256) void softmax_rows(
    float* S, int ldS, long sSz,
    u16* P, int ldP, long sPz, int ncols)
{
  const int row = blockIdx.x;
  const int z = blockIdx.y;
  float* s = S + (long)z * sSz + (long)row * ldS;
  u16*   p = P + (long)z * sPz + (long)row * ldP;
  const int tid = threadIdx.x;
  const int lane = tid & 63, wave = tid >> 6;

  float v[9];
  int cnt = 0;
  float mx = -1e30f;
  for (int c = tid; c < ncols; c += 256) {
    float t = s[c];
    v[cnt++] = t;
    mx = fmaxf(mx, t);
  }
#pragma unroll
  for (int off = 32; off >= 1; off >>= 1) mx = fmaxf(mx, __shfl_xor(mx, off));
  __shared__ float redm[4];
  __shared__ float reds[4];
  if (lane == 0) redm[wave] = mx;
  __syncthreads();
  mx = fmaxf(fmaxf(redm[0], redm[1]), fmaxf(redm[2], redm[3]));

  float sum = 0.f;
  for (int i = 0; i < cnt; i++) { v[i] = __expf(v[i] - mx); sum += v[i]; }
#pragma unroll
  for (int off = 32; off >= 1; off >>= 1) sum += __shfl_xor(sum, off);
  if (lane == 0) reds[wave] = sum;
  __syncthreads();
  sum = reds[0] + reds[1] + reds[2] + reds[3];
  const float inv = 1.0f / sum;

  cnt = 0;
  for (int c = tid; c < ncols; c += 256) p[c] = f2bf(v[cnt++] * inv);
}

// ---------------------------------------------------------------------------
// transpose_in: outp[j*inRows+i] = (bf16) tin[i*inCols+j]; tin dtype per flag
// ---------------------------------------------------------------------------
__global__ __launch_bounds__(256) void transpose_in(
    const void* __restrict__ tinv, u16* __restrict__ outp,
    const int* __restrict__ flagp, int inRows, int inCols)
{
  const bool f32 = *flagp != 0;
  __shared__ u16 tile[32][33];
  const int bx = blockIdx.x * 32;
  const int by = blockIdx.y * 32;
  const int tx = threadIdx.x & 31;
  const int ty = threadIdx.x >> 5;
#pragma unroll
  for (int k = 0; k < 4; k++) {
    const long idx = (long)(by + ty + k * 8) * inCols + bx + tx;
    tile[ty + k * 8][tx] = f32 ? f2bf(((const float*)tinv)[idx]) : ((const u16*)tinv)[idx];
  }
  __syncthreads();
#pragma unroll
  for (int k = 0; k < 4; k++) {
    const int j = bx + ty + k * 8;
    const int i = by + tx;
    outp[(long)j * inRows + i] = tile[tx][ty + k * 8];
  }
}

// ---------------------------------------------------------------------------
// transpose_v: bf16 strided transpose. dst[j*lddst+n] = src[n*ldsrc+j]
// rows%32==0, cols%32==0. grid(cols/32, rows/32).
// ---------------------------------------------------------------------------
__global__ __launch_bounds__(256) void transpose_v(
    const u16* __restrict__ src, int ldsrc,
    u16* __restrict__ dst, int lddst, int rows, int cols)
{
  __shared__ u16 tile[32][33];
  const int bx = blockIdx.x * 32;   // over cols (j)
  const int by = blockIdx.y * 32;   // over rows (n)
  const int tx = threadIdx.x & 31;
  const int ty = threadIdx.x >> 5;
#pragma unroll
  for (int k = 0; k < 4; k++)
    tile[ty + k * 8][tx] = src[(long)(by + ty + k * 8) * ldsrc + bx + tx];
  __syncthreads();
#pragma unroll
  for (int k = 0; k < 4; k++)
    dst[(long)(bx + ty + k * 8) * lddst + by + tx] = tile[tx][ty + k * 8];
}

// flat convert (n % 4 == 0)
__global__ __launch_bounds__(256) void cvt_flat(
    const void* __restrict__ src, u16* __restrict__ dst,
    const int* __restrict__ flagp, long n)
{
  const bool f32 = *flagp != 0;
  long i = ((long)blockIdx.x * 256 + threadIdx.x) * 4;
  if (i + 3 < n) {
    if (f32) {
      f32x4 v = *(const f32x4*)((const float*)src + i);
#pragma unroll
      for (int j = 0; j < 4; j++) dst[i + j] = f2bf(v[j]);
    } else {
      *(uint2*)(dst + i) = *(const uint2*)((const u16*)src + i);
    }
  }
}

struct P8 { const void* p[8]; };
__global__ __launch_bounds__(256) void cvt_bias(P8 s, u16* __restrict__ dst,
                                                const int* __restrict__ flagp)
{
  const bool f32 = *flagp != 0;
  const int sizes[8] = {2304, 2304, 6912, 6912, 2304, 2304, 768, 768};
  int gid = blockIdx.x * 256 + threadIdx.x;
  int seg = 0, off = gid;
  while (seg < 8 && off >= sizes[seg]) { off -= sizes[seg]; seg++; }
  if (seg >= 8) return;
  float v = f32 ? ((const float*)s.p[seg])[off] : bf2f(((const u16*)s.p[seg])[off]);
  dst[gid] = f2bf(v);
}

// final: out[j*inRows+i] += transposed bf16 tin; out dtype per flag
__global__ __launch_bounds__(256) void transpose_add_out(
    const u16* __restrict__ tin, void* outv, long oOff,
    const int* __restrict__ flagp, int inRows, int inCols)
{
  const bool f32 = *flagp != 0;
  __shared__ u16 tile[32][33];
  const int bx = blockIdx.x * 32;
  const int by = blockIdx.y * 32;
  const int tx = threadIdx.x & 31;
  const int ty = threadIdx.x >> 5;
#pragma unroll
  for (int k = 0; k < 4; k++)
    tile[ty + k * 8][tx] = tin[(long)(by + ty + k * 8) * inCols + bx + tx];
  __syncthreads();
#pragma unroll
  for (int k = 0; k < 4; k++) {
    const int j = bx + ty + k * 8;
    const int i = by + tx;
    const long idx = (long)j * inRows + i;
    const float val = bf2f(tile[tx][ty + k * 8]);
    if (f32) {
      float* o = (float*)outv + oOff;
      o[idx] = o[idx] + val;
    } else {
      u16* o = (u16*)outv + oOff;
      o[idx] = f2bf(bf2f(o[idx]) + val);
    }
  }
}

// ---------------------------------------------------------------------------
extern "C" void kernel_launch(void* const* d_in, const int* in_sizes, int n_in,
                              void* d_out, int out_size, void* d_ws, size_t ws_size,
                              hipStream_t stream)
{
  const int N = 2304, C = 768, HD = 96, HDC = 288;
  const size_t NC = (size_t)N * C;

  const void* x    = d_in[0];
  const void* y    = d_in[1];
  const void* Wqx  = d_in[2];  const void* bqx  = d_in[3];
  const void* Wqy  = d_in[4];  const void* bqy  = d_in[5];
  const void* Wqxc = d_in[6];  const void* bqxc = d_in[7];
  const void* Wqyc = d_in[8];  const void* bqyc = d_in[9];
  const void* Wpxc = d_in[10]; const void* bpxc = d_in[11];
  const void* Wpyc = d_in[12]; const void* bpyc = d_in[13];
  const void* Wax  = d_in[14]; const void* bax  = d_in[15];
  const void* Way  = d_in[16]; const void* bay  = d_in[17];

  char* base = (char*)d_ws;
  int* flag = (int*)base;
  size_t off = 256;
  auto alloc16 = [&](size_t elems) -> u16* {
    u16* p = (u16*)(base + off);
    off = (off + elems * 2 + 255) & ~(size_t)255;
    return p;
  };

  // ---- fat-path fixed layout (all alloc sizes are 256B multiples -> pairs
  // of same-size buffers allocated back-to-back are stride-contiguous, which
  // the Z=2 batched GEMM calls below rely on) ----
  u16* WqxT  = alloc16((size_t)2304 * 768);
  u16* WqyT  = alloc16((size_t)2304 * 768);
  u16* WqxcT = alloc16((size_t)6912 * 2304);
  u16* WqycT = alloc16((size_t)6912 * 2304);
  u16* WpxcT = alloc16((size_t)2304 * 2304);
  u16* WpycT = alloc16((size_t)2304 * 2304);
  u16* WaxT  = alloc16((size_t)768 * 768);
  u16* WayT  = alloc16((size_t)768 * 768);
  u16* biasB = alloc16(24576);
  u16* xb = alloc16(NC);
  u16* yb = alloc16(NC);
  u16* RT = alloc16(2 * NC);      // xt,yt -> attx,atty -> attxc,attyc
  u16* RQ1 = alloc16(3 * NC);     // qkvxs -> qkvxc
  u16* RQ2 = alloc16(3 * NC);     // qkvys -> qkvyc
  u16* RS = alloc16(2 * NC);      // xself, yself
  u16* VT = alloc16(2 * NC);      // transposed V: spatial x/y (flash), channel reuse slot 0
  size_t fixedEnd = off;
  float* Sbuf = (float*)(base + fixedEnd);
  size_t availS = ws_size > fixedEnd ? ws_size - fixedEnd : 0;

  const size_t spHead = (size_t)N * N * 4;
  const bool fat = ws_size >= fixedEnd + spHead;

  auto G64 = [&](const void* A, int lda, long sAz, int aExt,
                 const void* B, int ldb, long sBz, int bNT, int bExt,
                 const void* bias, void* Out, int ldo, long sOz, long oOff, int outMode,
                 float scale, int M, int Nn, int K, int Z) {
    dim3 grid((Nn + BN - 1) / BN, (M + BM - 1) / BM, Z);
    gemm64<<<grid, 256, 0, stream>>>(A, lda, sAz, aExt, B, ldb, sBz, bNT, bExt,
                                     bias, Out, ldo, sOz, oOff, outMode, flag,
                                     scale, M, Nn, K);
  };
  auto G128 = [&](const u16* A, int lda, long sAz,
                  const u16* B, int ldb, long sBz,
                  const u16* bias, int sBiasZ,
                  void* Out, int ldo, long sOz, long oOff, int outMode,
                  float scale, int M, int Nn, int K, int Z) {
    dim3 grid(Nn / 128, M / 128, Z);
    gemm128<<<grid, 256, 0, stream>>>(A, lda, sAz, B, ldb, sBz, bias, sBiasZ,
                                      Out, ldo, sOz, oOff, outMode, flag,
                                      scale, M, Nn, K);
  };

  probe_dtype<<<1, 256, 0, stream>>>((const u32*)x, 1024, flag);

  if (fat) {
    transpose_in<<<dim3(2304 / 32, 768 / 32),  256, 0, stream>>>(Wqx,  WqxT,  flag, 768,  2304);
    transpose_in<<<dim3(2304 / 32, 768 / 32),  256, 0, stream>>>(Wqy,  WqyT,  flag, 768,  2304);
    transpose_in<<<dim3(6912 / 32, 2304 / 32), 256, 0, stream>>>(Wqxc, WqxcT, flag, 2304, 6912);
    transpose_in<<<dim3(6912 / 32, 2304 / 32), 256, 0, stream>>>(Wqyc, WqycT, flag, 2304, 6912);
    transpose_in<<<dim3(2304 / 32, 2304 / 32), 256, 0, stream>>>(Wpxc, WpxcT, flag, 2304, 2304);
    transpose_in<<<dim3(2304 / 32, 2304 / 32), 256, 0, stream>>>(Wpyc, WpycT, flag, 2304, 2304);
    transpose_in<<<dim3(768 / 32, 768 / 32),   256, 0, stream>>>(Wax,  WaxT,  flag, 768,  768);
    transpose_in<<<dim3(768 / 32, 768 / 32),   256, 0, stream>>>(Way,  WayT,  flag, 768,  768);
    P8 bp; bp.p[0] = bqx; bp.p[1] = bqy; bp.p[2] = bqxc; bp.p[3] = bqyc;
    bp.p[4] = bpxc; bp.p[5] = bpyc; bp.p[6] = bax; bp.p[7] = bay;
    cvt_bias<<<96, 256, 0, stream>>>(bp, biasB, flag);
    const u16 *bqxB = biasB, *bqxcB = biasB + 4608,
              *bpxcB = biasB + 18432, *baxB = biasB + 23040;
    cvt_flat<<<(unsigned)(NC / 4 / 256), 256, 0, stream>>>(x, xb, flag, (long)NC);
    cvt_flat<<<(unsigned)(NC / 4 / 256), 256, 0, stream>>>(y, yb, flag, (long)NC);
    u16 *xt = RT, *yt = RT + NC;
    transpose_in<<<dim3(N / 32, C / 32), 256, 0, stream>>>(x, xt, flag, C, N);
    transpose_in<<<dim3(N / 32, C / 32), 256, 0, stream>>>(y, yt, flag, C, N);

    // channel attention: scores gemm128 NT -> softmax -> PV gemm_pv NT
    auto attF = [&](const u16* qB, const u16* kB, const u16* vB, int ldq,
                    u16* att, int Mq, int hd, float scl) {
      // Vt[j, n] = V[n, j]; j over all 8*hd columns, ld = Mq
      transpose_v<<<dim3((8 * hd) / 32, Mq / 32), 256, 0, stream>>>(vB, ldq, VT, Mq, Mq, 8 * hd);
      const long perHead = (long)Mq * Mq * 4;
      int nb = (int)(availS / perHead);
      if (nb > 8) nb = 8;
      for (int h0 = 0; h0 < 8; h0 += nb) {
        const int zc = (8 - h0 < nb) ? 8 - h0 : nb;
        G128(qB + h0 * hd, ldq, hd, kB + h0 * hd, ldq, hd, nullptr, 0,
             Sbuf, Mq, (long)Mq * Mq, 0, 1, scl, Mq, Mq, hd, zc);
        softmax_rows<<<dim3(Mq, zc), 256, 0, stream>>>(Sbuf, Mq, (long)Mq * Mq,
            (u16*)Sbuf, 2 * Mq, (long)Mq * 2 * Mq, Mq);
        gemm_pv<<<dim3(hd / 96, Mq / 64, zc), 256, 0, stream>>>(
            (const u16*)Sbuf, 2 * Mq, (long)Mq * 2 * Mq,
            VT + (long)h0 * hd * Mq, Mq, (long)hd * Mq,
            att + (long)h0 * Mq * hd, hd, (long)Mq * hd, Mq);
      }
    };

    // ---- spatial phase ----
    // x and y batched via Z=2 (A stride NC, W stride NC, bias stride 3C, out stride 3NC)
    u16 *qkvxs = RQ1;
    G128(xt, C, (long)NC, WqxT, C, (long)NC, bqxB, 3 * C,
         qkvxs, 3 * C, 3 * (long)NC, 0, 0, 1.f, N, 3 * C, C, 2);

    // fused spatial attention (x and y in one launch; S never hits memory)
    u16 *qkvys = RQ2;
    u16 *attx = RT;
    const float sscale = 1.0f / sqrtf(96.0f);
    transpose_v<<<dim3((8 * HD) / 32, N / 32), 256, 0, stream>>>(
        qkvxs + 2 * C, 3 * C, VT, N, N, 8 * HD);
    transpose_v<<<dim3((8 * HD) / 32, N / 32), 256, 0, stream>>>(
        qkvys + 2 * C, 3 * C, VT + NC, N, N, 8 * HD);
    flash96<<<dim3(N / 64, 8, 2), 256, 0, stream>>>(
        qkvxs, 3 * (long)NC, VT, (long)NC, attx, (long)NC, 3 * C, N, sscale);

    u16 *xself = RS;
    G128(attx, C, (long)NC, WaxT, C, (long)768 * 768, baxB, C,
         xself, C, (long)NC, 0, 0, 1.f, N, C, C, 2);

    // ---- channel phase ----
    u16 *qkvxc = RQ1, *qkvyc = RQ2;
    G128(xb, N, (long)NC, WqxcT, N, (long)6912 * 2304, bqxcB, 3 * N,
         qkvxc, 3 * N, 3 * (long)NC, 0, 0, 1.f, C, 3 * N, N, 2);

    u16 *attxc = RT, *attyc = RT + NC;
    const float cscale = 1.0f / sqrtf(288.0f);
    attF(qkvxc, qkvyc + N, qkvyc + 2 * N, 3 * N, attxc, C, HDC, cscale);
    attF(qkvyc, qkvxc + N, qkvxc + 2 * N, 3 * N, attyc, C, HDC, cscale);

    G128(attxc, N, (long)NC, WpxcT, N, (long)2304 * 2304, bpxcB, N,
         d_out, N, (long)NC, 0, 2, 1.f, C, N, N, 2);

    transpose_add_out<<<dim3(C / 32, N / 32), 256, 0, stream>>>(xself, d_out, 0, flag, N, C);
    transpose_add_out<<<dim3(C / 32, N / 32), 256, 0, stream>>>(RS + NC, d_out, (long)NC, flag, N, C);
    return;
  }

  // ================= fallback: round-3 verified path =================
  {
    char* b2 = (char*)d_ws;
    u16* RA = (u16*)(b2 + 256);
    u16* RB = RA + 3 * NC;
    u16* RD = RB + 3 * NC;
    u16* RE = RD + 2 * NC;
    const size_t offSsp = 256 + (size_t)(8 * NC) * 2;
    float* Ssp = (float*)(b2 + offSsp);
    const size_t availSp = ws_size > offSsp ? ws_size - offSsp : 0;
    const size_t offSch = 256 + (size_t)(10 * NC) * 2;
    float* Sch = (float*)(b2 + offSch);
    const size_t availCh = ws_size > offSch ? ws_size - offSch : 0;

    u16 *xt = RD, *yt = RD + NC;
    u16 *qkvxs = RA, *qkvys = RB;
    u16 *attx = RD, *atty = RD + NC;
    u16 *xself = RE, *yself = RE + NC;
    u16 *qkvxc = RA, *qkvyc = RB;
    u16 *attxc = RD, *attyc = RD + NC;

    auto attention = [&](const u16* qB, const u16* kB, const u16* vB, int ldq,
                         u16* att, int Mq, int hd, float scl,
                         float* S, size_t availBytes) {
      const long perHead = (long)Mq * Mq * 4;
      int nb = (int)(availBytes / perHead);
      if (nb > 8) nb = 8;
      if (nb >= 1) {
        for (int h0 = 0; h0 < 8; h0 += nb) {
          const int zc = (8 - h0 < nb) ? 8 - h0 : nb;
          G64(qB + h0 * hd, ldq, hd, 0, kB + h0 * hd, ldq, hd, 1, 0, nullptr,
              S, Mq, (long)Mq * Mq, 0, 1, scl, Mq, Mq, hd, zc);
          softmax_rows<<<dim3(Mq, zc), 256, 0, stream>>>(S, Mq, (long)Mq * Mq,
              (u16*)S, 2 * Mq, (long)Mq * 2 * Mq, Mq);
          G64((const u16*)S, 2 * Mq, (long)Mq * 2 * Mq, 0, vB + h0 * hd, ldq, hd, 0, 0,
              nullptr, att + (long)h0 * Mq * hd, hd, (long)Mq * hd, 0, 0,
              1.f, Mq, hd, Mq, zc);
        }
      } else {
        long rows = (long)(availBytes / ((size_t)Mq * 4)) & ~63L;
        if (rows < 64) rows = 64;
        if (rows > Mq) rows = Mq;
        for (int h = 0; h < 8; h++) {
          for (int m0 = 0; m0 < Mq; m0 += (int)rows) {
            const int mr = (Mq - m0 < rows) ? (int)(Mq - m0) : (int)rows;
            G64(qB + (long)m0 * ldq + h * hd, ldq, 0, 0, kB + h * hd, ldq, 0, 1, 0,
                nullptr, S, Mq, 0, 0, 1, scl, mr, Mq, hd, 1);
            softmax_rows<<<dim3(mr, 1), 256, 0, stream>>>(S, Mq, 0, (u16*)S, 2 * Mq, 0, Mq);
            G64((const u16*)S, 2 * Mq, 0, 0, vB + h * hd, ldq, 0, 0, 0, nullptr,
                att + (long)h * Mq * hd + (long)m0 * hd, hd, 0, 0, 0, 1.f, mr, hd, Mq, 1);
          }
        }
      }
    };

    transpose_in<<<dim3(N / 32, C / 32), 256, 0, stream>>>(x, xt, flag, C, N);
    transpose_in<<<dim3(N / 32, C / 32), 256, 0, stream>>>(y, yt, flag, C, N);

    G64(xt, C, 0, 0, Wqx, 3 * C, 0, 0, 1, bqx, qkvxs, 3 * C, 0, 0, 0, 1.f, N, 3 * C, C, 1);
    G64(yt, C, 0, 0, Wqy, 3 * C, 0, 0, 1, bqy, qkvys, 3 * C, 0, 0, 0, 1.f, N, 3 * C, C, 1);

    const float sscale = 1.0f / sqrtf(96.0f);
    attention(qkvxs, qkvxs + C, qkvxs + 2 * C, 3 * C, attx, N, HD, sscale, Ssp, availSp);
    attention(qkvys, qkvys + C, qkvys + 2 * C, 3 * C, atty, N, HD, sscale, Ssp, availSp);

    G64(attx, C, 0, 0, Wax, C, 0, 0, 1, bax, xself, C, 0, 0, 0, 1.f, N, C, C, 1);
    G64(atty, C, 0, 0, Way, C, 0, 0, 1, bay, yself, C, 0, 0, 0, 1.f, N, C, C, 1);

    G64(x, N, 0, 1, Wqxc, 3 * N, 0, 0, 1, bqxc, qkvxc, 3 * N, 0, 0, 0, 1.f, C, 3 * N, N, 1);
    G64(y, N, 0, 1, Wqyc, 3 * N, 0, 0, 1, bqyc, qkvyc, 3 * N, 0, 0, 0, 1.f, C, 3 * N, N, 1);

    const float cscale = 1.0f / sqrtf(288.0f);
    attention(qkvxc, qkvyc + N, qkvyc + 2 * N, 3 * N, attxc, C, HDC, cscale, Sch, availCh);
    attention(qkvyc, qkvxc + N, qkvxc + 2 * N, 3 * N, attyc, C, HDC, cscale, Sch, availCh);

    G64(attxc, N, 0, 0, Wpxc, N, 0, 0, 1, bpxc, d_out, N, 0, 0, 2, 1.f, C, N, N, 1);
    G64(attyc, N, 0, 0, Wpyc, N, 0, 0, 1, bpyc, d_out, N, 0, (long)NC, 2, 1.f, C, N, N, 1);

    transpose_add_out<<<dim3(C / 32, N / 32), 256, 0, stream>>>(xself, d_out, 0, flag, N, C);
    transpose_add_out<<<dim3(C / 32, N / 32), 256, 0, stream>>>(yself, d_out, (long)NC, flag, N, C);
  }
}

// Round 4
// 714.518 us; speedup vs baseline: 1.5138x; 1.1251x over previous
//
#include <hip/hip_runtime.h>
#include <math.h>

typedef unsigned short u16;
typedef unsigned int u32;
typedef short bf16x8 __attribute__((ext_vector_type(8)));
typedef float f32x4 __attribute__((ext_vector_type(4)));
typedef float f32x16 __attribute__((ext_vector_type(16)));

__device__ __forceinline__ float bf2f(u16 u) {
  union { unsigned int i; float f; } v;
  v.i = ((unsigned int)u) << 16;
  return v.f;
}
__device__ __forceinline__ u16 f2bf(float f) {
  union { float f; unsigned int i; } v;
  v.f = f;
  unsigned int u = v.i;
  return (u16)((u + 0x7fffu + ((u >> 16) & 1u)) >> 16);
}
// pack two f32 -> two bf16 in one u32 (lo = a, hi = b)
__device__ __forceinline__ u32 pkbf(float a, float b) {
  u32 d;
  asm("v_cvt_pk_bf16_f32 %0, %1, %2" : "=v"(d) : "v"(a), "v"(b));
  return d;
}

// async global->LDS, 16B per lane. LDS dest = wave-uniform base + lane*16.
__device__ __forceinline__ void glds16(const u16* g, u16* l) {
  __builtin_amdgcn_global_load_lds(
      (const __attribute__((address_space(1))) void*)g,
      (__attribute__((address_space(3))) void*)l, 16, 0, 0);
}

// ---------------------------------------------------------------------------
// dtype probe: fp32(1) vs bf16(0) from bit statistics of x.
// ---------------------------------------------------------------------------
__global__ __launch_bounds__(256) void probe_dtype(const u32* __restrict__ xw,
                                                   int nwords, int* flag)
{
  const int tid = threadIdx.x;
  int cnt = 0;
  for (int i = tid; i < nwords; i += 256) {
    u32 w = xw[i];
    u32 e = (w >> 7) & 0xFFu;
    if (e >= 110u && e <= 140u) cnt++;
  }
#pragma unroll
  for (int off = 32; off >= 1; off >>= 1) cnt += __shfl_xor(cnt, off);
  __shared__ int s[4];
  if ((tid & 63) == 0) s[tid >> 6] = cnt;
  __syncthreads();
  if (tid == 0) {
    int tot = s[0] + s[1] + s[2] + s[3];
    flag[0] = (tot < nwords / 2) ? 1 : 0;
  }
}

// ---------------------------------------------------------------------------
// gemm128: 128x128 tile, BK=32, NT-only, all-bf16 inputs, glds staging.
// Double-buffered 2-phase pipeline: stage tile t+1 while computing tile t.
// Out[m,n] = scale * sum_k A[m,k] * B[n,k] + bias[n + z*sBiasZ]
// ---------------------------------------------------------------------------
__global__ __launch_bounds__(256) void gemm128(
    const u16* __restrict__ A, int lda, long sAz,
    const u16* __restrict__ B, int ldb, long sBz,
    const u16* __restrict__ bias, int sBiasZ,
    void* __restrict__ OutV, int ldo, long sOz, long oOff, int outMode,
    const int* __restrict__ flagp,
    float scale, int M, int Nn, int K)
{
  const int z = blockIdx.z;
  const u16* Ab = A + (long)z * sAz;
  const u16* Bb = B + (long)z * sBz;
  const int bm = blockIdx.y * 128;
  const int bn = blockIdx.x * 128;

  __shared__ u16 As[2][128 * 32];
  __shared__ u16 Bs[2][128 * 32];

  const int tid  = threadIdx.x;
  const int lane = tid & 63;
  const int wave = tid >> 6;
  const int wr = wave >> 1, wc = wave & 1;
  const int q = lane >> 4, l15 = lane & 15;

  f32x4 acc[4][4];
#pragma unroll
  for (int i = 0; i < 4; i++)
#pragma unroll
    for (int j = 0; j < 4; j++) acc[i][j] = (f32x4){0.f, 0.f, 0.f, 0.f};

  const int srow = tid >> 2;
  const int sc8  = (tid & 3) * 8;
  const u16* aptr = Ab + (long)(bm + srow) * lda + sc8;
  const u16* bptr = Bb + (long)(bn + srow) * ldb + sc8;

  auto stage = [&](int buf, int k0) {
    u16* asl = As[buf] + tid * 8;
    u16* bsl = Bs[buf] + tid * 8;
    glds16(aptr + k0, asl);
    glds16(aptr + (long)64 * lda + k0, asl + 256 * 8);
    glds16(bptr + k0, bsl);
    glds16(bptr + (long)64 * ldb + k0, bsl + 256 * 8);
  };
  auto compute = [&](int buf) {
    bf16x8 af[4], bfr[4];
#pragma unroll
    for (int mi = 0; mi < 4; mi++)
      af[mi] = *(const bf16x8*)(As[buf] + (wr * 64 + mi * 16 + l15) * 32 + q * 8);
#pragma unroll
    for (int nj = 0; nj < 4; nj++)
      bfr[nj] = *(const bf16x8*)(Bs[buf] + (wc * 64 + nj * 16 + l15) * 32 + q * 8);
#pragma unroll
    for (int mi = 0; mi < 4; mi++)
#pragma unroll
      for (int nj = 0; nj < 4; nj++)
        acc[mi][nj] = __builtin_amdgcn_mfma_f32_16x16x32_bf16(af[mi], bfr[nj], acc[mi][nj], 0, 0, 0);
  };

  // prologue: stage tile 0, drain, then pipeline.
  stage(0, 0);
  __syncthreads();           // emits s_waitcnt vmcnt(0) lgkmcnt(0) + s_barrier
  int cur = 0;
  for (int k0 = 32; k0 < K; k0 += 32) {
    stage(cur ^ 1, k0);      // next tile's loads fly during current compute
    compute(cur);
    __syncthreads();
    cur ^= 1;
  }
  compute(cur);

  const int flagv = (outMode == 2) ? *flagp : 0;
  const bool storeF32 = (outMode == 1) || (outMode == 2 && flagv);
  const u16* bz = bias ? bias + (long)z * sBiasZ : nullptr;
#pragma unroll
  for (int mi = 0; mi < 4; mi++) {
    const int r0 = bm + wr * 64 + mi * 16 + q * 4;
#pragma unroll
    for (int nj = 0; nj < 4; nj++) {
      const int col = bn + wc * 64 + nj * 16 + l15;
      const float bsv = bz ? bf2f(bz[col]) : 0.0f;
      if (storeF32) {
        float* Out = (float*)OutV + oOff + (long)z * sOz;
#pragma unroll
        for (int r = 0; r < 4; r++)
          Out[(long)(r0 + r) * ldo + col] = acc[mi][nj][r] * scale + bsv;
      } else {
        u16* Out = (u16*)OutV + oOff + (long)z * sOz;
#pragma unroll
        for (int r = 0; r < 4; r++)
          Out[(long)(r0 + r) * ldo + col] = f2bf(acc[mi][nj][r] * scale + bsv);
      }
    }
  }
}

// ---------------------------------------------------------------------------
// flashS: fused spatial attention, hd=96, m214-style 32x32 swapped-operand
// structure. 4 waves x 32 q-rows = BQ 128 per block; KV tiles of 64.
//  - S^T = mfma32(K-frag, Q-frag): lane owns P-row for q=lane&31 (C-layout
//    col=lane&31, row=(reg&3)+8*(reg>>2)+4*(lane>>5) -- m74/m101 verified).
//  - softmax: 31 local fmax + one shfl_xor(32); defer-max THR=8 (T13).
//  - P->PV A-frags in-register via 16 cvt_pk + 8 permlane32_swap (T12);
//    P never touches LDS.
//  - K in LDS [64][128pad], V [96][64], granule ^= (row&7) XOR swizzle;
//    staged by glds16 with PRE-SWIZZLED global source (m173), dbuf 2-phase.
// grid = (Mq/128, 8 heads, 2 tensors), 256 threads. LDS 56 KB.
// ---------------------------------------------------------------------------
__global__ __launch_bounds__(256) void flashS(
    const u16* __restrict__ QKV, long sTz,   // q at col h*96; k at col 768+h*96
    const u16* __restrict__ VTb, long sVz,   // Vt [768][Mq] per tensor
    u16* __restrict__ Out, long sOz,         // att + h*Mq*96 + q*96 + d
    int ldq, int Mq, float scl)
{
  const int bm = blockIdx.x * 128;
  const int h  = blockIdx.y;
  const int t  = blockIdx.z;
  const int h96 = h * 96;
  const u16* qB  = QKV + (long)t * sTz;
  const u16* kB  = qB + 768;
  const u16* vtB = VTb + (long)t * sVz + (long)h96 * Mq;
  u16* oB = Out + (long)t * sOz + (long)h * Mq * 96;

  __shared__ u16 KsL[2][64 * 128];   // row = 256B (16 granules), cols 0..95 used
  __shared__ u16 VsL[2][96 * 64];    // row = 128B (8 granules)

  const int tid  = threadIdx.x;
  const int lane = tid & 63;
  const int wave = tid >> 6;
  const int l31  = lane & 31;
  const int hi   = lane >> 5;

  // ---- Q fragments, hoisted + pre-scaled (ref scales Q before matmul) ----
  bf16x8 qf[6];
  {
    const u16* qrow = qB + (long)(bm + wave * 32 + l31) * ldq + h96;
#pragma unroll
    for (int cs = 0; cs < 6; cs++) {
      union { bf16x8 v; u16 e[8]; } a, b;
      a.v = *(const bf16x8*)(qrow + cs * 16 + hi * 8);
#pragma unroll
      for (int e = 0; e < 8; e++) b.e[e] = f2bf(bf2f(a.e[e]) * scl);
      qf[cs] = b.v;
    }
  }

  f32x16 accO[3];
#pragma unroll
  for (int r = 0; r < 16; r++) { accO[0][r] = 0.f; accO[1][r] = 0.f; accO[2][r] = 0.f; }
  float m_r = -1e30f, l_r = 0.f;

  // stage via glds16 with pre-swizzled global source: LDS granule G holds
  // data for (row, g) where g = (G & mask) ^ (row & 7).
  auto stageKV = [&](int buf, int k0) {
    const u16* kBase = kB + (long)k0 * ldq + h96;
#pragma unroll
    for (int i = 0; i < 4; i++) {
      const int G = tid + 256 * i;
      const int row = G >> 4;
      const int g = (G & 15) ^ (row & 7);
      const u16* src = (g < 12) ? (kBase + (long)row * ldq + g * 8) : kB;
      glds16(src, &KsL[buf][G * 8]);
    }
    const u16* vBase = vtB + k0;
#pragma unroll
    for (int i = 0; i < 3; i++) {
      const int G = tid + 256 * i;
      const int row = G >> 3;
      const int g = (G & 7) ^ (row & 7);
      glds16(vBase + (long)row * Mq + g * 8, &VsL[buf][G * 8]);
    }
  };
  auto ldK = [&](int buf, int kt2, int cs) -> bf16x8 {
    const int row = kt2 * 32 + l31;
    const int g = (2 * cs + hi) ^ (row & 7);
    return *(const bf16x8*)(&KsL[buf][row * 128 + g * 8]);
  };
  auto ldV = [&](int buf, int dt, int s) -> bf16x8 {
    const int row = dt * 32 + l31;
    const int g = (2 * s + hi) ^ (row & 7);
    return *(const bf16x8*)(&VsL[buf][row * 64 + g * 8]);
  };

  stageKV(0, 0);
  __syncthreads();
  int cur = 0;
  const int nt = Mq / 64;
  for (int kt = 0; kt < nt; kt++) {
    if (kt + 1 < nt) stageKV(cur ^ 1, (kt + 1) * 64);  // flies under compute

    // ---- S^T = K Q^T : lane owns 32 P-values for q-row l31 ----
    f32x16 sA, sB;
#pragma unroll
    for (int r = 0; r < 16; r++) { sA[r] = 0.f; sB[r] = 0.f; }
#pragma unroll
    for (int cs = 0; cs < 6; cs++) {
      sA = __builtin_amdgcn_mfma_f32_32x32x16_bf16(ldK(cur, 0, cs), qf[cs], sA, 0, 0, 0);
      sB = __builtin_amdgcn_mfma_f32_32x32x16_bf16(ldK(cur, 1, cs), qf[cs], sB, 0, 0, 0);
    }

    // ---- online softmax: local + one cross-half shfl ----
    float tm = -1e30f;
#pragma unroll
    for (int r = 0; r < 16; r++) tm = fmaxf(tm, fmaxf(sA[r], sB[r]));
    tm = fmaxf(tm, __shfl_xor(tm, 32));
    if (!__all(tm <= m_r + 8.f)) {            // defer-max (T13)
      const float mn = fmaxf(m_r, tm);
      const float al = __expf(m_r - mn);
      m_r = mn; l_r *= al;
#pragma unroll
      for (int r = 0; r < 16; r++) {
        const float a = __shfl(al, (r & 3) + 8 * (r >> 2) + 4 * hi);
        accO[0][r] *= a; accO[1][r] *= a; accO[2][r] *= a;
      }
    }
    float rs = 0.f;
#pragma unroll
    for (int r = 0; r < 16; r++) {
      sA[r] = __expf(sA[r] - m_r); rs += sA[r];
      sB[r] = __expf(sB[r] - m_r); rs += sB[r];
    }
    rs += __shfl_xor(rs, 32);
    l_r += rs;

    // ---- PV: A-frags built in-register (cvt_pk + permlane32_swap) ----
#pragma unroll
    for (int s = 0; s < 4; s++) {
      const f32x16& P = (s < 2) ? sA : sB;
      const int rb = (s & 1) * 8;
      u32 X  = pkbf(P[rb + 0], P[rb + 1]);
      u32 X2 = pkbf(P[rb + 2], P[rb + 3]);
      u32 Y  = pkbf(P[rb + 4], P[rb + 5]);
      u32 Y2 = pkbf(P[rb + 6], P[rb + 7]);
      asm volatile("v_permlane32_swap_b32 %0, %1" : "+v"(X), "+v"(Y));
      asm volatile("v_permlane32_swap_b32 %0, %1" : "+v"(X2), "+v"(Y2));
      union { u32 w[4]; bf16x8 v; } pa;
      pa.w[0] = X; pa.w[1] = X2; pa.w[2] = Y; pa.w[3] = Y2;
#pragma unroll
      for (int dt = 0; dt < 3; dt++)
        accO[dt] = __builtin_amdgcn_mfma_f32_32x32x16_bf16(pa.v, ldV(cur, dt, s), accO[dt], 0, 0, 0);
    }

    __syncthreads();     // stage visible + all reads of cur done
    cur ^= 1;
  }

  // ---- epilogue: normalize rows, store bf16 ----
  const float inv = 1.0f / l_r;
#pragma unroll
  for (int r = 0; r < 16; r++) {
    const int row = (r & 3) + 8 * (r >> 2) + 4 * hi;
    const float iv = __shfl(inv, row);
    const long rowb = (long)(bm + wave * 32 + row) * 96;
#pragma unroll
    for (int dt = 0; dt < 3; dt++)
      oB[rowb + dt * 32 + l31] = f2bf(accO[dt][r] * iv);
  }
}

// ---------------------------------------------------------------------------
// gemm_pv: PV-shaped NT GEMM. Out[m, bn+c] = sum_k P[m,k] * Vt[bn+c, k].
// BM=64, BN=96 (exact head width unit), BK=32, glds staging, bf16 out.
// Double-buffered 2-phase pipeline.
// grid = (hd/96, M/64, nheads); K = Mq. All dims: M%64, K%32, lds %8.
// ---------------------------------------------------------------------------
__global__ __launch_bounds__(256) void gemm_pv(
    const u16* __restrict__ P, int ldP, long sPz,
    const u16* __restrict__ Vt, int ldVt, long sVz,
    u16* __restrict__ Out, int ldo, long sOz, int K)
{
  const int z = blockIdx.z;
  const u16* Pz = P + (long)z * sPz;
  const u16* Vz = Vt + (long)z * sVz;
  u16* Oz = Out + (long)z * sOz;
  const int bm = blockIdx.y * 64;
  const int bn = blockIdx.x * 96;

  __shared__ u16 As[2][64 * 32];   // [64][32]
  __shared__ u16 Bs[2][96 * 32];   // [96][32] (rows = output cols)

  const int tid  = threadIdx.x;
  const int lane = tid & 63;
  const int wave = tid >> 6;
  const int wr = wave >> 1, wc = wave & 1;
  const int q = lane >> 4, l15 = lane & 15;

  f32x4 acc[2][3];
#pragma unroll
  for (int i = 0; i < 2; i++)
#pragma unroll
    for (int j = 0; j < 3; j++) acc[i][j] = (f32x4){0.f, 0.f, 0.f, 0.f};

  const int srow = lane >> 2;        // 0..15
  const int sc8  = (lane & 3) * 8;   // 0,8,16,24

  // A: 4 chunks of 16 rows; wave w stages chunk w.
  const u16* aRow = Pz + (long)(bm + wave * 16 + srow) * ldP + sc8;
  // B: 6 chunks of 16 rows; waves 0..2 stage chunks 2w, 2w+1.
  const u16* bRow0 = nullptr; const u16* bRow1 = nullptr;
  if (wave < 3) {
    bRow0 = Vz + (long)(bn + (2 * wave) * 16 + srow) * ldVt + sc8;
    bRow1 = Vz + (long)(bn + (2 * wave + 1) * 16 + srow) * ldVt + sc8;
  }

  auto stage = [&](int buf, int k0) {
    glds16(aRow + k0, As[buf] + wave * 512 + lane * 8);
    if (wave < 3) {
      glds16(bRow0 + k0, Bs[buf] + (2 * wave) * 512 + lane * 8);
      glds16(bRow1 + k0, Bs[buf] + (2 * wave + 1) * 512 + lane * 8);
    }
  };
  auto compute = [&](int buf) {
    bf16x8 af[2], bfr[3];
#pragma unroll
    for (int mi = 0; mi < 2; mi++)
      af[mi] = *(const bf16x8*)(As[buf] + (wr * 32 + mi * 16 + l15) * 32 + q * 8);
#pragma unroll
    for (int nj = 0; nj < 3; nj++)
      bfr[nj] = *(const bf16x8*)(Bs[buf] + (wc * 48 + nj * 16 + l15) * 32 + q * 8);
#pragma unroll
    for (int mi = 0; mi < 2; mi++)
#pragma unroll
      for (int nj = 0; nj < 3; nj++)
        acc[mi][nj] = __builtin_amdgcn_mfma_f32_16x16x32_bf16(af[mi], bfr[nj], acc[mi][nj], 0, 0, 0);
  };

  stage(0, 0);
  __syncthreads();
  int cur = 0;
  for (int k0 = 32; k0 < K; k0 += 32) {
    stage(cur ^ 1, k0);
    compute(cur);
    __syncthreads();
    cur ^= 1;
  }
  compute(cur);

#pragma unroll
  for (int mi = 0; mi < 2; mi++) {
    const int r0 = bm + wr * 32 + mi * 16 + q * 4;
#pragma unroll
    for (int nj = 0; nj < 3; nj++) {
      const int cl = bn + wc * 48 + nj * 16 + l15;
#pragma unroll
      for (int r = 0; r < 4; r++)
        Oz[(long)(r0 + r) * ldo + cl] = f2bf(acc[mi][nj][r]);
    }
  }
}

// ---------------------------------------------------------------------------
// Generic 64x64 MFMA bf16 GEMM (round-3 verified; fallback path only).
// ---------------------------------------------------------------------------
#define BM 64
#define BN 64
#define BK 32
#define LDSP (BK + 8)

__global__ __launch_bounds__(256) void gemm64(
    const void* __restrict__ Av, int lda, long sAz, int aExt,
    const void* __restrict__ Bv, int ldb, long sBz, int bNT, int bExt,
    const void* __restrict__ biasv,
    void* __restrict__ OutV, int ldo, long sOz, long oOff, int outMode,
    const int* __restrict__ flagp,
    float scale, int M, int Nn, int K)
{
  const int flagv = *flagp;
  const bool aF32 = aExt && flagv;
  const bool bF32 = bExt && flagv;

  const int z = blockIdx.z;
  const int bm = blockIdx.y * BM;
  const int bn = blockIdx.x * BN;

  __shared__ u16 As[BM][LDSP];
  __shared__ u16 Bs[BN][LDSP];

  const int tid  = threadIdx.x;
  const int lane = tid & 63;
  const int wave = tid >> 6;
  const int wr = wave >> 1;
  const int wc = wave & 1;
  const int q   = lane >> 4;
  const int l15 = lane & 15;

  f32x4 acc[2][2];
#pragma unroll
  for (int i = 0; i < 2; i++)
#pragma unroll
    for (int j = 0; j < 2; j++) acc[i][j] = (f32x4){0.f, 0.f, 0.f, 0.f};

  const int am  = tid >> 2;
  const int ach = (tid & 3) * 8;

  for (int k0 = 0; k0 < K; k0 += BK) {
    __syncthreads();
    if (aF32) {
      const float* src = (const float*)Av + (long)z * sAz + (long)(bm + am) * lda + (k0 + ach);
      f32x4 f0 = *(const f32x4*)src;
      f32x4 f1 = *(const f32x4*)(src + 4);
      u16 t[8] = {f2bf(f0[0]), f2bf(f0[1]), f2bf(f0[2]), f2bf(f0[3]),
                  f2bf(f1[0]), f2bf(f1[1]), f2bf(f1[2]), f2bf(f1[3])};
      *(uint4*)(&As[am][ach]) = *(const uint4*)t;
    } else {
      const u16* src = (const u16*)Av + (long)z * sAz + (long)(bm + am) * lda + (k0 + ach);
      *(uint4*)(&As[am][ach]) = *(const uint4*)src;
    }
    if (bNT) {
      if (bF32) {
        u16 t[8] = {0, 0, 0, 0, 0, 0, 0, 0};
        if (bn + am < Nn) {
          const float* src = (const float*)Bv + (long)z * sBz + (long)(bn + am) * ldb + (k0 + ach);
          f32x4 f0 = *(const f32x4*)src;
          f32x4 f1 = *(const f32x4*)(src + 4);
#pragma unroll
          for (int j = 0; j < 4; j++) { t[j] = f2bf(f0[j]); t[4 + j] = f2bf(f1[j]); }
        }
        *(uint4*)(&Bs[am][ach]) = *(const uint4*)t;
      } else {
        uint4 val = make_uint4(0u, 0u, 0u, 0u);
        if (bn + am < Nn)
          val = *(const uint4*)((const u16*)Bv + (long)z * sBz + (long)(bn + am) * ldb + (k0 + ach));
        *(uint4*)(&Bs[am][ach]) = val;
      }
    } else {
      const int kk = tid >> 3;
      const int n0 = (tid & 7) * 8;
      if (bn + n0 < Nn) {
        if (bF32) {
          const float* src = (const float*)Bv + (long)z * sBz + (long)(k0 + kk) * ldb + (bn + n0);
          f32x4 f0 = *(const f32x4*)src;
          f32x4 f1 = *(const f32x4*)(src + 4);
#pragma unroll
          for (int j = 0; j < 4; j++) {
            Bs[n0 + j][kk] = f2bf(f0[j]);
            Bs[n0 + 4 + j][kk] = f2bf(f1[j]);
          }
        } else {
          uint4 val = *(const uint4*)((const u16*)Bv + (long)z * sBz + (long)(k0 + kk) * ldb + (bn + n0));
          const u16* pv = (const u16*)&val;
#pragma unroll
          for (int j = 0; j < 8; j++) Bs[n0 + j][kk] = pv[j];
        }
      } else {
#pragma unroll
        for (int j = 0; j < 8; j++) Bs[n0 + j][kk] = 0;
      }
    }
    __syncthreads();

    bf16x8 af[2], bfr[2];
#pragma unroll
    for (int t = 0; t < 2; t++)
      af[t] = *(const bf16x8*)(&As[wr * 32 + t * 16 + l15][q * 8]);
#pragma unroll
    for (int t = 0; t < 2; t++)
      bfr[t] = *(const bf16x8*)(&Bs[wc * 32 + t * 16 + l15][q * 8]);
#pragma unroll
    for (int i = 0; i < 2; i++)
#pragma unroll
      for (int j = 0; j < 2; j++)
        acc[i][j] = __builtin_amdgcn_mfma_f32_16x16x32_bf16(af[i], bfr[j], acc[i][j], 0, 0, 0);
  }

#pragma unroll
  for (int i = 0; i < 2; i++) {
    const int r0 = bm + wr * 32 + i * 16 + q * 4;
#pragma unroll
    for (int j = 0; j < 2; j++) {
      const int col = bn + wc * 32 + j * 16 + l15;
      if (col >= Nn) continue;
      float bsv = 0.0f;
      if (biasv) bsv = flagv ? ((const float*)biasv)[col] : bf2f(((const u16*)biasv)[col]);
      const bool storeF32 = (outMode == 1) || (outMode == 2 && flagv);
      if (storeF32) {
        float* Out = (float*)OutV + oOff + (long)z * sOz;
#pragma unroll
        for (int r = 0; r < 4; r++)
          Out[(long)(r0 + r) * ldo + col] = acc[i][j][r] * scale + bsv;
      } else {
        u16* Out = (u16*)OutV + oOff + (long)z * sOz;
#pragma unroll
        for (int r = 0; r < 4; r++)
          Out[(long)(r0 + r) * ldo + col] = f2bf(acc[i][j][r] * scale + bsv);
      }
    }
  }
}

// ---------------------------------------------------------------------------
// Row softmax: fp32 scores row -> bf16 probabilities; P aliases S (in-place).
// ---------------------------------------------------------------------------
__global__ __launch_bounds__(256) void softmax_rows(
    float* S, int ldS, long sSz,
    u16* P, int ldP, long sPz, int ncols)
{
  const int row = blockIdx.x;
  const int z = blockIdx.y;
  float* s = S + (long)z * sSz + (long)row * ldS;
  u16*   p = P + (long)z * sPz + (long)row * ldP;
  const int tid = threadIdx.x;
  const int lane = tid & 63, wave = tid >> 6;

  float v[9];
  int cnt = 0;
  float mx = -1e30f;
  for (int c = tid; c < ncols; c += 256) {
    float t = s[c];
    v[cnt++] = t;
    mx = fmaxf(mx, t);
  }
#pragma unroll
  for (int off = 32; off >= 1; off >>= 1) mx = fmaxf(mx, __shfl_xor(mx, off));
  __shared__ float redm[4];
  __shared__ float reds[4];
  if (lane == 0) redm[wave] = mx;
  __syncthreads();
  mx = fmaxf(fmaxf(redm[0], redm[1]), fmaxf(redm[2], redm[3]));

  float sum = 0.f;
  for (int i = 0; i < cnt; i++) { v[i] = __expf(v[i] - mx); sum += v[i]; }
#pragma unroll
  for (int off = 32; off >= 1; off >>= 1) sum += __shfl_xor(sum, off);
  if (lane == 0) reds[wave] = sum;
  __syncthreads();
  sum = reds[0] + reds[1] + reds[2] + reds[3];
  const float inv = 1.0f / sum;

  cnt = 0;
  for (int c = tid; c < ncols; c += 256) p[c] = f2bf(v[cnt++] * inv);
}

// ---------------------------------------------------------------------------
// transpose_in: outp[j*inRows+i] = (bf16) tin[i*inCols+j]; tin dtype per flag
// ---------------------------------------------------------------------------
__global__ __launch_bounds__(256) void transpose_in(
    const void* __restrict__ tinv, u16* __restrict__ outp,
    const int* __restrict__ flagp, int inRows, int inCols)
{
  const bool f32 = *flagp != 0;
  __shared__ u16 tile[32][33];
  const int bx = blockIdx.x * 32;
  const int by = blockIdx.y * 32;
  const int tx = threadIdx.x & 31;
  const int ty = threadIdx.x >> 5;
#pragma unroll
  for (int k = 0; k < 4; k++) {
    const long idx = (long)(by + ty + k * 8) * inCols + bx + tx;
    tile[ty + k * 8][tx] = f32 ? f2bf(((const float*)tinv)[idx]) : ((const u16*)tinv)[idx];
  }
  __syncthreads();
#pragma unroll
  for (int k = 0; k < 4; k++) {
    const int j = bx + ty + k * 8;
    const int i = by + tx;
    outp[(long)j * inRows + i] = tile[tx][ty + k * 8];
  }
}

// ---------------------------------------------------------------------------
// transpose_v: bf16 strided transpose. dst[j*lddst+n] = src[n*ldsrc+j]
// rows%32==0, cols%32==0. grid(cols/32, rows/32).
// ---------------------------------------------------------------------------
__global__ __launch_bounds__(256) void transpose_v(
    const u16* __restrict__ src, int ldsrc,
    u16* __restrict__ dst, int lddst, int rows, int cols)
{
  __shared__ u16 tile[32][33];
  const int bx = blockIdx.x * 32;   // over cols (j)
  const int by = blockIdx.y * 32;   // over rows (n)
  const int tx = threadIdx.x & 31;
  const int ty = threadIdx.x >> 5;
#pragma unroll
  for (int k = 0; k < 4; k++)
    tile[ty + k * 8][tx] = src[(long)(by + ty + k * 8) * ldsrc + bx + tx];
  __syncthreads();
#pragma unroll
  for (int k = 0; k < 4; k++)
    dst[(long)(bx + ty + k * 8) * lddst + by + tx] = tile[tx][ty + k * 8];
}

// flat convert (n % 4 == 0)
__global__ __launch_bounds__(256) void cvt_flat(
    const void* __restrict__ src, u16* __restrict__ dst,
    const int* __restrict__ flagp, long n)
{
  const bool f32 = *flagp != 0;
  long i = ((long)blockIdx.x * 256 + threadIdx.x) * 4;
  if (i + 3 < n) {
    if (f32) {
      f32x4 v = *(const f32x4*)((const float*)src + i);
#pragma unroll
      for (int j = 0; j < 4; j++) dst[i + j] = f2bf(v[j]);
    } else {
      *(uint2*)(dst + i) = *(const uint2*)((const u16*)src + i);
    }
  }
}

struct P8 { const void* p[8]; };
__global__ __launch_bounds__(256) void cvt_bias(P8 s, u16* __restrict__ dst,
                                                const int* __restrict__ flagp)
{
  const bool f32 = *flagp != 0;
  const int sizes[8] = {2304, 2304, 6912, 6912, 2304, 2304, 768, 768};
  int gid = blockIdx.x * 256 + threadIdx.x;
  int seg = 0, off = gid;
  while (seg < 8 && off >= sizes[seg]) { off -= sizes[seg]; seg++; }
  if (seg >= 8) return;
  float v = f32 ? ((const float*)s.p[seg])[off] : bf2f(((const u16*)s.p[seg])[off]);
  dst[gid] = f2bf(v);
}

// final: out[j*inRows+i] += transposed bf16 tin; out dtype per flag
__global__ __launch_bounds__(256) void transpose_add_out(
    const u16* __restrict__ tin, void* outv, long oOff,
    const int* __restrict__ flagp, int inRows, int inCols)
{
  const bool f32 = *flagp != 0;
  __shared__ u16 tile[32][33];
  const int bx = blockIdx.x * 32;
  const int by = blockIdx.y * 32;
  const int tx = threadIdx.x & 31;
  const int ty = threadIdx.x >> 5;
#pragma unroll
  for (int k = 0; k < 4; k++)
    tile[ty + k * 8][tx] = tin[(long)(by + ty + k * 8) * inCols + bx + tx];
  __syncthreads();
#pragma unroll
  for (int k = 0; k < 4; k++) {
    const int j = bx + ty + k * 8;
    const int i = by + tx;
    const long idx = (long)j * inRows + i;
    const float val = bf2f(tile[tx][ty + k * 8]);
    if (f32) {
      float* o = (float*)outv + oOff;
      o[idx] = o[idx] + val;
    } else {
      u16* o = (u16*)outv + oOff;
      o[idx] = f2bf(bf2f(o[idx]) + val);
    }
  }
}

// ---------------------------------------------------------------------------
extern "C" void kernel_launch(void* const* d_in, const int* in_sizes, int n_in,
                              void* d_out, int out_size, void* d_ws, size_t ws_size,
                              hipStream_t stream)
{
  const int N = 2304, C = 768, HD = 96, HDC = 288;
  const size_t NC = (size_t)N * C;

  const void* x    = d_in[0];
  const void* y    = d_in[1];
  const void* Wqx  = d_in[2];  const void* bqx  = d_in[3];
  const void* Wqy  = d_in[4];  const void* bqy  = d_in[5];
  const void* Wqxc = d_in[6];  const void* bqxc = d_in[7];
  const void* Wqyc = d_in[8];  const void* bqyc = d_in[9];
  const void* Wpxc = d_in[10]; const void* bpxc = d_in[11];
  const void* Wpyc = d_in[12]; const void* bpyc = d_in[13];
  const void* Wax  = d_in[14]; const void* bax  = d_in[15];
  const void* Way  = d_in[16]; const void* bay  = d_in[17];

  char* base = (char*)d_ws;
  int* flag = (int*)base;
  size_t off = 256;
  auto alloc16 = [&](size_t elems) -> u16* {
    u16* p = (u16*)(base + off);
    off = (off + elems * 2 + 255) & ~(size_t)255;
    return p;
  };

  // ---- fat-path fixed layout (all alloc sizes are 256B multiples -> pairs
  // of same-size buffers allocated back-to-back are stride-contiguous, which
  // the Z=2 batched GEMM calls below rely on) ----
  u16* WqxT  = alloc16((size_t)2304 * 768);
  u16* WqyT  = alloc16((size_t)2304 * 768);
  u16* WqxcT = alloc16((size_t)6912 * 2304);
  u16* WqycT = alloc16((size_t)6912 * 2304);
  u16* WpxcT = alloc16((size_t)2304 * 2304);
  u16* WpycT = alloc16((size_t)2304 * 2304);
  u16* WaxT  = alloc16((size_t)768 * 768);
  u16* WayT  = alloc16((size_t)768 * 768);
  u16* biasB = alloc16(24576);
  u16* xb = alloc16(NC);
  u16* yb = alloc16(NC);
  u16* RT = alloc16(2 * NC);      // xt,yt -> attx,atty -> attxc,attyc
  u16* RQ1 = alloc16(3 * NC);     // qkvxs -> qkvxc
  u16* RQ2 = alloc16(3 * NC);     // qkvys -> qkvyc
  u16* RS = alloc16(2 * NC);      // xself, yself
  u16* VT = alloc16(2 * NC);      // transposed V: spatial x/y (flash), channel reuse slot 0
  size_t fixedEnd = off;
  float* Sbuf = (float*)(base + fixedEnd);
  size_t availS = ws_size > fixedEnd ? ws_size - fixedEnd : 0;

  const size_t spHead = (size_t)N * N * 4;
  const bool fat = ws_size >= fixedEnd + spHead;

  auto G64 = [&](const void* A, int lda, long sAz, int aExt,
                 const void* B, int ldb, long sBz, int bNT, int bExt,
                 const void* bias, void* Out, int ldo, long sOz, long oOff, int outMode,
                 float scale, int M, int Nn, int K, int Z) {
    dim3 grid((Nn + BN - 1) / BN, (M + BM - 1) / BM, Z);
    gemm64<<<grid, 256, 0, stream>>>(A, lda, sAz, aExt, B, ldb, sBz, bNT, bExt,
                                     bias, Out, ldo, sOz, oOff, outMode, flag,
                                     scale, M, Nn, K);
  };
  auto G128 = [&](const u16* A, int lda, long sAz,
                  const u16* B, int ldb, long sBz,
                  const u16* bias, int sBiasZ,
                  void* Out, int ldo, long sOz, long oOff, int outMode,
                  float scale, int M, int Nn, int K, int Z) {
    dim3 grid(Nn / 128, M / 128, Z);
    gemm128<<<grid, 256, 0, stream>>>(A, lda, sAz, B, ldb, sBz, bias, sBiasZ,
                                      Out, ldo, sOz, oOff, outMode, flag,
                                      scale, M, Nn, K);
  };

  probe_dtype<<<1, 256, 0, stream>>>((const u32*)x, 1024, flag);

  if (fat) {
    transpose_in<<<dim3(2304 / 32, 768 / 32),  256, 0, stream>>>(Wqx,  WqxT,  flag, 768,  2304);
    transpose_in<<<dim3(2304 / 32, 768 / 32),  256, 0, stream>>>(Wqy,  WqyT,  flag, 768,  2304);
    transpose_in<<<dim3(6912 / 32, 2304 / 32), 256, 0, stream>>>(Wqxc, WqxcT, flag, 2304, 6912);
    transpose_in<<<dim3(6912 / 32, 2304 / 32), 256, 0, stream>>>(Wqyc, WqycT, flag, 2304, 6912);
    transpose_in<<<dim3(2304 / 32, 2304 / 32), 256, 0, stream>>>(Wpxc, WpxcT, flag, 2304, 2304);
    transpose_in<<<dim3(2304 / 32, 2304 / 32), 256, 0, stream>>>(Wpyc, WpycT, flag, 2304, 2304);
    transpose_in<<<dim3(768 / 32, 768 / 32),   256, 0, stream>>>(Wax,  WaxT,  flag, 768,  768);
    transpose_in<<<dim3(768 / 32, 768 / 32),   256, 0, stream>>>(Way,  WayT,  flag, 768,  768);
    P8 bp; bp.p[0] = bqx; bp.p[1] = bqy; bp.p[2] = bqxc; bp.p[3] = bqyc;
    bp.p[4] = bpxc; bp.p[5] = bpyc; bp.p[6] = bax; bp.p[7] = bay;
    cvt_bias<<<96, 256, 0, stream>>>(bp, biasB, flag);
    const u16 *bqxB = biasB, *bqxcB = biasB + 4608,
              *bpxcB = biasB + 18432, *baxB = biasB + 23040;
    cvt_flat<<<(unsigned)(NC / 4 / 256), 256, 0, stream>>>(x, xb, flag, (long)NC);
    cvt_flat<<<(unsigned)(NC / 4 / 256), 256, 0, stream>>>(y, yb, flag, (long)NC);
    u16 *xt = RT, *yt = RT + NC;
    transpose_in<<<dim3(N / 32, C / 32), 256, 0, stream>>>(x, xt, flag, C, N);
    transpose_in<<<dim3(N / 32, C / 32), 256, 0, stream>>>(y, yt, flag, C, N);

    // channel attention: scores gemm128 NT -> softmax -> PV gemm_pv NT
    auto attF = [&](const u16* qB, const u16* kB, const u16* vB, int ldq,
                    u16* att, int Mq, int hd, float scl) {
      // Vt[j, n] = V[n, j]; j over all 8*hd columns, ld = Mq
      transpose_v<<<dim3((8 * hd) / 32, Mq / 32), 256, 0, stream>>>(vB, ldq, VT, Mq, Mq, 8 * hd);
      const long perHead = (long)Mq * Mq * 4;
      int nb = (int)(availS / perHead);
      if (nb > 8) nb = 8;
      for (int h0 = 0; h0 < 8; h0 += nb) {
        const int zc = (8 - h0 < nb) ? 8 - h0 : nb;
        G128(qB + h0 * hd, ldq, hd, kB + h0 * hd, ldq, hd, nullptr, 0,
             Sbuf, Mq, (long)Mq * Mq, 0, 1, scl, Mq, Mq, hd, zc);
        softmax_rows<<<dim3(Mq, zc), 256, 0, stream>>>(Sbuf, Mq, (long)Mq * Mq,
            (u16*)Sbuf, 2 * Mq, (long)Mq * 2 * Mq, Mq);
        gemm_pv<<<dim3(hd / 96, Mq / 64, zc), 256, 0, stream>>>(
            (const u16*)Sbuf, 2 * Mq, (long)Mq * 2 * Mq,
            VT + (long)h0 * hd * Mq, Mq, (long)hd * Mq,
            att + (long)h0 * Mq * hd, hd, (long)Mq * hd, Mq);
      }
    };

    // ---- spatial phase ----
    // x and y batched via Z=2 (A stride NC, W stride NC, bias stride 3C, out stride 3NC)
    u16 *qkvxs = RQ1;
    G128(xt, C, (long)NC, WqxT, C, (long)NC, bqxB, 3 * C,
         qkvxs, 3 * C, 3 * (long)NC, 0, 0, 1.f, N, 3 * C, C, 2);

    // fused spatial attention (x and y in one launch; S never hits memory)
    u16 *qkvys = RQ2;
    u16 *attx = RT;
    const float sscale = 1.0f / sqrtf(96.0f);
    transpose_v<<<dim3((8 * HD) / 32, N / 32), 256, 0, stream>>>(
        qkvxs + 2 * C, 3 * C, VT, N, N, 8 * HD);
    transpose_v<<<dim3((8 * HD) / 32, N / 32), 256, 0, stream>>>(
        qkvys + 2 * C, 3 * C, VT + NC, N, N, 8 * HD);
    flashS<<<dim3(N / 128, 8, 2), 256, 0, stream>>>(
        qkvxs, 3 * (long)NC, VT, (long)NC, attx, (long)NC, 3 * C, N, sscale);

    u16 *xself = RS;
    G128(attx, C, (long)NC, WaxT, C, (long)768 * 768, baxB, C,
         xself, C, (long)NC, 0, 0, 1.f, N, C, C, 2);

    // ---- channel phase ----
    u16 *qkvxc = RQ1, *qkvyc = RQ2;
    G128(xb, N, (long)NC, WqxcT, N, (long)6912 * 2304, bqxcB, 3 * N,
         qkvxc, 3 * N, 3 * (long)NC, 0, 0, 1.f, C, 3 * N, N, 2);

    u16 *attxc = RT, *attyc = RT + NC;
    const float cscale = 1.0f / sqrtf(288.0f);
    attF(qkvxc, qkvyc + N, qkvyc + 2 * N, 3 * N, attxc, C, HDC, cscale);
    attF(qkvyc, qkvxc + N, qkvxc + 2 * N, 3 * N, attyc, C, HDC, cscale);

    G128(attxc, N, (long)NC, WpxcT, N, (long)2304 * 2304, bpxcB, N,
         d_out, N, (long)NC, 0, 2, 1.f, C, N, N, 2);

    transpose_add_out<<<dim3(C / 32, N / 32), 256, 0, stream>>>(xself, d_out, 0, flag, N, C);
    transpose_add_out<<<dim3(C / 32, N / 32), 256, 0, stream>>>(RS + NC, d_out, (long)NC, flag, N, C);
    return;
  }

  // ================= fallback: round-3 verified path =================
  {
    char* b2 = (char*)d_ws;
    u16* RA = (u16*)(b2 + 256);
    u16* RB = RA + 3 * NC;
    u16* RD = RB + 3 * NC;
    u16* RE = RD + 2 * NC;
    const size_t offSsp = 256 + (size_t)(8 * NC) * 2;
    float* Ssp = (float*)(b2 + offSsp);
    const size_t availSp = ws_size > offSsp ? ws_size - offSsp : 0;
    const size_t offSch = 256 + (size_t)(10 * NC) * 2;
    float* Sch = (float*)(b2 + offSch);
    const size_t availCh = ws_size > offSch ? ws_size - offSch : 0;

    u16 *xt = RD, *yt = RD + NC;
    u16 *qkvxs = RA, *qkvys = RB;
    u16 *attx = RD, *atty = RD + NC;
    u16 *xself = RE, *yself = RE + NC;
    u16 *qkvxc = RA, *qkvyc = RB;
    u16 *attxc = RD, *attyc = RD + NC;

    auto attention = [&](const u16* qB, const u16* kB, const u16* vB, int ldq,
                         u16* att, int Mq, int hd, float scl,
                         float* S, size_t availBytes) {
      const long perHead = (long)Mq * Mq * 4;
      int nb = (int)(availBytes / perHead);
      if (nb > 8) nb = 8;
      if (nb >= 1) {
        for (int h0 = 0; h0 < 8; h0 += nb) {
          const int zc = (8 - h0 < nb) ? 8 - h0 : nb;
          G64(qB + h0 * hd, ldq, hd, 0, kB + h0 * hd, ldq, hd, 1, 0, nullptr,
              S, Mq, (long)Mq * Mq, 0, 1, scl, Mq, Mq, hd, zc);
          softmax_rows<<<dim3(Mq, zc), 256, 0, stream>>>(S, Mq, (long)Mq * Mq,
              (u16*)S, 2 * Mq, (long)Mq * 2 * Mq, Mq);
          G64((const u16*)S, 2 * Mq, (long)Mq * 2 * Mq, 0, vB + h0 * hd, ldq, hd, 0, 0,
              nullptr, att + (long)h0 * Mq * hd, hd, (long)Mq * hd, 0, 0,
              1.f, Mq, hd, Mq, zc);
        }
      } else {
        long rows = (long)(availBytes / ((size_t)Mq * 4)) & ~63L;
        if (rows < 64) rows = 64;
        if (rows > Mq) rows = Mq;
        for (int h = 0; h < 8; h++) {
          for (int m0 = 0; m0 < Mq; m0 += (int)rows) {
            const int mr = (Mq - m0 < rows) ? (int)(Mq - m0) : (int)rows;
            G64(qB + (long)m0 * ldq + h * hd, ldq, 0, 0, kB + h * hd, ldq, 0, 1, 0,
                nullptr, S, Mq, 0, 0, 1, scl, mr, Mq, hd, 1);
            softmax_rows<<<dim3(mr, 1), 256, 0, stream>>>(S, Mq, 0, (u16*)S, 2 * Mq, 0, Mq);
            G64((const u16*)S, 2 * Mq, 0, 0, vB + h * hd, ldq, 0, 0, 0, nullptr,
                att + (long)h * Mq * hd + (long)m0 * hd, hd, 0, 0, 0, 1.f, mr, hd, Mq, 1);
          }
        }
      }
    };

    transpose_in<<<dim3(N / 32, C / 32), 256, 0, stream>>>(x, xt, flag, C, N);
    transpose_in<<<dim3(N / 32, C / 32), 256, 0, stream>>>(y, yt, flag, C, N);

    G64(xt, C, 0, 0, Wqx, 3 * C, 0, 0, 1, bqx, qkvxs, 3 * C, 0, 0, 0, 1.f, N, 3 * C, C, 1);
    G64(yt, C, 0, 0, Wqy, 3 * C, 0, 0, 1, bqy, qkvys, 3 * C, 0, 0, 0, 1.f, N, 3 * C, C, 1);

    const float sscale = 1.0f / sqrtf(96.0f);
    attention(qkvxs, qkvxs + C, qkvxs + 2 * C, 3 * C, attx, N, HD, sscale, Ssp, availSp);
    attention(qkvys, qkvys + C, qkvys + 2 * C, 3 * C, atty, N, HD, sscale, Ssp, availSp);

    G64(attx, C, 0, 0, Wax, C, 0, 0, 1, bax, xself, C, 0, 0, 0, 1.f, N, C, C, 1);
    G64(atty, C, 0, 0, Way, C, 0, 0, 1, bay, yself, C, 0, 0, 0, 1.f, N, C, C, 1);

    G64(x, N, 0, 1, Wqxc, 3 * N, 0, 0, 1, bqxc, qkvxc, 3 * N, 0, 0, 0, 1.f, C, 3 * N, N, 1);
    G64(y, N, 0, 1, Wqyc, 3 * N, 0, 0, 1, bqyc, qkvyc, 3 * N, 0, 0, 0, 1.f, C, 3 * N, N, 1);

    const float cscale = 1.0f / sqrtf(288.0f);
    attention(qkvxc, qkvyc + N, qkvyc + 2 * N, 3 * N, attxc, C, HDC, cscale, Sch, availCh);
    attention(qkvyc, qkvxc + N, qkvxc + 2 * N, 3 * N, attyc, C, HDC, cscale, Sch, availCh);

    G64(attxc, N, 0, 0, Wpxc, N, 0, 0, 1, bpxc, d_out, N, 0, 0, 2, 1.f, C, N, N, 1);
    G64(attyc, N, 0, 0, Wpyc, N, 0, 0, 1, bpyc, d_out, N, 0, (long)NC, 2, 1.f, C, N, N, 1);

    transpose_add_out<<<dim3(C / 32, N / 32), 256, 0, stream>>>(xself, d_out, 0, flag, N, C);
    transpose_add_out<<<dim3(C / 32, N / 32), 256, 0, stream>>>(yself, d_out, (long)NC, flag, N, C);
  }
}

// Round 6
// 696.029 us; speedup vs baseline: 1.5540x; 1.0266x over previous
//
#include <hip/hip_runtime.h>
#include <math.h>

typedef unsigned short u16;
typedef unsigned int u32;
typedef short bf16x8 __attribute__((ext_vector_type(8)));
typedef float f32x4 __attribute__((ext_vector_type(4)));
typedef float f32x16 __attribute__((ext_vector_type(16)));

__device__ __forceinline__ float bf2f(u16 u) {
  union { unsigned int i; float f; } v;
  v.i = ((unsigned int)u) << 16;
  return v.f;
}
__device__ __forceinline__ u16 f2bf(float f) {
  union { float f; unsigned int i; } v;
  v.f = f;
  unsigned int u = v.i;
  return (u16)((u + 0x7fffu + ((u >> 16) & 1u)) >> 16);
}
// pack two f32 -> two bf16 in one u32 (lo = a, hi = b)
__device__ __forceinline__ u32 pkbf(float a, float b) {
  u32 d;
  asm("v_cvt_pk_bf16_f32 %0, %1, %2" : "=v"(d) : "v"(a), "v"(b));
  return d;
}

// async global->LDS, 16B per lane. LDS dest = wave-uniform base + lane*16.
__device__ __forceinline__ void glds16(const u16* g, u16* l) {
  __builtin_amdgcn_global_load_lds(
      (const __attribute__((address_space(1))) void*)g,
      (__attribute__((address_space(3))) void*)l, 16, 0, 0);
}

// ---------------------------------------------------------------------------
// dtype probe: fp32(1) vs bf16(0) from bit statistics of x.
// ---------------------------------------------------------------------------
__global__ __launch_bounds__(256) void probe_dtype(const u32* __restrict__ xw,
                                                   int nwords, int* flag)
{
  const int tid = threadIdx.x;
  int cnt = 0;
  for (int i = tid; i < nwords; i += 256) {
    u32 w = xw[i];
    u32 e = (w >> 7) & 0xFFu;
    if (e >= 110u && e <= 140u) cnt++;
  }
#pragma unroll
  for (int off = 32; off >= 1; off >>= 1) cnt += __shfl_xor(cnt, off);
  __shared__ int s[4];
  if ((tid & 63) == 0) s[tid >> 6] = cnt;
  __syncthreads();
  if (tid == 0) {
    int tot = s[0] + s[1] + s[2] + s[3];
    flag[0] = (tot < nwords / 2) ? 1 : 0;
  }
}

// ---------------------------------------------------------------------------
// gemm128: 128x128 tile, BK=32, NT-only, all-bf16 inputs, glds staging.
// Double-buffered 2-phase pipeline: stage tile t+1 while computing tile t.
// Out[m,n] = scale * sum_k A[m,k] * B[n,k] + bias[n + z*sBiasZ]
// ---------------------------------------------------------------------------
__global__ __launch_bounds__(256) void gemm128(
    const u16* __restrict__ A, int lda, long sAz,
    const u16* __restrict__ B, int ldb, long sBz,
    const u16* __restrict__ bias, int sBiasZ,
    void* __restrict__ OutV, int ldo, long sOz, long oOff, int outMode,
    const int* __restrict__ flagp,
    float scale, int M, int Nn, int K)
{
  const int z = blockIdx.z;
  const u16* Ab = A + (long)z * sAz;
  const u16* Bb = B + (long)z * sBz;
  const int bm = blockIdx.y * 128;
  const int bn = blockIdx.x * 128;

  __shared__ u16 As[2][128 * 32];
  __shared__ u16 Bs[2][128 * 32];

  const int tid  = threadIdx.x;
  const int lane = tid & 63;
  const int wave = tid >> 6;
  const int wr = wave >> 1, wc = wave & 1;
  const int q = lane >> 4, l15 = lane & 15;

  f32x4 acc[4][4];
#pragma unroll
  for (int i = 0; i < 4; i++)
#pragma unroll
    for (int j = 0; j < 4; j++) acc[i][j] = (f32x4){0.f, 0.f, 0.f, 0.f};

  const int srow = tid >> 2;
  const int sc8  = (tid & 3) * 8;
  const u16* aptr = Ab + (long)(bm + srow) * lda + sc8;
  const u16* bptr = Bb + (long)(bn + srow) * ldb + sc8;

  auto stage = [&](int buf, int k0) {
    u16* asl = As[buf] + tid * 8;
    u16* bsl = Bs[buf] + tid * 8;
    glds16(aptr + k0, asl);
    glds16(aptr + (long)64 * lda + k0, asl + 256 * 8);
    glds16(bptr + k0, bsl);
    glds16(bptr + (long)64 * ldb + k0, bsl + 256 * 8);
  };
  auto compute = [&](int buf) {
    bf16x8 af[4], bfr[4];
#pragma unroll
    for (int mi = 0; mi < 4; mi++)
      af[mi] = *(const bf16x8*)(As[buf] + (wr * 64 + mi * 16 + l15) * 32 + q * 8);
#pragma unroll
    for (int nj = 0; nj < 4; nj++)
      bfr[nj] = *(const bf16x8*)(Bs[buf] + (wc * 64 + nj * 16 + l15) * 32 + q * 8);
#pragma unroll
    for (int mi = 0; mi < 4; mi++)
#pragma unroll
      for (int nj = 0; nj < 4; nj++)
        acc[mi][nj] = __builtin_amdgcn_mfma_f32_16x16x32_bf16(af[mi], bfr[nj], acc[mi][nj], 0, 0, 0);
  };

  // prologue: stage tile 0, drain, then pipeline.
  stage(0, 0);
  __syncthreads();           // emits s_waitcnt vmcnt(0) lgkmcnt(0) + s_barrier
  int cur = 0;
  for (int k0 = 32; k0 < K; k0 += 32) {
    stage(cur ^ 1, k0);      // next tile's loads fly during current compute
    compute(cur);
    __syncthreads();
    cur ^= 1;
  }
  compute(cur);

  const int flagv = (outMode == 2) ? *flagp : 0;
  const bool storeF32 = (outMode == 1) || (outMode == 2 && flagv);
  const u16* bz = bias ? bias + (long)z * sBiasZ : nullptr;
#pragma unroll
  for (int mi = 0; mi < 4; mi++) {
    const int r0 = bm + wr * 64 + mi * 16 + q * 4;
#pragma unroll
    for (int nj = 0; nj < 4; nj++) {
      const int col = bn + wc * 64 + nj * 16 + l15;
      const float bsv = bz ? bf2f(bz[col]) : 0.0f;
      if (storeF32) {
        float* Out = (float*)OutV + oOff + (long)z * sOz;
#pragma unroll
        for (int r = 0; r < 4; r++)
          Out[(long)(r0 + r) * ldo + col] = acc[mi][nj][r] * scale + bsv;
      } else {
        u16* Out = (u16*)OutV + oOff + (long)z * sOz;
#pragma unroll
        for (int r = 0; r < 4; r++)
          Out[(long)(r0 + r) * ldo + col] = f2bf(acc[mi][nj][r] * scale + bsv);
      }
    }
  }
}

// ---------------------------------------------------------------------------
// flashS v2: fused spatial attention, hd=96, 32x32 swapped-operand structure
// with WAVE-PAIR KV-SPLIT for occupancy (round-4 was 1.1 block/CU, occ 6%).
//  - block = 64 q-rows, 4 waves. Wave-pair p in {0,1} handles keys
//    [p*Mq/2, (p+1)*Mq/2) with its own dbuf K/V LDS (KVBLK=32).
//    grid = (Mq/64, 8, 2) = 576 blocks; LDS 64KB -> 2 blocks/CU.
//  - S^T = mfma32(K, Q): lane owns P-row for q=lane&31 (C-layout
//    col=lane&31, row=(reg&3)+8*(reg>>2)+4*(lane>>5) -- m74/m101 verified).
//  - QK^T split into two 3-deep chains (summed) to cut MFMA latency chain.
//  - softmax: 16 local fmax + one shfl_xor(32); defer-max THR=8 (T13).
//  - P -> PV A-frags in-register via cvt_pk + permlane32_swap (T12).
//  - K [32][128] gran^= (row&7); V [96][40] gran ^= (row&3); staged by
//    glds16 with PRE-SWIZZLED global source (m173), dbuf 2-phase.
//  - end: in-LDS merge of the two kv-split partials (m,l,O); no extra
//    global traffic. Waves 0,1 store the merged/normalized output.
// ---------------------------------------------------------------------------
__global__ __launch_bounds__(256) void flashS(
    const u16* __restrict__ QKV, long sTz,   // q at col h*96; k at col 768+h*96
    const u16* __restrict__ VTb, long sVz,   // Vt [768][Mq] per tensor
    u16* __restrict__ Out, long sOz,         // att + h*Mq*96 + q*96 + d
    int ldq, int Mq, float scl)
{
  const int bm = blockIdx.x * 64;
  const int h  = blockIdx.y;
  const int t  = blockIdx.z;
  const int h96 = h * 96;
  const u16* qB  = QKV + (long)t * sTz;
  const u16* kB  = qB + 768;
  const u16* vtB = VTb + (long)t * sVz + (long)h96 * Mq;
  u16* oB = Out + (long)t * sOz + (long)h * Mq * 96;

  // per pair (16384 u16): K 2 bufs x 4096 ([32][128]); V 2 bufs x 4096 ([96][40]+pad)
  __shared__ u16 SH[2 * 16384];

  const int tid  = threadIdx.x;
  const int lane = tid & 63;
  const int wave = tid >> 6;
  const int l31  = lane & 31;
  const int hi   = lane >> 5;
  const int wp   = wave >> 1;    // kv-split half
  const int wq   = wave & 1;     // q 32-row group
  const int ptid = tid & 127;
  u16* PB = SH + wp * 16384;
  const int kst = wp * (Mq >> 1);

  // ---- Q fragments, hoisted + pre-scaled (ref scales Q before matmul) ----
  bf16x8 qf[6];
  {
    const u16* qrow = qB + (long)(bm + wq * 32 + l31) * ldq + h96;
#pragma unroll
    for (int cs = 0; cs < 6; cs++) {
      union { bf16x8 v; u16 e[8]; } a, b;
      a.v = *(const bf16x8*)(qrow + cs * 16 + hi * 8);
#pragma unroll
      for (int e = 0; e < 8; e++) b.e[e] = f2bf(bf2f(a.e[e]) * scl);
      qf[cs] = b.v;
    }
  }

  f32x16 accO[3];
#pragma unroll
  for (int r = 0; r < 16; r++) { accO[0][r] = 0.f; accO[1][r] = 0.f; accO[2][r] = 0.f; }
  float m_r = -1e30f, l_r = 0.f;

  // stage with pre-swizzled global source: LDS slot gi holds key/col group
  // gi^(row&mask); read of group c comes from slot c^(row&mask).
  auto stageKV = [&](int buf, int k0) {
    const u16* kBase = kB + (long)k0 * ldq + h96;
    u16* kd = PB + buf * 4096;
#pragma unroll
    for (int i = 0; i < 4; i++) {
      const int G = ptid + 128 * i;            // 0..511
      const int row = G >> 4, gi = G & 15;
      const int g = gi ^ (row & 7);
      const u16* src = (g < 12) ? (kBase + (long)row * ldq + g * 8) : kB;
      glds16(src, kd + G * 8);
    }
    const u16* vBase = vtB + k0;
    u16* vd = PB + 8192 + buf * 4096;
#pragma unroll
    for (int i = 0; i < 4; i++) {
      const int G = ptid + 128 * i;            // 0..511 (480..511 pad)
      const int row = G / 5, gi = G - row * 5;
      const bool ok = (G < 480) && (gi < 4);
      const u16* src = ok ? (vBase + (long)row * Mq + (long)(gi ^ (row & 3)) * 8) : vtB;
      glds16(src, vd + G * 8);
    }
  };
  auto ldK = [&](int buf, int cs) -> bf16x8 {
    const int g = (2 * cs + hi) ^ (l31 & 7);
    return *(const bf16x8*)(PB + buf * 4096 + l31 * 128 + g * 8);
  };
  auto ldV = [&](int buf, int dt, int s) -> bf16x8 {
    const int row = dt * 32 + l31;
    const int g = (2 * s + hi) ^ (row & 3);
    return *(const bf16x8*)(PB + 8192 + buf * 4096 + row * 40 + g * 8);
  };

  stageKV(0, kst);
  __syncthreads();
  int cur = 0;
  const int nt = Mq >> 6;                      // (Mq/2)/32
  for (int kt = 0; kt < nt; kt++) {
    if (kt + 1 < nt) stageKV(cur ^ 1, kst + (kt + 1) * 32);  // flies under compute

    // ---- S^T = K Q^T, two 3-deep chains summed ----
    f32x16 s1, s2;
#pragma unroll
    for (int r = 0; r < 16; r++) { s1[r] = 0.f; s2[r] = 0.f; }
    __builtin_amdgcn_s_setprio(1);
#pragma unroll
    for (int cs = 0; cs < 3; cs++) {
      s1 = __builtin_amdgcn_mfma_f32_32x32x16_bf16(ldK(cur, 2 * cs),     qf[2 * cs],     s1, 0, 0, 0);
      s2 = __builtin_amdgcn_mfma_f32_32x32x16_bf16(ldK(cur, 2 * cs + 1), qf[2 * cs + 1], s2, 0, 0, 0);
    }
    __builtin_amdgcn_s_setprio(0);
    f32x16 sA;
#pragma unroll
    for (int r = 0; r < 16; r++) sA[r] = s1[r] + s2[r];

    // ---- online softmax: local + one cross-half shfl ----
    float tm = -1e30f;
#pragma unroll
    for (int r = 0; r < 16; r++) tm = fmaxf(tm, sA[r]);
    tm = fmaxf(tm, __shfl_xor(tm, 32));
    if (!__all(tm <= m_r + 8.f)) {            // defer-max (T13)
      const float mn = fmaxf(m_r, tm);
      const float al = __expf(m_r - mn);
      m_r = mn; l_r *= al;
#pragma unroll
      for (int r = 0; r < 16; r++) {
        const float a = __shfl(al, (r & 3) + 8 * (r >> 2) + 4 * hi);
        accO[0][r] *= a; accO[1][r] *= a; accO[2][r] *= a;
      }
    }
    float rs = 0.f;
#pragma unroll
    for (int r = 0; r < 16; r++) { sA[r] = __expf(sA[r] - m_r); rs += sA[r]; }
    rs += __shfl_xor(rs, 32);
    l_r += rs;

    // ---- PV: A-frags built in-register (cvt_pk + permlane32_swap) ----
#pragma unroll
    for (int s = 0; s < 2; s++) {
      const int rb = s * 8;
      u32 X  = pkbf(sA[rb + 0], sA[rb + 1]);
      u32 X2 = pkbf(sA[rb + 2], sA[rb + 3]);
      u32 Y  = pkbf(sA[rb + 4], sA[rb + 5]);
      u32 Y2 = pkbf(sA[rb + 6], sA[rb + 7]);
      asm volatile("v_permlane32_swap_b32 %0, %1" : "+v"(X), "+v"(Y));
      asm volatile("v_permlane32_swap_b32 %0, %1" : "+v"(X2), "+v"(Y2));
      union { u32 w[4]; bf16x8 v; } pa;
      pa.w[0] = X; pa.w[1] = X2; pa.w[2] = Y; pa.w[3] = Y2;
      __builtin_amdgcn_s_setprio(1);
#pragma unroll
      for (int dt = 0; dt < 3; dt++)
        accO[dt] = __builtin_amdgcn_mfma_f32_32x32x16_bf16(pa.v, ldV(cur, dt, s), accO[dt], 0, 0, 0);
      __builtin_amdgcn_s_setprio(0);
    }

    __syncthreads();     // stage visible + all reads of cur done
    cur ^= 1;
  }

  // ---- in-LDS merge of kv-split partials; waves 0,1 store ----
  float* fsh = (float*)SH;
  const int MLOFF = 128 * 49;                  // acc area: 128 lanes x 49 floats
  if (wp == 1) {
    float* ab = fsh + (wq * 64 + lane) * 49;
#pragma unroll
    for (int dt = 0; dt < 3; dt++)
#pragma unroll
      for (int r = 0; r < 16; r++) ab[dt * 16 + r] = accO[dt][r];
    fsh[MLOFF + wq * 64 + lane] = m_r;
    fsh[MLOFF + 128 + wq * 64 + lane] = l_r;
  }
  __syncthreads();
  if (wp == 0) {
    const float m2 = fsh[MLOFF + wq * 64 + lane];
    const float l2 = fsh[MLOFF + 128 + wq * 64 + lane];
    const float mm = fmaxf(m_r, m2);
    const float a1 = __expf(m_r - mm);
    const float a2 = __expf(m2 - mm);
    const float inv = 1.0f / (l_r * a1 + l2 * a2);
    const float* ab = fsh + (wq * 64 + lane) * 49;
#pragma unroll
    for (int r = 0; r < 16; r++) {
      const int row = (r & 3) + 8 * (r >> 2) + 4 * hi;
      const float f1 = __shfl(a1 * inv, row);
      const float f2 = __shfl(a2 * inv, row);
      const long rowb = (long)(bm + wq * 32 + row) * 96;
#pragma unroll
      for (int dt = 0; dt < 3; dt++)
        oB[rowb + dt * 32 + l31] = f2bf(accO[dt][r] * f1 + ab[dt * 16 + r] * f2);
    }
  }
}

// ---------------------------------------------------------------------------
// gemm_pv: PV-shaped NT GEMM. Out[m, bn+c] = sum_k P[m,k] * Vt[bn+c, k].
// BM=64, BN=96 (exact head width unit), BK=32, glds staging, bf16 out.
// Double-buffered 2-phase pipeline.
// grid = (hd/96, M/64, nheads); K = Mq. All dims: M%64, K%32, lds %8.
// ---------------------------------------------------------------------------
__global__ __launch_bounds__(256) void gemm_pv(
    const u16* __restrict__ P, int ldP, long sPz,
    const u16* __restrict__ Vt, int ldVt, long sVz,
    u16* __restrict__ Out, int ldo, long sOz, int K)
{
  const int z = blockIdx.z;
  const u16* Pz = P + (long)z * sPz;
  const u16* Vz = Vt + (long)z * sVz;
  u16* Oz = Out + (long)z * sOz;
  const int bm = blockIdx.y * 64;
  const int bn = blockIdx.x * 96;

  __shared__ u16 As[2][64 * 32];   // [64][32]
  __shared__ u16 Bs[2][96 * 32];   // [96][32] (rows = output cols)

  const int tid  = threadIdx.x;
  const int lane = tid & 63;
  const int wave = tid >> 6;
  const int wr = wave >> 1, wc = wave & 1;
  const int q = lane >> 4, l15 = lane & 15;

  f32x4 acc[2][3];
#pragma unroll
  for (int i = 0; i < 2; i++)
#pragma unroll
    for (int j = 0; j < 3; j++) acc[i][j] = (f32x4){0.f, 0.f, 0.f, 0.f};

  const int srow = lane >> 2;        // 0..15
  const int sc8  = (lane & 3) * 8;   // 0,8,16,24

  // A: 4 chunks of 16 rows; wave w stages chunk w.
  const u16* aRow = Pz + (long)(bm + wave * 16 + srow) * ldP + sc8;
  // B: 6 chunks of 16 rows; waves 0..2 stage chunks 2w, 2w+1.
  const u16* bRow0 = nullptr; const u16* bRow1 = nullptr;
  if (wave < 3) {
    bRow0 = Vz + (long)(bn + (2 * wave) * 16 + srow) * ldVt + sc8;
    bRow1 = Vz + (long)(bn + (2 * wave + 1) * 16 + srow) * ldVt + sc8;
  }

  auto stage = [&](int buf, int k0) {
    glds16(aRow + k0, As[buf] + wave * 512 + lane * 8);
    if (wave < 3) {
      glds16(bRow0 + k0, Bs[buf] + (2 * wave) * 512 + lane * 8);
      glds16(bRow1 + k0, Bs[buf] + (2 * wave + 1) * 512 + lane * 8);
    }
  };
  auto compute = [&](int buf) {
    bf16x8 af[2], bfr[3];
#pragma unroll
    for (int mi = 0; mi < 2; mi++)
      af[mi] = *(const bf16x8*)(As[buf] + (wr * 32 + mi * 16 + l15) * 32 + q * 8);
#pragma unroll
    for (int nj = 0; nj < 3; nj++)
      bfr[nj] = *(const bf16x8*)(Bs[buf] + (wc * 48 + nj * 16 + l15) * 32 + q * 8);
#pragma unroll
    for (int mi = 0; mi < 2; mi++)
#pragma unroll
      for (int nj = 0; nj < 3; nj++)
        acc[mi][nj] = __builtin_amdgcn_mfma_f32_16x16x32_bf16(af[mi], bfr[nj], acc[mi][nj], 0, 0, 0);
  };

  stage(0, 0);
  __syncthreads();
  int cur = 0;
  for (int k0 = 32; k0 < K; k0 += 32) {
    stage(cur ^ 1, k0);
    compute(cur);
    __syncthreads();
    cur ^= 1;
  }
  compute(cur);

#pragma unroll
  for (int mi = 0; mi < 2; mi++) {
    const int r0 = bm + wr * 32 + mi * 16 + q * 4;
#pragma unroll
    for (int nj = 0; nj < 3; nj++) {
      const int cl = bn + wc * 48 + nj * 16 + l15;
#pragma unroll
      for (int r = 0; r < 4; r++)
        Oz[(long)(r0 + r) * ldo + cl] = f2bf(acc[mi][nj][r]);
    }
  }
}

// ---------------------------------------------------------------------------
// Generic 64x64 MFMA bf16 GEMM (round-3 verified; fallback path only).
// ---------------------------------------------------------------------------
#define BM 64
#define BN 64
#define BK 32
#define LDSP (BK + 8)

__global__ __launch_bounds__(256) void gemm64(
    const void* __restrict__ Av, int lda, long sAz, int aExt,
    const void* __restrict__ Bv, int ldb, long sBz, int bNT, int bExt,
    const void* __restrict__ biasv,
    void* __restrict__ OutV, int ldo, long sOz, long oOff, int outMode,
    const int* __restrict__ flagp,
    float scale, int M, int Nn, int K)
{
  const int flagv = *flagp;
  const bool aF32 = aExt && flagv;
  const bool bF32 = bExt && flagv;

  const int z = blockIdx.z;
  const int bm = blockIdx.y * BM;
  const int bn = blockIdx.x * BN;

  __shared__ u16 As[BM][LDSP];
  __shared__ u16 Bs[BN][LDSP];

  const int tid  = threadIdx.x;
  const int lane = tid & 63;
  const int wave = tid >> 6;
  const int wr = wave >> 1;
  const int wc = wave & 1;
  const int q   = lane >> 4;
  const int l15 = lane & 15;

  f32x4 acc[2][2];
#pragma unroll
  for (int i = 0; i < 2; i++)
#pragma unroll
    for (int j = 0; j < 2; j++) acc[i][j] = (f32x4){0.f, 0.f, 0.f, 0.f};

  const int am  = tid >> 2;
  const int ach = (tid & 3) * 8;

  for (int k0 = 0; k0 < K; k0 += BK) {
    __syncthreads();
    if (aF32) {
      const float* src = (const float*)Av + (long)z * sAz + (long)(bm + am) * lda + (k0 + ach);
      f32x4 f0 = *(const f32x4*)src;
      f32x4 f1 = *(const f32x4*)(src + 4);
      u16 t[8] = {f2bf(f0[0]), f2bf(f0[1]), f2bf(f0[2]), f2bf(f0[3]),
                  f2bf(f1[0]), f2bf(f1[1]), f2bf(f1[2]), f2bf(f1[3])};
      *(uint4*)(&As[am][ach]) = *(const uint4*)t;
    } else {
      const u16* src = (const u16*)Av + (long)z * sAz + (long)(bm + am) * lda + (k0 + ach);
      *(uint4*)(&As[am][ach]) = *(const uint4*)src;
    }
    if (bNT) {
      if (bF32) {
        u16 t[8] = {0, 0, 0, 0, 0, 0, 0, 0};
        if (bn + am < Nn) {
          const float* src = (const float*)Bv + (long)z * sBz + (long)(bn + am) * ldb + (k0 + ach);
          f32x4 f0 = *(const f32x4*)src;
          f32x4 f1 = *(const f32x4*)(src + 4);
#pragma unroll
          for (int j = 0; j < 4; j++) { t[j] = f2bf(f0[j]); t[4 + j] = f2bf(f1[j]); }
        }
        *(uint4*)(&Bs[am][ach]) = *(const uint4*)t;
      } else {
        uint4 val = make_uint4(0u, 0u, 0u, 0u);
        if (bn + am < Nn)
          val = *(const uint4*)((const u16*)Bv + (long)z * sBz + (long)(bn + am) * ldb + (k0 + ach));
        *(uint4*)(&Bs[am][ach]) = val;
      }
    } else {
      const int kk = tid >> 3;
      const int n0 = (tid & 7) * 8;
      if (bn + n0 < Nn) {
        if (bF32) {
          const float* src = (const float*)Bv + (long)z * sBz + (long)(k0 + kk) * ldb + (bn + n0);
          f32x4 f0 = *(const f32x4*)src;
          f32x4 f1 = *(const f32x4*)(src + 4);
#pragma unroll
          for (int j = 0; j < 4; j++) {
            Bs[n0 + j][kk] = f2bf(f0[j]);
            Bs[n0 + 4 + j][kk] = f2bf(f1[j]);
          }
        } else {
          uint4 val = *(const uint4*)((const u16*)Bv + (long)z * sBz + (long)(k0 + kk) * ldb + (bn + n0));
          const u16* pv = (const u16*)&val;
#pragma unroll
          for (int j = 0; j < 8; j++) Bs[n0 + j][kk] = pv[j];
        }
      } else {
#pragma unroll
        for (int j = 0; j < 8; j++) Bs[n0 + j][kk] = 0;
      }
    }
    __syncthreads();

    bf16x8 af[2], bfr[2];
#pragma unroll
    for (int t = 0; t < 2; t++)
      af[t] = *(const bf16x8*)(&As[wr * 32 + t * 16 + l15][q * 8]);
#pragma unroll
    for (int t = 0; t < 2; t++)
      bfr[t] = *(const bf16x8*)(&Bs[wc * 32 + t * 16 + l15][q * 8]);
#pragma unroll
    for (int i = 0; i < 2; i++)
#pragma unroll
      for (int j = 0; j < 2; j++)
        acc[i][j] = __builtin_amdgcn_mfma_f32_16x16x32_bf16(af[i], bfr[j], acc[i][j], 0, 0, 0);
  }

#pragma unroll
  for (int i = 0; i < 2; i++) {
    const int r0 = bm + wr * 32 + i * 16 + q * 4;
#pragma unroll
    for (int j = 0; j < 2; j++) {
      const int col = bn + wc * 32 + j * 16 + l15;
      if (col >= Nn) continue;
      float bsv = 0.0f;
      if (biasv) bsv = flagv ? ((const float*)biasv)[col] : bf2f(((const u16*)biasv)[col]);
      const bool storeF32 = (outMode == 1) || (outMode == 2 && flagv);
      if (storeF32) {
        float* Out = (float*)OutV + oOff + (long)z * sOz;
#pragma unroll
        for (int r = 0; r < 4; r++)
          Out[(long)(r0 + r) * ldo + col] = acc[i][j][r] * scale + bsv;
      } else {
        u16* Out = (u16*)OutV + oOff + (long)z * sOz;
#pragma unroll
        for (int r = 0; r < 4; r++)
          Out[(long)(r0 + r) * ldo + col] = f2bf(acc[i][j][r] * scale + bsv);
      }
    }
  }
}

// ---------------------------------------------------------------------------
// Row softmax: fp32 scores row -> bf16 probabilities; P aliases S (in-place).
// ---------------------------------------------------------------------------
__global__ __launch_bounds__(256) void softmax_rows(
    float* S, int ldS, long sSz,
    u16* P, int ldP, long sPz, int ncols)
{
  const int row = blockIdx.x;
  const int z = blockIdx.y;
  float* s = S + (long)z * sSz + (long)row * ldS;
  u16*   p = P + (long)z * sPz + (long)row * ldP;
  const int tid = threadIdx.x;
  const int lane = tid & 63, wave = tid >> 6;

  float v[9];
  int cnt = 0;
  float mx = -1e30f;
  for (int c = tid; c < ncols; c += 256) {
    float t = s[c];
    v[cnt++] = t;
    mx = fmaxf(mx, t);
  }
#pragma unroll
  for (int off = 32; off >= 1; off >>= 1) mx = fmaxf(mx, __shfl_xor(mx, off));
  __shared__ float redm[4];
  __shared__ float reds[4];
  if (lane == 0) redm[wave] = mx;
  __syncthreads();
  mx = fmaxf(fmaxf(redm[0], redm[1]), fmaxf(redm[2], redm[3]));

  float sum = 0.f;
  for (int i = 0; i < cnt; i++) { v[i] = __expf(v[i] - mx); sum += v[i]; }
#pragma unroll
  for (int off = 32; off >= 1; off >>= 1) sum += __shfl_xor(sum, off);
  if (lane == 0) reds[wave] = sum;
  __syncthreads();
  sum = reds[0] + reds[1] + reds[2] + reds[3];
  const float inv = 1.0f / sum;

  cnt = 0;
  for (int c = tid; c < ncols; c += 256) p[c] = f2bf(v[cnt++] * inv);
}

// ---------------------------------------------------------------------------
// transpose_in: outp[j*inRows+i] = (bf16) tin[i*inCols+j]; tin dtype per flag
// ---------------------------------------------------------------------------
__global__ __launch_bounds__(256) void transpose_in(
    const void* __restrict__ tinv, u16* __restrict__ outp,
    const int* __restrict__ flagp, int inRows, int inCols)
{
  const bool f32 = *flagp != 0;
  __shared__ u16 tile[32][33];
  const int bx = blockIdx.x * 32;
  const int by = blockIdx.y * 32;
  const int tx = threadIdx.x & 31;
  const int ty = threadIdx.x >> 5;
#pragma unroll
  for (int k = 0; k < 4; k++) {
    const long idx = (long)(by + ty + k * 8) * inCols + bx + tx;
    tile[ty + k * 8][tx] = f32 ? f2bf(((const float*)tinv)[idx]) : ((const u16*)tinv)[idx];
  }
  __syncthreads();
#pragma unroll
  for (int k = 0; k < 4; k++) {
    const int j = bx + ty + k * 8;
    const int i = by + tx;
    outp[(long)j * inRows + i] = tile[tx][ty + k * 8];
  }
}

// ---------------------------------------------------------------------------
// transpose_v: bf16 strided transpose. dst[j*lddst+n] = src[n*ldsrc+j]
// rows%32==0, cols%32==0. grid(cols/32, rows/32).
// ---------------------------------------------------------------------------
__global__ __launch_bounds__(256) void transpose_v(
    const u16* __restrict__ src, int ldsrc,
    u16* __restrict__ dst, int lddst, int rows, int cols)
{
  __shared__ u16 tile[32][33];
  const int bx = blockIdx.x * 32;   // over cols (j)
  const int by = blockIdx.y * 32;   // over rows (n)
  const int tx = threadIdx.x & 31;
  const int ty = threadIdx.x >> 5;
#pragma unroll
  for (int k = 0; k < 4; k++)
    tile[ty + k * 8][tx] = src[(long)(by + ty + k * 8) * ldsrc + bx + tx];
  __syncthreads();
#pragma unroll
  for (int k = 0; k < 4; k++)
    dst[(long)(bx + ty + k * 8) * lddst + by + tx] = tile[tx][ty + k * 8];
}

// flat convert (n % 4 == 0)
__global__ __launch_bounds__(256) void cvt_flat(
    const void* __restrict__ src, u16* __restrict__ dst,
    const int* __restrict__ flagp, long n)
{
  const bool f32 = *flagp != 0;
  long i = ((long)blockIdx.x * 256 + threadIdx.x) * 4;
  if (i + 3 < n) {
    if (f32) {
      f32x4 v = *(const f32x4*)((const float*)src + i);
#pragma unroll
      for (int j = 0; j < 4; j++) dst[i + j] = f2bf(v[j]);
    } else {
      *(uint2*)(dst + i) = *(const uint2*)((const u16*)src + i);
    }
  }
}

struct P8 { const void* p[8]; };
__global__ __launch_bounds__(256) void cvt_bias(P8 s, u16* __restrict__ dst,
                                                const int* __restrict__ flagp)
{
  const bool f32 = *flagp != 0;
  const int sizes[8] = {2304, 2304, 6912, 6912, 2304, 2304, 768, 768};
  int gid = blockIdx.x * 256 + threadIdx.x;
  int seg = 0, off = gid;
  while (seg < 8 && off >= sizes[seg]) { off -= sizes[seg]; seg++; }
  if (seg >= 8) return;
  float v = f32 ? ((const float*)s.p[seg])[off] : bf2f(((const u16*)s.p[seg])[off]);
  dst[gid] = f2bf(v);
}

// final: out[j*inRows+i] += transposed bf16 tin; out dtype per flag
__global__ __launch_bounds__(256) void transpose_add_out(
    const u16* __restrict__ tin, void* outv, long oOff,
    const int* __restrict__ flagp, int inRows, int inCols)
{
  const bool f32 = *flagp != 0;
  __shared__ u16 tile[32][33];
  const int bx = blockIdx.x * 32;
  const int by = blockIdx.y * 32;
  const int tx = threadIdx.x & 31;
  const int ty = threadIdx.x >> 5;
#pragma unroll
  for (int k = 0; k < 4; k++)
    tile[ty + k * 8][tx] = tin[(long)(by + ty + k * 8) * inCols + bx + tx];
  __syncthreads();
#pragma unroll
  for (int k = 0; k < 4; k++) {
    const int j = bx + ty + k * 8;
    const int i = by + tx;
    const long idx = (long)j * inRows + i;
    const float val = bf2f(tile[tx][ty + k * 8]);
    if (f32) {
      float* o = (float*)outv + oOff;
      o[idx] = o[idx] + val;
    } else {
      u16* o = (u16*)outv + oOff;
      o[idx] = f2bf(bf2f(o[idx]) + val);
    }
  }
}

// ---------------------------------------------------------------------------
extern "C" void kernel_launch(void* const* d_in, const int* in_sizes, int n_in,
                              void* d_out, int out_size, void* d_ws, size_t ws_size,
                              hipStream_t stream)
{
  const int N = 2304, C = 768, HD = 96, HDC = 288;
  const size_t NC = (size_t)N * C;

  const void* x    = d_in[0];
  const void* y    = d_in[1];
  const void* Wqx  = d_in[2];  const void* bqx  = d_in[3];
  const void* Wqy  = d_in[4];  const void* bqy  = d_in[5];
  const void* Wqxc = d_in[6];  const void* bqxc = d_in[7];
  const void* Wqyc = d_in[8];  const void* bqyc = d_in[9];
  const void* Wpxc = d_in[10]; const void* bpxc = d_in[11];
  const void* Wpyc = d_in[12]; const void* bpyc = d_in[13];
  const void* Wax  = d_in[14]; const void* bax  = d_in[15];
  const void* Way  = d_in[16]; const void* bay  = d_in[17];

  char* base = (char*)d_ws;
  int* flag = (int*)base;
  size_t off = 256;
  auto alloc16 = [&](size_t elems) -> u16* {
    u16* p = (u16*)(base + off);
    off = (off + elems * 2 + 255) & ~(size_t)255;
    return p;
  };

  // ---- fat-path fixed layout (all alloc sizes are 256B multiples -> pairs
  // of same-size buffers allocated back-to-back are stride-contiguous, which
  // the Z=2 batched GEMM calls below rely on) ----
  u16* WqxT  = alloc16((size_t)2304 * 768);
  u16* WqyT  = alloc16((size_t)2304 * 768);
  u16* WqxcT = alloc16((size_t)6912 * 2304);
  u16* WqycT = alloc16((size_t)6912 * 2304);
  u16* WpxcT = alloc16((size_t)2304 * 2304);
  u16* WpycT = alloc16((size_t)2304 * 2304);
  u16* WaxT  = alloc16((size_t)768 * 768);
  u16* WayT  = alloc16((size_t)768 * 768);
  u16* biasB = alloc16(24576);
  u16* xb = alloc16(NC);
  u16* yb = alloc16(NC);
  u16* RT = alloc16(2 * NC);      // xt,yt -> attx,atty -> attxc,attyc
  u16* RQ1 = alloc16(3 * NC);     // qkvxs -> qkvxc
  u16* RQ2 = alloc16(3 * NC);     // qkvys -> qkvyc
  u16* RS = alloc16(2 * NC);      // xself, yself
  u16* VT = alloc16(2 * NC);      // transposed V: spatial x/y (flash), channel reuse slot 0
  size_t fixedEnd = off;
  float* Sbuf = (float*)(base + fixedEnd);
  size_t availS = ws_size > fixedEnd ? ws_size - fixedEnd : 0;

  const size_t spHead = (size_t)N * N * 4;
  const bool fat = ws_size >= fixedEnd + spHead;

  auto G64 = [&](const void* A, int lda, long sAz, int aExt,
                 const void* B, int ldb, long sBz, int bNT, int bExt,
                 const void* bias, void* Out, int ldo, long sOz, long oOff, int outMode,
                 float scale, int M, int Nn, int K, int Z) {
    dim3 grid((Nn + BN - 1) / BN, (M + BM - 1) / BM, Z);
    gemm64<<<grid, 256, 0, stream>>>(A, lda, sAz, aExt, B, ldb, sBz, bNT, bExt,
                                     bias, Out, ldo, sOz, oOff, outMode, flag,
                                     scale, M, Nn, K);
  };
  auto G128 = [&](const u16* A, int lda, long sAz,
                  const u16* B, int ldb, long sBz,
                  const u16* bias, int sBiasZ,
                  void* Out, int ldo, long sOz, long oOff, int outMode,
                  float scale, int M, int Nn, int K, int Z) {
    dim3 grid(Nn / 128, M / 128, Z);
    gemm128<<<grid, 256, 0, stream>>>(A, lda, sAz, B, ldb, sBz, bias, sBiasZ,
                                      Out, ldo, sOz, oOff, outMode, flag,
                                      scale, M, Nn, K);
  };

  probe_dtype<<<1, 256, 0, stream>>>((const u32*)x, 1024, flag);

  if (fat) {
    transpose_in<<<dim3(2304 / 32, 768 / 32),  256, 0, stream>>>(Wqx,  WqxT,  flag, 768,  2304);
    transpose_in<<<dim3(2304 / 32, 768 / 32),  256, 0, stream>>>(Wqy,  WqyT,  flag, 768,  2304);
    transpose_in<<<dim3(6912 / 32, 2304 / 32), 256, 0, stream>>>(Wqxc, WqxcT, flag, 2304, 6912);
    transpose_in<<<dim3(6912 / 32, 2304 / 32), 256, 0, stream>>>(Wqyc, WqycT, flag, 2304, 6912);
    transpose_in<<<dim3(2304 / 32, 2304 / 32), 256, 0, stream>>>(Wpxc, WpxcT, flag, 2304, 2304);
    transpose_in<<<dim3(2304 / 32, 2304 / 32), 256, 0, stream>>>(Wpyc, WpycT, flag, 2304, 2304);
    transpose_in<<<dim3(768 / 32, 768 / 32),   256, 0, stream>>>(Wax,  WaxT,  flag, 768,  768);
    transpose_in<<<dim3(768 / 32, 768 / 32),   256, 0, stream>>>(Way,  WayT,  flag, 768,  768);
    P8 bp; bp.p[0] = bqx; bp.p[1] = bqy; bp.p[2] = bqxc; bp.p[3] = bqyc;
    bp.p[4] = bpxc; bp.p[5] = bpyc; bp.p[6] = bax; bp.p[7] = bay;
    cvt_bias<<<96, 256, 0, stream>>>(bp, biasB, flag);
    const u16 *bqxB = biasB, *bqxcB = biasB + 4608,
              *bpxcB = biasB + 18432, *baxB = biasB + 23040;
    cvt_flat<<<(unsigned)(NC / 4 / 256), 256, 0, stream>>>(x, xb, flag, (long)NC);
    cvt_flat<<<(unsigned)(NC / 4 / 256), 256, 0, stream>>>(y, yb, flag, (long)NC);
    u16 *xt = RT, *yt = RT + NC;
    transpose_in<<<dim3(N / 32, C / 32), 256, 0, stream>>>(x, xt, flag, C, N);
    transpose_in<<<dim3(N / 32, C / 32), 256, 0, stream>>>(y, yt, flag, C, N);

    // channel attention: scores gemm128 NT -> softmax -> PV gemm_pv NT
    auto attF = [&](const u16* qB, const u16* kB, const u16* vB, int ldq,
                    u16* att, int Mq, int hd, float scl) {
      // Vt[j, n] = V[n, j]; j over all 8*hd columns, ld = Mq
      transpose_v<<<dim3((8 * hd) / 32, Mq / 32), 256, 0, stream>>>(vB, ldq, VT, Mq, Mq, 8 * hd);
      const long perHead = (long)Mq * Mq * 4;
      int nb = (int)(availS / perHead);
      if (nb > 8) nb = 8;
      for (int h0 = 0; h0 < 8; h0 += nb) {
        const int zc = (8 - h0 < nb) ? 8 - h0 : nb;
        G128(qB + h0 * hd, ldq, hd, kB + h0 * hd, ldq, hd, nullptr, 0,
             Sbuf, Mq, (long)Mq * Mq, 0, 1, scl, Mq, Mq, hd, zc);
        softmax_rows<<<dim3(Mq, zc), 256, 0, stream>>>(Sbuf, Mq, (long)Mq * Mq,
            (u16*)Sbuf, 2 * Mq, (long)Mq * 2 * Mq, Mq);
        gemm_pv<<<dim3(hd / 96, Mq / 64, zc), 256, 0, stream>>>(
            (const u16*)Sbuf, 2 * Mq, (long)Mq * 2 * Mq,
            VT + (long)h0 * hd * Mq, Mq, (long)hd * Mq,
            att + (long)h0 * Mq * hd, hd, (long)Mq * hd, Mq);
      }
    };

    // ---- spatial phase ----
    // x and y batched via Z=2 (A stride NC, W stride NC, bias stride 3C, out stride 3NC)
    u16 *qkvxs = RQ1;
    G128(xt, C, (long)NC, WqxT, C, (long)NC, bqxB, 3 * C,
         qkvxs, 3 * C, 3 * (long)NC, 0, 0, 1.f, N, 3 * C, C, 2);

    // fused spatial attention (x and y in one launch; S never hits memory)
    u16 *qkvys = RQ2;
    u16 *attx = RT;
    const float sscale = 1.0f / sqrtf(96.0f);
    transpose_v<<<dim3((8 * HD) / 32, N / 32), 256, 0, stream>>>(
        qkvxs + 2 * C, 3 * C, VT, N, N, 8 * HD);
    transpose_v<<<dim3((8 * HD) / 32, N / 32), 256, 0, stream>>>(
        qkvys + 2 * C, 3 * C, VT + NC, N, N, 8 * HD);
    flashS<<<dim3(N / 64, 8, 2), 256, 0, stream>>>(
        qkvxs, 3 * (long)NC, VT, (long)NC, attx, (long)NC, 3 * C, N, sscale);

    u16 *xself = RS;
    G128(attx, C, (long)NC, WaxT, C, (long)768 * 768, baxB, C,
         xself, C, (long)NC, 0, 0, 1.f, N, C, C, 2);

    // ---- channel phase ----
    u16 *qkvxc = RQ1, *qkvyc = RQ2;
    G128(xb, N, (long)NC, WqxcT, N, (long)6912 * 2304, bqxcB, 3 * N,
         qkvxc, 3 * N, 3 * (long)NC, 0, 0, 1.f, C, 3 * N, N, 2);

    u16 *attxc = RT, *attyc = RT + NC;
    const float cscale = 1.0f / sqrtf(288.0f);
    attF(qkvxc, qkvyc + N, qkvyc + 2 * N, 3 * N, attxc, C, HDC, cscale);
    attF(qkvyc, qkvxc + N, qkvxc + 2 * N, 3 * N, attyc, C, HDC, cscale);

    G128(attxc, N, (long)NC, WpxcT, N, (long)2304 * 2304, bpxcB, N,
         d_out, N, (long)NC, 0, 2, 1.f, C, N, N, 2);

    transpose_add_out<<<dim3(C / 32, N / 32), 256, 0, stream>>>(xself, d_out, 0, flag, N, C);
    transpose_add_out<<<dim3(C / 32, N / 32), 256, 0, stream>>>(RS + NC, d_out, (long)NC, flag, N, C);
    return;
  }

  // ================= fallback: round-3 verified path =================
  {
    char* b2 = (char*)d_ws;
    u16* RA = (u16*)(b2 + 256);
    u16* RB = RA + 3 * NC;
    u16* RD = RB + 3 * NC;
    u16* RE = RD + 2 * NC;
    const size_t offSsp = 256 + (size_t)(8 * NC) * 2;
    float* Ssp = (float*)(b2 + offSsp);
    const size_t availSp = ws_size > offSsp ? ws_size - offSsp : 0;
    const size_t offSch = 256 + (size_t)(10 * NC) * 2;
    float* Sch = (float*)(b2 + offSch);
    const size_t availCh = ws_size > offSch ? ws_size - offSch : 0;

    u16 *xt = RD, *yt = RD + NC;
    u16 *qkvxs = RA, *qkvys = RB;
    u16 *attx = RD, *atty = RD + NC;
    u16 *xself = RE, *yself = RE + NC;
    u16 *qkvxc = RA, *qkvyc = RB;
    u16 *attxc = RD, *attyc = RD + NC;

    auto attention = [&](const u16* qB, const u16* kB, const u16* vB, int ldq,
                         u16* att, int Mq, int hd, float scl,
                         float* S, size_t availBytes) {
      const long perHead = (long)Mq * Mq * 4;
      int nb = (int)(availBytes / perHead);
      if (nb > 8) nb = 8;
      if (nb >= 1) {
        for (int h0 = 0; h0 < 8; h0 += nb) {
          const int zc = (8 - h0 < nb) ? 8 - h0 : nb;
          G64(qB + h0 * hd, ldq, hd, 0, kB + h0 * hd, ldq, hd, 1, 0, nullptr,
              S, Mq, (long)Mq * Mq, 0, 1, scl, Mq, Mq, hd, zc);
          softmax_rows<<<dim3(Mq, zc), 256, 0, stream>>>(S, Mq, (long)Mq * Mq,
              (u16*)S, 2 * Mq, (long)Mq * 2 * Mq, Mq);
          G64((const u16*)S, 2 * Mq, (long)Mq * 2 * Mq, 0, vB + h0 * hd, ldq, hd, 0, 0,
              nullptr, att + (long)h0 * Mq * hd, hd, (long)Mq * hd, 0, 0,
              1.f, Mq, hd, Mq, zc);
        }
      } else {
        long rows = (long)(availBytes / ((size_t)Mq * 4)) & ~63L;
        if (rows < 64) rows = 64;
        if (rows > Mq) rows = Mq;
        for (int h = 0; h < 8; h++) {
          for (int m0 = 0; m0 < Mq; m0 += (int)rows) {
            const int mr = (Mq - m0 < rows) ? (int)(Mq - m0) : (int)rows;
            G64(qB + (long)m0 * ldq + h * hd, ldq, 0, 0, kB + h * hd, ldq, 0, 1, 0,
                nullptr, S, Mq, 0, 0, 1, scl, mr, Mq, hd, 1);
            softmax_rows<<<dim3(mr, 1), 256, 0, stream>>>(S, Mq, 0, (u16*)S, 2 * Mq, 0, Mq);
            G64((const u16*)S, 2 * Mq, 0, 0, vB + h * hd, ldq, 0, 0, 0, nullptr,
                att + (long)h * Mq * hd + (long)m0 * hd, hd, 0, 0, 0, 1.f, mr, hd, Mq, 1);
          }
        }
      }
    };

    transpose_in<<<dim3(N / 32, C / 32), 256, 0, stream>>>(x, xt, flag, C, N);
    transpose_in<<<dim3(N / 32, C / 32), 256, 0, stream>>>(y, yt, flag, C, N);

    G64(xt, C, 0, 0, Wqx, 3 * C, 0, 0, 1, bqx, qkvxs, 3 * C, 0, 0, 0, 1.f, N, 3 * C, C, 1);
    G64(yt, C, 0, 0, Wqy, 3 * C, 0, 0, 1, bqy, qkvys, 3 * C, 0, 0, 0, 1.f, N, 3 * C, C, 1);

    const float sscale = 1.0f / sqrtf(96.0f);
    attention(qkvxs, qkvxs + C, qkvxs + 2 * C, 3 * C, attx, N, HD, sscale, Ssp, availSp);
    attention(qkvys, qkvys + C, qkvys + 2 * C, 3 * C, atty, N, HD, sscale, Ssp, availSp);

    G64(attx, C, 0, 0, Wax, C, 0, 0, 1, bax, xself, C, 0, 0, 0, 1.f, N, C, C, 1);
    G64(atty, C, 0, 0, Way, C, 0, 0, 1, bay, yself, C, 0, 0, 0, 1.f, N, C, C, 1);

    G64(x, N, 0, 1, Wqxc, 3 * N, 0, 0, 1, bqxc, qkvxc, 3 * N, 0, 0, 0, 1.f, C, 3 * N, N, 1);
    G64(y, N, 0, 1, Wqyc, 3 * N, 0, 0, 1, bqyc, qkvyc, 3 * N, 0, 0, 0, 1.f, C, 3 * N, N, 1);

    const float cscale = 1.0f / sqrtf(288.0f);
    attention(qkvxc, qkvyc + N, qkvyc + 2 * N, 3 * N, attxc, C, HDC, cscale, Sch, availCh);
    attention(qkvyc, qkvxc + N, qkvxc + 2 * N, 3 * N, attyc, C, HDC, cscale, Sch, availCh);

    G64(attxc, N, 0, 0, Wpxc, N, 0, 0, 1, bpxc, d_out, N, 0, 0, 2, 1.f, C, N, N, 1);
    G64(attyc, N, 0, 0, Wpyc, N, 0, 0, 1, bpyc, d_out, N, 0, (long)NC, 2, 1.f, C, N, N, 1);

    transpose_add_out<<<dim3(C / 32, N / 32), 256, 0, stream>>>(xself, d_out, 0, flag, N, C);
    transpose_add_out<<<dim3(C / 32, N / 32), 256, 0, stream>>>(yself, d_out, (long)NC, flag, N, C);
  }
}

// Round 7
// 688.245 us; speedup vs baseline: 1.5715x; 1.0113x over previous
//
#include <hip/hip_runtime.h>
#include <math.h>

typedef unsigned short u16;
typedef unsigned int u32;
typedef short bf16x8 __attribute__((ext_vector_type(8)));
typedef float f32x4 __attribute__((ext_vector_type(4)));
typedef float f32x16 __attribute__((ext_vector_type(16)));

__device__ __forceinline__ float bf2f(u16 u) {
  union { unsigned int i; float f; } v;
  v.i = ((unsigned int)u) << 16;
  return v.f;
}
__device__ __forceinline__ u16 f2bf(float f) {
  union { float f; unsigned int i; } v;
  v.f = f;
  unsigned int u = v.i;
  return (u16)((u + 0x7fffu + ((u >> 16) & 1u)) >> 16);
}
// pack two f32 -> two bf16 in one u32 (lo = a, hi = b)
__device__ __forceinline__ u32 pkbf(float a, float b) {
  u32 d;
  asm("v_cvt_pk_bf16_f32 %0, %1, %2" : "=v"(d) : "v"(a), "v"(b));
  return d;
}
// raw v_exp_f32: computes 2^x
__device__ __forceinline__ float exp2_raw(float x) {
  float r;
  asm("v_exp_f32 %0, %1" : "=v"(r) : "v"(x));
  return r;
}

// async global->LDS, 16B per lane. LDS dest = wave-uniform base + lane*16.
__device__ __forceinline__ void glds16(const u16* g, u16* l) {
  __builtin_amdgcn_global_load_lds(
      (const __attribute__((address_space(1))) void*)g,
      (__attribute__((address_space(3))) void*)l, 16, 0, 0);
}

// ---------------------------------------------------------------------------
// dtype probe: fp32(1) vs bf16(0) from bit statistics of x.
// ---------------------------------------------------------------------------
__global__ __launch_bounds__(256) void probe_dtype(const u32* __restrict__ xw,
                                                   int nwords, int* flag)
{
  const int tid = threadIdx.x;
  int cnt = 0;
  for (int i = tid; i < nwords; i += 256) {
    u32 w = xw[i];
    u32 e = (w >> 7) & 0xFFu;
    if (e >= 110u && e <= 140u) cnt++;
  }
#pragma unroll
  for (int off = 32; off >= 1; off >>= 1) cnt += __shfl_xor(cnt, off);
  __shared__ int s[4];
  if ((tid & 63) == 0) s[tid >> 6] = cnt;
  __syncthreads();
  if (tid == 0) {
    int tot = s[0] + s[1] + s[2] + s[3];
    flag[0] = (tot < nwords / 2) ? 1 : 0;
  }
}

// ---------------------------------------------------------------------------
// gemm128: 128x128 tile, BK=32, NT-only, all-bf16 inputs, glds staging.
// Double-buffered 2-phase pipeline: stage tile t+1 while computing tile t.
// Out[m,n] = scale * sum_k A[m,k] * B[n,k] + bias[n + z*sBiasZ]
// ---------------------------------------------------------------------------
__global__ __launch_bounds__(256) void gemm128(
    const u16* __restrict__ A, int lda, long sAz,
    const u16* __restrict__ B, int ldb, long sBz,
    const u16* __restrict__ bias, int sBiasZ,
    void* __restrict__ OutV, int ldo, long sOz, long oOff, int outMode,
    const int* __restrict__ flagp,
    float scale, int M, int Nn, int K)
{
  const int z = blockIdx.z;
  const u16* Ab = A + (long)z * sAz;
  const u16* Bb = B + (long)z * sBz;
  const int bm = blockIdx.y * 128;
  const int bn = blockIdx.x * 128;

  __shared__ u16 As[2][128 * 32];
  __shared__ u16 Bs[2][128 * 32];

  const int tid  = threadIdx.x;
  const int lane = tid & 63;
  const int wave = tid >> 6;
  const int wr = wave >> 1, wc = wave & 1;
  const int q = lane >> 4, l15 = lane & 15;

  f32x4 acc[4][4];
#pragma unroll
  for (int i = 0; i < 4; i++)
#pragma unroll
    for (int j = 0; j < 4; j++) acc[i][j] = (f32x4){0.f, 0.f, 0.f, 0.f};

  const int srow = tid >> 2;
  const int sc8  = (tid & 3) * 8;
  const u16* aptr = Ab + (long)(bm + srow) * lda + sc8;
  const u16* bptr = Bb + (long)(bn + srow) * ldb + sc8;

  auto stage = [&](int buf, int k0) {
    u16* asl = As[buf] + tid * 8;
    u16* bsl = Bs[buf] + tid * 8;
    glds16(aptr + k0, asl);
    glds16(aptr + (long)64 * lda + k0, asl + 256 * 8);
    glds16(bptr + k0, bsl);
    glds16(bptr + (long)64 * ldb + k0, bsl + 256 * 8);
  };
  auto compute = [&](int buf) {
    bf16x8 af[4], bfr[4];
#pragma unroll
    for (int mi = 0; mi < 4; mi++)
      af[mi] = *(const bf16x8*)(As[buf] + (wr * 64 + mi * 16 + l15) * 32 + q * 8);
#pragma unroll
    for (int nj = 0; nj < 4; nj++)
      bfr[nj] = *(const bf16x8*)(Bs[buf] + (wc * 64 + nj * 16 + l15) * 32 + q * 8);
#pragma unroll
    for (int mi = 0; mi < 4; mi++)
#pragma unroll
      for (int nj = 0; nj < 4; nj++)
        acc[mi][nj] = __builtin_amdgcn_mfma_f32_16x16x32_bf16(af[mi], bfr[nj], acc[mi][nj], 0, 0, 0);
  };

  // prologue: stage tile 0, drain, then pipeline.
  stage(0, 0);
  __syncthreads();           // emits s_waitcnt vmcnt(0) lgkmcnt(0) + s_barrier
  int cur = 0;
  for (int k0 = 32; k0 < K; k0 += 32) {
    stage(cur ^ 1, k0);      // next tile's loads fly during current compute
    compute(cur);
    __syncthreads();
    cur ^= 1;
  }
  compute(cur);

  const int flagv = (outMode == 2) ? *flagp : 0;
  const bool storeF32 = (outMode == 1) || (outMode == 2 && flagv);
  const u16* bz = bias ? bias + (long)z * sBiasZ : nullptr;
#pragma unroll
  for (int mi = 0; mi < 4; mi++) {
    const int r0 = bm + wr * 64 + mi * 16 + q * 4;
#pragma unroll
    for (int nj = 0; nj < 4; nj++) {
      const int col = bn + wc * 64 + nj * 16 + l15;
      const float bsv = bz ? bf2f(bz[col]) : 0.0f;
      if (storeF32) {
        float* Out = (float*)OutV + oOff + (long)z * sOz;
#pragma unroll
        for (int r = 0; r < 4; r++)
          Out[(long)(r0 + r) * ldo + col] = acc[mi][nj][r] * scale + bsv;
      } else {
        u16* Out = (u16*)OutV + oOff + (long)z * sOz;
#pragma unroll
        for (int r = 0; r < 4; r++)
          Out[(long)(r0 + r) * ldo + col] = f2bf(acc[mi][nj][r] * scale + bsv);
      }
    }
  }
}

// ---------------------------------------------------------------------------
// flashS v3: fused spatial attention, hd=96, 32x32 swapped-operand + wave-pair
// KV-split (round-6 verified). v3 = VALU diet (round-6: VALUBusy 41% > 3x
// MfmaUtil -> VALU-throughput-bound):
//  - log2-domain softmax: Q pre-scaled by scl*log2(e); P = v_exp(s-m) (2^x),
//    removing the hidden mul in __expf. THR = 8*log2e = 11.5416.
//  - staging source pointers hoisted out of the k-loop (swizzle/div/select
//    math is iteration-invariant); advanced by constant stride per tile.
//  - max3-shaped fmax tree; vector add s1+s2 (v_pk_add_f32).
// Everything else identical to the round-6 passing kernel.
// ---------------------------------------------------------------------------
__global__ __launch_bounds__(256) void flashS(
    const u16* __restrict__ QKV, long sTz,   // q at col h*96; k at col 768+h*96
    const u16* __restrict__ VTb, long sVz,   // Vt [768][Mq] per tensor
    u16* __restrict__ Out, long sOz,         // att + h*Mq*96 + q*96 + d
    int ldq, int Mq, float scl)
{
  const int bm = blockIdx.x * 64;
  const int h  = blockIdx.y;
  const int t  = blockIdx.z;
  const int h96 = h * 96;
  const u16* qB  = QKV + (long)t * sTz;
  const u16* kB  = qB + 768;
  const u16* vtB = VTb + (long)t * sVz + (long)h96 * Mq;
  u16* oB = Out + (long)t * sOz + (long)h * Mq * 96;

  // per pair (16384 u16): K 2 bufs x 4096 ([32][128]); V 2 bufs x 4096 ([96][40]+pad)
  __shared__ u16 SH[2 * 16384];

  const int tid  = threadIdx.x;
  const int lane = tid & 63;
  const int wave = tid >> 6;
  const int l31  = lane & 31;
  const int hi   = lane >> 5;
  const int wp   = wave >> 1;    // kv-split half
  const int wq   = wave & 1;     // q 32-row group
  const int ptid = tid & 127;
  u16* PB = SH + wp * 16384;
  const int kst = wp * (Mq >> 1);

  // ---- Q fragments, hoisted + pre-scaled by scl*log2(e) (log2-domain SM) ----
  const float scl2 = scl * 1.44269504f;
  bf16x8 qf[6];
  {
    const u16* qrow = qB + (long)(bm + wq * 32 + l31) * ldq + h96;
#pragma unroll
    for (int cs = 0; cs < 6; cs++) {
      union { bf16x8 v; u16 e[8]; } a, b;
      a.v = *(const bf16x8*)(qrow + cs * 16 + hi * 8);
#pragma unroll
      for (int e = 0; e < 8; e++) b.e[e] = f2bf(bf2f(a.e[e]) * scl2);
      qf[cs] = b.v;
    }
  }

  f32x16 accO[3];
#pragma unroll
  for (int r = 0; r < 16; r++) { accO[0][r] = 0.f; accO[1][r] = 0.f; accO[2][r] = 0.f; }
  float m_r = -1e30f, l_r = 0.f;

  // ---- hoisted per-lane staging sources (swizzle pattern is k-invariant;
  // only the base advances: K += 32*ldq, V += 32 per tile). Redirected dummy
  // lanes land in LDS pad slots (never read) and stay in-bounds globally. ----
  const long kStep = 32L * ldq;
  const u16* kS0; const u16* kS1; const u16* kS2; const u16* kS3;
  const u16* vS0; const u16* vS1; const u16* vS2; const u16* vS3;
  {
    const u16* kBase = kB + (long)kst * ldq + h96;
    const u16* vBase = vtB + kst;
    auto kinit = [&](int i) -> const u16* {
      const int G = ptid + 128 * i;
      const int row = G >> 4, gi = G & 15;
      const int g = gi ^ (row & 7);
      return (g < 12) ? (kBase + (long)row * ldq + g * 8) : kB;
    };
    auto vinit = [&](int i) -> const u16* {
      const int G = ptid + 128 * i;
      const int row = G / 5, gi = G - row * 5;
      const bool ok = (G < 480) && (gi < 4);
      return ok ? (vBase + (long)row * Mq + (long)(gi ^ (row & 3)) * 8) : vtB;
    };
    kS0 = kinit(0); kS1 = kinit(1); kS2 = kinit(2); kS3 = kinit(3);
    vS0 = vinit(0); vS1 = vinit(1); vS2 = vinit(2); vS3 = vinit(3);
  }

  auto stageKV = [&](int buf) {
    u16* kd = PB + buf * 4096 + ptid * 8;
    u16* vd = PB + 8192 + buf * 4096 + ptid * 8;
    glds16(kS0, kd);            glds16(kS1, kd + 128 * 8);
    glds16(kS2, kd + 256 * 8);  glds16(kS3, kd + 384 * 8);
    glds16(vS0, vd);            glds16(vS1, vd + 128 * 8);
    glds16(vS2, vd + 256 * 8);  glds16(vS3, vd + 384 * 8);
    kS0 += kStep; kS1 += kStep; kS2 += kStep; kS3 += kStep;
    vS0 += 32; vS1 += 32; vS2 += 32; vS3 += 32;
  };
  auto ldK = [&](int buf, int cs) -> bf16x8 {
    const int g = (2 * cs + hi) ^ (l31 & 7);
    return *(const bf16x8*)(PB + buf * 4096 + l31 * 128 + g * 8);
  };
  auto ldV = [&](int buf, int dt, int s) -> bf16x8 {
    const int row = dt * 32 + l31;
    const int g = (2 * s + hi) ^ (row & 3);
    return *(const bf16x8*)(PB + 8192 + buf * 4096 + row * 40 + g * 8);
  };

  stageKV(0);
  __syncthreads();
  int cur = 0;
  const int nt = Mq >> 6;                      // (Mq/2)/32
  for (int kt = 0; kt < nt; kt++) {
    if (kt + 1 < nt) stageKV(cur ^ 1);         // flies under compute

    // ---- S^T = K Q^T, two 3-deep chains summed ----
    f32x16 s1, s2;
#pragma unroll
    for (int r = 0; r < 16; r++) { s1[r] = 0.f; s2[r] = 0.f; }
    __builtin_amdgcn_s_setprio(1);
#pragma unroll
    for (int cs = 0; cs < 3; cs++) {
      s1 = __builtin_amdgcn_mfma_f32_32x32x16_bf16(ldK(cur, 2 * cs),     qf[2 * cs],     s1, 0, 0, 0);
      s2 = __builtin_amdgcn_mfma_f32_32x32x16_bf16(ldK(cur, 2 * cs + 1), qf[2 * cs + 1], s2, 0, 0, 0);
    }
    __builtin_amdgcn_s_setprio(0);
    f32x16 sA = s1 + s2;                       // vector add (v_pk_add_f32)

    // ---- online softmax (log2 domain): max3 tree + one cross-half shfl ----
    float t0 = fmaxf(fmaxf(sA[0], sA[1]), sA[2]);
    float t1 = fmaxf(fmaxf(sA[3], sA[4]), sA[5]);
    float t2 = fmaxf(fmaxf(sA[6], sA[7]), sA[8]);
    float t3 = fmaxf(fmaxf(sA[9], sA[10]), sA[11]);
    float t4 = fmaxf(fmaxf(sA[12], sA[13]), sA[14]);
    float tm = fmaxf(fmaxf(fmaxf(t0, t1), t2), fmaxf(fmaxf(t3, t4), sA[15]));
    tm = fmaxf(tm, __shfl_xor(tm, 32));
    if (!__all(tm <= m_r + 11.5416f)) {        // defer-max (T13), 8*log2e
      const float mn = fmaxf(m_r, tm);
      const float al = exp2_raw(m_r - mn);
      m_r = mn; l_r *= al;
#pragma unroll
      for (int r = 0; r < 16; r++) {
        const float a = __shfl(al, (r & 3) + 8 * (r >> 2) + 4 * hi);
        accO[0][r] *= a; accO[1][r] *= a; accO[2][r] *= a;
      }
    }
#pragma unroll
    for (int r = 0; r < 16; r++) sA[r] = exp2_raw(sA[r] - m_r);
    float rs = (((sA[0] + sA[1]) + (sA[2] + sA[3])) + ((sA[4] + sA[5]) + (sA[6] + sA[7])))
             + (((sA[8] + sA[9]) + (sA[10] + sA[11])) + ((sA[12] + sA[13]) + (sA[14] + sA[15])));
    rs += __shfl_xor(rs, 32);
    l_r += rs;

    // ---- PV: A-frags built in-register (cvt_pk + permlane32_swap) ----
#pragma unroll
    for (int s = 0; s < 2; s++) {
      const int rb = s * 8;
      u32 X  = pkbf(sA[rb + 0], sA[rb + 1]);
      u32 X2 = pkbf(sA[rb + 2], sA[rb + 3]);
      u32 Y  = pkbf(sA[rb + 4], sA[rb + 5]);
      u32 Y2 = pkbf(sA[rb + 6], sA[rb + 7]);
      asm volatile("v_permlane32_swap_b32 %0, %1" : "+v"(X), "+v"(Y));
      asm volatile("v_permlane32_swap_b32 %0, %1" : "+v"(X2), "+v"(Y2));
      union { u32 w[4]; bf16x8 v; } pa;
      pa.w[0] = X; pa.w[1] = X2; pa.w[2] = Y; pa.w[3] = Y2;
      __builtin_amdgcn_s_setprio(1);
#pragma unroll
      for (int dt = 0; dt < 3; dt++)
        accO[dt] = __builtin_amdgcn_mfma_f32_32x32x16_bf16(pa.v, ldV(cur, dt, s), accO[dt], 0, 0, 0);
      __builtin_amdgcn_s_setprio(0);
    }

    __syncthreads();     // stage visible + all reads of cur done
    cur ^= 1;
  }

  // ---- in-LDS merge of kv-split partials; waves 0,1 store ----
  float* fsh = (float*)SH;
  const int MLOFF = 128 * 49;                  // acc area: 128 lanes x 49 floats
  if (wp == 1) {
    float* ab = fsh + (wq * 64 + lane) * 49;
#pragma unroll
    for (int dt = 0; dt < 3; dt++)
#pragma unroll
      for (int r = 0; r < 16; r++) ab[dt * 16 + r] = accO[dt][r];
    fsh[MLOFF + wq * 64 + lane] = m_r;
    fsh[MLOFF + 128 + wq * 64 + lane] = l_r;
  }
  __syncthreads();
  if (wp == 0) {
    const float m2 = fsh[MLOFF + wq * 64 + lane];
    const float l2 = fsh[MLOFF + 128 + wq * 64 + lane];
    const float mm = fmaxf(m_r, m2);
    const float a1 = exp2_raw(m_r - mm);
    const float a2 = exp2_raw(m2 - mm);
    const float inv = 1.0f / (l_r * a1 + l2 * a2);
    const float* ab = fsh + (wq * 64 + lane) * 49;
#pragma unroll
    for (int r = 0; r < 16; r++) {
      const int row = (r & 3) + 8 * (r >> 2) + 4 * hi;
      const float f1 = __shfl(a1 * inv, row);
      const float f2 = __shfl(a2 * inv, row);
      const long rowb = (long)(bm + wq * 32 + row) * 96;
#pragma unroll
      for (int dt = 0; dt < 3; dt++)
        oB[rowb + dt * 32 + l31] = f2bf(accO[dt][r] * f1 + ab[dt * 16 + r] * f2);
    }
  }
}

// ---------------------------------------------------------------------------
// gemm_pv: PV-shaped NT GEMM. Out[m, bn+c] = sum_k P[m,k] * Vt[bn+c, k].
// BM=64, BN=96 (exact head width unit), BK=32, glds staging, bf16 out.
// Double-buffered 2-phase pipeline.
// grid = (hd/96, M/64, nheads); K = Mq. All dims: M%64, K%32, lds %8.
// ---------------------------------------------------------------------------
__global__ __launch_bounds__(256) void gemm_pv(
    const u16* __restrict__ P, int ldP, long sPz,
    const u16* __restrict__ Vt, int ldVt, long sVz,
    u16* __restrict__ Out, int ldo, long sOz, int K)
{
  const int z = blockIdx.z;
  const u16* Pz = P + (long)z * sPz;
  const u16* Vz = Vt + (long)z * sVz;
  u16* Oz = Out + (long)z * sOz;
  const int bm = blockIdx.y * 64;
  const int bn = blockIdx.x * 96;

  __shared__ u16 As[2][64 * 32];   // [64][32]
  __shared__ u16 Bs[2][96 * 32];   // [96][32] (rows = output cols)

  const int tid  = threadIdx.x;
  const int lane = tid & 63;
  const int wave = tid >> 6;
  const int wr = wave >> 1, wc = wave & 1;
  const int q = lane >> 4, l15 = lane & 15;

  f32x4 acc[2][3];
#pragma unroll
  for (int i = 0; i < 2; i++)
#pragma unroll
    for (int j = 0; j < 3; j++) acc[i][j] = (f32x4){0.f, 0.f, 0.f, 0.f};

  const int srow = lane >> 2;        // 0..15
  const int sc8  = (lane & 3) * 8;   // 0,8,16,24

  // A: 4 chunks of 16 rows; wave w stages chunk w.
  const u16* aRow = Pz + (long)(bm + wave * 16 + srow) * ldP + sc8;
  // B: 6 chunks of 16 rows; waves 0..2 stage chunks 2w, 2w+1.
  const u16* bRow0 = nullptr; const u16* bRow1 = nullptr;
  if (wave < 3) {
    bRow0 = Vz + (long)(bn + (2 * wave) * 16 + srow) * ldVt + sc8;
    bRow1 = Vz + (long)(bn + (2 * wave + 1) * 16 + srow) * ldVt + sc8;
  }

  auto stage = [&](int buf, int k0) {
    glds16(aRow + k0, As[buf] + wave * 512 + lane * 8);
    if (wave < 3) {
      glds16(bRow0 + k0, Bs[buf] + (2 * wave) * 512 + lane * 8);
      glds16(bRow1 + k0, Bs[buf] + (2 * wave + 1) * 512 + lane * 8);
    }
  };
  auto compute = [&](int buf) {
    bf16x8 af[2], bfr[3];
#pragma unroll
    for (int mi = 0; mi < 2; mi++)
      af[mi] = *(const bf16x8*)(As[buf] + (wr * 32 + mi * 16 + l15) * 32 + q * 8);
#pragma unroll
    for (int nj = 0; nj < 3; nj++)
      bfr[nj] = *(const bf16x8*)(Bs[buf] + (wc * 48 + nj * 16 + l15) * 32 + q * 8);
#pragma unroll
    for (int mi = 0; mi < 2; mi++)
#pragma unroll
      for (int nj = 0; nj < 3; nj++)
        acc[mi][nj] = __builtin_amdgcn_mfma_f32_16x16x32_bf16(af[mi], bfr[nj], acc[mi][nj], 0, 0, 0);
  };

  stage(0, 0);
  __syncthreads();
  int cur = 0;
  for (int k0 = 32; k0 < K; k0 += 32) {
    stage(cur ^ 1, k0);
    compute(cur);
    __syncthreads();
    cur ^= 1;
  }
  compute(cur);

#pragma unroll
  for (int mi = 0; mi < 2; mi++) {
    const int r0 = bm + wr * 32 + mi * 16 + q * 4;
#pragma unroll
    for (int nj = 0; nj < 3; nj++) {
      const int cl = bn + wc * 48 + nj * 16 + l15;
#pragma unroll
      for (int r = 0; r < 4; r++)
        Oz[(long)(r0 + r) * ldo + cl] = f2bf(acc[mi][nj][r]);
    }
  }
}

// ---------------------------------------------------------------------------
// Generic 64x64 MFMA bf16 GEMM (round-3 verified; fallback path only).
// ---------------------------------------------------------------------------
#define BM 64
#define BN 64
#define BK 32
#define LDSP (BK + 8)

__global__ __launch_bounds__(256) void gemm64(
    const void* __restrict__ Av, int lda, long sAz, int aExt,
    const void* __restrict__ Bv, int ldb, long sBz, int bNT, int bExt,
    const void* __restrict__ biasv,
    void* __restrict__ OutV, int ldo, long sOz, long oOff, int outMode,
    const int* __restrict__ flagp,
    float scale, int M, int Nn, int K)
{
  const int flagv = *flagp;
  const bool aF32 = aExt && flagv;
  const bool bF32 = bExt && flagv;

  const int z = blockIdx.z;
  const int bm = blockIdx.y * BM;
  const int bn = blockIdx.x * BN;

  __shared__ u16 As[BM][LDSP];
  __shared__ u16 Bs[BN][LDSP];

  const int tid  = threadIdx.x;
  const int lane = tid & 63;
  const int wave = tid >> 6;
  const int wr = wave >> 1;
  const int wc = wave & 1;
  const int q   = lane >> 4;
  const int l15 = lane & 15;

  f32x4 acc[2][2];
#pragma unroll
  for (int i = 0; i < 2; i++)
#pragma unroll
    for (int j = 0; j < 2; j++) acc[i][j] = (f32x4){0.f, 0.f, 0.f, 0.f};

  const int am  = tid >> 2;
  const int ach = (tid & 3) * 8;

  for (int k0 = 0; k0 < K; k0 += BK) {
    __syncthreads();
    if (aF32) {
      const float* src = (const float*)Av + (long)z * sAz + (long)(bm + am) * lda + (k0 + ach);
      f32x4 f0 = *(const f32x4*)src;
      f32x4 f1 = *(const f32x4*)(src + 4);
      u16 t[8] = {f2bf(f0[0]), f2bf(f0[1]), f2bf(f0[2]), f2bf(f0[3]),
                  f2bf(f1[0]), f2bf(f1[1]), f2bf(f1[2]), f2bf(f1[3])};
      *(uint4*)(&As[am][ach]) = *(const uint4*)t;
    } else {
      const u16* src = (const u16*)Av + (long)z * sAz + (long)(bm + am) * lda + (k0 + ach);
      *(uint4*)(&As[am][ach]) = *(const uint4*)src;
    }
    if (bNT) {
      if (bF32) {
        u16 t[8] = {0, 0, 0, 0, 0, 0, 0, 0};
        if (bn + am < Nn) {
          const float* src = (const float*)Bv + (long)z * sBz + (long)(bn + am) * ldb + (k0 + ach);
          f32x4 f0 = *(const f32x4*)src;
          f32x4 f1 = *(const f32x4*)(src + 4);
#pragma unroll
          for (int j = 0; j < 4; j++) { t[j] = f2bf(f0[j]); t[4 + j] = f2bf(f1[j]); }
        }
        *(uint4*)(&Bs[am][ach]) = *(const uint4*)t;
      } else {
        uint4 val = make_uint4(0u, 0u, 0u, 0u);
        if (bn + am < Nn)
          val = *(const uint4*)((const u16*)Bv + (long)z * sBz + (long)(bn + am) * ldb + (k0 + ach));
        *(uint4*)(&Bs[am][ach]) = val;
      }
    } else {
      const int kk = tid >> 3;
      const int n0 = (tid & 7) * 8;
      if (bn + n0 < Nn) {
        if (bF32) {
          const float* src = (const float*)Bv + (long)z * sBz + (long)(k0 + kk) * ldb + (bn + n0);
          f32x4 f0 = *(const f32x4*)src;
          f32x4 f1 = *(const f32x4*)(src + 4);
#pragma unroll
          for (int j = 0; j < 4; j++) {
            Bs[n0 + j][kk] = f2bf(f0[j]);
            Bs[n0 + 4 + j][kk] = f2bf(f1[j]);
          }
        } else {
          uint4 val = *(const uint4*)((const u16*)Bv + (long)z * sBz + (long)(k0 + kk) * ldb + (bn + n0));
          const u16* pv = (const u16*)&val;
#pragma unroll
          for (int j = 0; j < 8; j++) Bs[n0 + j][kk] = pv[j];
        }
      } else {
#pragma unroll
        for (int j = 0; j < 8; j++) Bs[n0 + j][kk] = 0;
      }
    }
    __syncthreads();

    bf16x8 af[2], bfr[2];
#pragma unroll
    for (int t = 0; t < 2; t++)
      af[t] = *(const bf16x8*)(&As[wr * 32 + t * 16 + l15][q * 8]);
#pragma unroll
    for (int t = 0; t < 2; t++)
      bfr[t] = *(const bf16x8*)(&Bs[wc * 32 + t * 16 + l15][q * 8]);
#pragma unroll
    for (int i = 0; i < 2; i++)
#pragma unroll
      for (int j = 0; j < 2; j++)
        acc[i][j] = __builtin_amdgcn_mfma_f32_16x16x32_bf16(af[i], bfr[j], acc[i][j], 0, 0, 0);
  }

#pragma unroll
  for (int i = 0; i < 2; i++) {
    const int r0 = bm + wr * 32 + i * 16 + q * 4;
#pragma unroll
    for (int j = 0; j < 2; j++) {
      const int col = bn + wc * 32 + j * 16 + l15;
      if (col >= Nn) continue;
      float bsv = 0.0f;
      if (biasv) bsv = flagv ? ((const float*)biasv)[col] : bf2f(((const u16*)biasv)[col]);
      const bool storeF32 = (outMode == 1) || (outMode == 2 && flagv);
      if (storeF32) {
        float* Out = (float*)OutV + oOff + (long)z * sOz;
#pragma unroll
        for (int r = 0; r < 4; r++)
          Out[(long)(r0 + r) * ldo + col] = acc[i][j][r] * scale + bsv;
      } else {
        u16* Out = (u16*)OutV + oOff + (long)z * sOz;
#pragma unroll
        for (int r = 0; r < 4; r++)
          Out[(long)(r0 + r) * ldo + col] = f2bf(acc[i][j][r] * scale + bsv);
      }
    }
  }
}

// ---------------------------------------------------------------------------
// Row softmax: fp32 scores row -> bf16 probabilities; P aliases S (in-place).
// ---------------------------------------------------------------------------
__global__ __launch_bounds__(256) void softmax_rows(
    float* S, int ldS, long sSz,
    u16* P, int ldP, long sPz, int ncols)
{
  const int row = blockIdx.x;
  const int z = blockIdx.y;
  float* s = S + (long)z * sSz + (long)row * ldS;
  u16*   p = P + (long)z * sPz + (long)row * ldP;
  const int tid = threadIdx.x;
  const int lane = tid & 63, wave = tid >> 6;

  float v[9];
  int cnt = 0;
  float mx = -1e30f;
  for (int c = tid; c < ncols; c += 256) {
    float t = s[c];
    v[cnt++] = t;
    mx = fmaxf(mx, t);
  }
#pragma unroll
  for (int off = 32; off >= 1; off >>= 1) mx = fmaxf(mx, __shfl_xor(mx, off));
  __shared__ float redm[4];
  __shared__ float reds[4];
  if (lane == 0) redm[wave] = mx;
  __syncthreads();
  mx = fmaxf(fmaxf(redm[0], redm[1]), fmaxf(redm[2], redm[3]));

  float sum = 0.f;
  for (int i = 0; i < cnt; i++) { v[i] = __expf(v[i] - mx); sum += v[i]; }
#pragma unroll
  for (int off = 32; off >= 1; off >>= 1) sum += __shfl_xor(sum, off);
  if (lane == 0) reds[wave] = sum;
  __syncthreads();
  sum = reds[0] + reds[1] + reds[2] + reds[3];
  const float inv = 1.0f / sum;

  cnt = 0;
  for (int c = tid; c < ncols; c += 256) p[c] = f2bf(v[cnt++] * inv);
}

// ---------------------------------------------------------------------------
// transpose_in: outp[j*inRows+i] = (bf16) tin[i*inCols+j]; tin dtype per flag
// ---------------------------------------------------------------------------
__global__ __launch_bounds__(256) void transpose_in(
    const void* __restrict__ tinv, u16* __restrict__ outp,
    const int* __restrict__ flagp, int inRows, int inCols)
{
  const bool f32 = *flagp != 0;
  __shared__ u16 tile[32][33];
  const int bx = blockIdx.x * 32;
  const int by = blockIdx.y * 32;
  const int tx = threadIdx.x & 31;
  const int ty = threadIdx.x >> 5;
#pragma unroll
  for (int k = 0; k < 4; k++) {
    const long idx = (long)(by + ty + k * 8) * inCols + bx + tx;
    tile[ty + k * 8][tx] = f32 ? f2bf(((const float*)tinv)[idx]) : ((const u16*)tinv)[idx];
  }
  __syncthreads();
#pragma unroll
  for (int k = 0; k < 4; k++) {
    const int j = bx + ty + k * 8;
    const int i = by + tx;
    outp[(long)j * inRows + i] = tile[tx][ty + k * 8];
  }
}

// ---------------------------------------------------------------------------
// transpose_v: bf16 strided transpose. dst[j*lddst+n] = src[n*ldsrc+j]
// rows%32==0, cols%32==0. grid(cols/32, rows/32).
// ---------------------------------------------------------------------------
__global__ __launch_bounds__(256) void transpose_v(
    const u16* __restrict__ src, int ldsrc,
    u16* __restrict__ dst, int lddst, int rows, int cols)
{
  __shared__ u16 tile[32][33];
  const int bx = blockIdx.x * 32;   // over cols (j)
  const int by = blockIdx.y * 32;   // over rows (n)
  const int tx = threadIdx.x & 31;
  const int ty = threadIdx.x >> 5;
#pragma unroll
  for (int k = 0; k < 4; k++)
    tile[ty + k * 8][tx] = src[(long)(by + ty + k * 8) * ldsrc + bx + tx];
  __syncthreads();
#pragma unroll
  for (int k = 0; k < 4; k++)
    dst[(long)(bx + ty + k * 8) * lddst + by + tx] = tile[tx][ty + k * 8];
}

// flat convert (n % 4 == 0)
__global__ __launch_bounds__(256) void cvt_flat(
    const void* __restrict__ src, u16* __restrict__ dst,
    const int* __restrict__ flagp, long n)
{
  const bool f32 = *flagp != 0;
  long i = ((long)blockIdx.x * 256 + threadIdx.x) * 4;
  if (i + 3 < n) {
    if (f32) {
      f32x4 v = *(const f32x4*)((const float*)src + i);
#pragma unroll
      for (int j = 0; j < 4; j++) dst[i + j] = f2bf(v[j]);
    } else {
      *(uint2*)(dst + i) = *(const uint2*)((const u16*)src + i);
    }
  }
}

struct P8 { const void* p[8]; };
__global__ __launch_bounds__(256) void cvt_bias(P8 s, u16* __restrict__ dst,
                                                const int* __restrict__ flagp)
{
  const bool f32 = *flagp != 0;
  const int sizes[8] = {2304, 2304, 6912, 6912, 2304, 2304, 768, 768};
  int gid = blockIdx.x * 256 + threadIdx.x;
  int seg = 0, off = gid;
  while (seg < 8 && off >= sizes[seg]) { off -= sizes[seg]; seg++; }
  if (seg >= 8) return;
  float v = f32 ? ((const float*)s.p[seg])[off] : bf2f(((const u16*)s.p[seg])[off]);
  dst[gid] = f2bf(v);
}

// final: out[j*inRows+i] += transposed bf16 tin; out dtype per flag
__global__ __launch_bounds__(256) void transpose_add_out(
    const u16* __restrict__ tin, void* outv, long oOff,
    const int* __restrict__ flagp, int inRows, int inCols)
{
  const bool f32 = *flagp != 0;
  __shared__ u16 tile[32][33];
  const int bx = blockIdx.x * 32;
  const int by = blockIdx.y * 32;
  const int tx = threadIdx.x & 31;
  const int ty = threadIdx.x >> 5;
#pragma unroll
  for (int k = 0; k < 4; k++)
    tile[ty + k * 8][tx] = tin[(long)(by + ty + k * 8) * inCols + bx + tx];
  __syncthreads();
#pragma unroll
  for (int k = 0; k < 4; k++) {
    const int j = bx + ty + k * 8;
    const int i = by + tx;
    const long idx = (long)j * inRows + i;
    const float val = bf2f(tile[tx][ty + k * 8]);
    if (f32) {
      float* o = (float*)outv + oOff;
      o[idx] = o[idx] + val;
    } else {
      u16* o = (u16*)outv + oOff;
      o[idx] = f2bf(bf2f(o[idx]) + val);
    }
  }
}

// ---------------------------------------------------------------------------
extern "C" void kernel_launch(void* const* d_in, const int* in_sizes, int n_in,
                              void* d_out, int out_size, void* d_ws, size_t ws_size,
                              hipStream_t stream)
{
  const int N = 2304, C = 768, HD = 96, HDC = 288;
  const size_t NC = (size_t)N * C;

  const void* x    = d_in[0];
  const void* y    = d_in[1];
  const void* Wqx  = d_in[2];  const void* bqx  = d_in[3];
  const void* Wqy  = d_in[4];  const void* bqy  = d_in[5];
  const void* Wqxc = d_in[6];  const void* bqxc = d_in[7];
  const void* Wqyc = d_in[8];  const void* bqyc = d_in[9];
  const void* Wpxc = d_in[10]; const void* bpxc = d_in[11];
  const void* Wpyc = d_in[12]; const void* bpyc = d_in[13];
  const void* Wax  = d_in[14]; const void* bax  = d_in[15];
  const void* Way  = d_in[16]; const void* bay  = d_in[17];

  char* base = (char*)d_ws;
  int* flag = (int*)base;
  size_t off = 256;
  auto alloc16 = [&](size_t elems) -> u16* {
    u16* p = (u16*)(base + off);
    off = (off + elems * 2 + 255) & ~(size_t)255;
    return p;
  };

  // ---- fat-path fixed layout (all alloc sizes are 256B multiples -> pairs
  // of same-size buffers allocated back-to-back are stride-contiguous, which
  // the Z=2 batched GEMM calls below rely on) ----
  u16* WqxT  = alloc16((size_t)2304 * 768);
  u16* WqyT  = alloc16((size_t)2304 * 768);
  u16* WqxcT = alloc16((size_t)6912 * 2304);
  u16* WqycT = alloc16((size_t)6912 * 2304);
  u16* WpxcT = alloc16((size_t)2304 * 2304);
  u16* WpycT = alloc16((size_t)2304 * 2304);
  u16* WaxT  = alloc16((size_t)768 * 768);
  u16* WayT  = alloc16((size_t)768 * 768);
  u16* biasB = alloc16(24576);
  u16* xb = alloc16(NC);
  u16* yb = alloc16(NC);
  u16* RT = alloc16(2 * NC);      // xt,yt -> attx,atty -> attxc,attyc
  u16* RQ1 = alloc16(3 * NC);     // qkvxs -> qkvxc
  u16* RQ2 = alloc16(3 * NC);     // qkvys -> qkvyc
  u16* RS = alloc16(2 * NC);      // xself, yself
  u16* VT = alloc16(2 * NC);      // transposed V: spatial x/y (flash), channel reuse slot 0
  size_t fixedEnd = off;
  float* Sbuf = (float*)(base + fixedEnd);
  size_t availS = ws_size > fixedEnd ? ws_size - fixedEnd : 0;

  const size_t spHead = (size_t)N * N * 4;
  const bool fat = ws_size >= fixedEnd + spHead;

  auto G64 = [&](const void* A, int lda, long sAz, int aExt,
                 const void* B, int ldb, long sBz, int bNT, int bExt,
                 const void* bias, void* Out, int ldo, long sOz, long oOff, int outMode,
                 float scale, int M, int Nn, int K, int Z) {
    dim3 grid((Nn + BN - 1) / BN, (M + BM - 1) / BM, Z);
    gemm64<<<grid, 256, 0, stream>>>(A, lda, sAz, aExt, B, ldb, sBz, bNT, bExt,
                                     bias, Out, ldo, sOz, oOff, outMode, flag,
                                     scale, M, Nn, K);
  };
  auto G128 = [&](const u16* A, int lda, long sAz,
                  const u16* B, int ldb, long sBz,
                  const u16* bias, int sBiasZ,
                  void* Out, int ldo, long sOz, long oOff, int outMode,
                  float scale, int M, int Nn, int K, int Z) {
    dim3 grid(Nn / 128, M / 128, Z);
    gemm128<<<grid, 256, 0, stream>>>(A, lda, sAz, B, ldb, sBz, bias, sBiasZ,
                                      Out, ldo, sOz, oOff, outMode, flag,
                                      scale, M, Nn, K);
  };

  probe_dtype<<<1, 256, 0, stream>>>((const u32*)x, 1024, flag);

  if (fat) {
    transpose_in<<<dim3(2304 / 32, 768 / 32),  256, 0, stream>>>(Wqx,  WqxT,  flag, 768,  2304);
    transpose_in<<<dim3(2304 / 32, 768 / 32),  256, 0, stream>>>(Wqy,  WqyT,  flag, 768,  2304);
    transpose_in<<<dim3(6912 / 32, 2304 / 32), 256, 0, stream>>>(Wqxc, WqxcT, flag, 2304, 6912);
    transpose_in<<<dim3(6912 / 32, 2304 / 32), 256, 0, stream>>>(Wqyc, WqycT, flag, 2304, 6912);
    transpose_in<<<dim3(2304 / 32, 2304 / 32), 256, 0, stream>>>(Wpxc, WpxcT, flag, 2304, 2304);
    transpose_in<<<dim3(2304 / 32, 2304 / 32), 256, 0, stream>>>(Wpyc, WpycT, flag, 2304, 2304);
    transpose_in<<<dim3(768 / 32, 768 / 32),   256, 0, stream>>>(Wax,  WaxT,  flag, 768,  768);
    transpose_in<<<dim3(768 / 32, 768 / 32),   256, 0, stream>>>(Way,  WayT,  flag, 768,  768);
    P8 bp; bp.p[0] = bqx; bp.p[1] = bqy; bp.p[2] = bqxc; bp.p[3] = bqyc;
    bp.p[4] = bpxc; bp.p[5] = bpyc; bp.p[6] = bax; bp.p[7] = bay;
    cvt_bias<<<96, 256, 0, stream>>>(bp, biasB, flag);
    const u16 *bqxB = biasB, *bqxcB = biasB + 4608,
              *bpxcB = biasB + 18432, *baxB = biasB + 23040;
    cvt_flat<<<(unsigned)(NC / 4 / 256), 256, 0, stream>>>(x, xb, flag, (long)NC);
    cvt_flat<<<(unsigned)(NC / 4 / 256), 256, 0, stream>>>(y, yb, flag, (long)NC);
    u16 *xt = RT, *yt = RT + NC;
    transpose_in<<<dim3(N / 32, C / 32), 256, 0, stream>>>(x, xt, flag, C, N);
    transpose_in<<<dim3(N / 32, C / 32), 256, 0, stream>>>(y, yt, flag, C, N);

    // channel attention: scores gemm128 NT -> softmax -> PV gemm_pv NT
    auto attF = [&](const u16* qB, const u16* kB, const u16* vB, int ldq,
                    u16* att, int Mq, int hd, float scl) {
      // Vt[j, n] = V[n, j]; j over all 8*hd columns, ld = Mq
      transpose_v<<<dim3((8 * hd) / 32, Mq / 32), 256, 0, stream>>>(vB, ldq, VT, Mq, Mq, 8 * hd);
      const long perHead = (long)Mq * Mq * 4;
      int nb = (int)(availS / perHead);
      if (nb > 8) nb = 8;
      for (int h0 = 0; h0 < 8; h0 += nb) {
        const int zc = (8 - h0 < nb) ? 8 - h0 : nb;
        G128(qB + h0 * hd, ldq, hd, kB + h0 * hd, ldq, hd, nullptr, 0,
             Sbuf, Mq, (long)Mq * Mq, 0, 1, scl, Mq, Mq, hd, zc);
        softmax_rows<<<dim3(Mq, zc), 256, 0, stream>>>(Sbuf, Mq, (long)Mq * Mq,
            (u16*)Sbuf, 2 * Mq, (long)Mq * 2 * Mq, Mq);
        gemm_pv<<<dim3(hd / 96, Mq / 64, zc), 256, 0, stream>>>(
            (const u16*)Sbuf, 2 * Mq, (long)Mq * 2 * Mq,
            VT + (long)h0 * hd * Mq, Mq, (long)hd * Mq,
            att + (long)h0 * Mq * hd, hd, (long)Mq * hd, Mq);
      }
    };

    // ---- spatial phase ----
    // x and y batched via Z=2 (A stride NC, W stride NC, bias stride 3C, out stride 3NC)
    u16 *qkvxs = RQ1;
    G128(xt, C, (long)NC, WqxT, C, (long)NC, bqxB, 3 * C,
         qkvxs, 3 * C, 3 * (long)NC, 0, 0, 1.f, N, 3 * C, C, 2);

    // fused spatial attention (x and y in one launch; S never hits memory)
    u16 *qkvys = RQ2;
    u16 *attx = RT;
    const float sscale = 1.0f / sqrtf(96.0f);
    transpose_v<<<dim3((8 * HD) / 32, N / 32), 256, 0, stream>>>(
        qkvxs + 2 * C, 3 * C, VT, N, N, 8 * HD);
    transpose_v<<<dim3((8 * HD) / 32, N / 32), 256, 0, stream>>>(
        qkvys + 2 * C, 3 * C, VT + NC, N, N, 8 * HD);
    flashS<<<dim3(N / 64, 8, 2), 256, 0, stream>>>(
        qkvxs, 3 * (long)NC, VT, (long)NC, attx, (long)NC, 3 * C, N, sscale);

    u16 *xself = RS;
    G128(attx, C, (long)NC, WaxT, C, (long)768 * 768, baxB, C,
         xself, C, (long)NC, 0, 0, 1.f, N, C, C, 2);

    // ---- channel phase ----
    u16 *qkvxc = RQ1, *qkvyc = RQ2;
    G128(xb, N, (long)NC, WqxcT, N, (long)6912 * 2304, bqxcB, 3 * N,
         qkvxc, 3 * N, 3 * (long)NC, 0, 0, 1.f, C, 3 * N, N, 2);

    u16 *attxc = RT, *attyc = RT + NC;
    const float cscale = 1.0f / sqrtf(288.0f);
    attF(qkvxc, qkvyc + N, qkvyc + 2 * N, 3 * N, attxc, C, HDC, cscale);
    attF(qkvyc, qkvxc + N, qkvxc + 2 * N, 3 * N, attyc, C, HDC, cscale);

    G128(attxc, N, (long)NC, WpxcT, N, (long)2304 * 2304, bpxcB, N,
         d_out, N, (long)NC, 0, 2, 1.f, C, N, N, 2);

    transpose_add_out<<<dim3(C / 32, N / 32), 256, 0, stream>>>(xself, d_out, 0, flag, N, C);
    transpose_add_out<<<dim3(C / 32, N / 32), 256, 0, stream>>>(RS + NC, d_out, (long)NC, flag, N, C);
    return;
  }

  // ================= fallback: round-3 verified path =================
  {
    char* b2 = (char*)d_ws;
    u16* RA = (u16*)(b2 + 256);
    u16* RB = RA + 3 * NC;
    u16* RD = RB + 3 * NC;
    u16* RE = RD + 2 * NC;
    const size_t offSsp = 256 + (size_t)(8 * NC) * 2;
    float* Ssp = (float*)(b2 + offSsp);
    const size_t availSp = ws_size > offSsp ? ws_size - offSsp : 0;
    const size_t offSch = 256 + (size_t)(10 * NC) * 2;
    float* Sch = (float*)(b2 + offSch);
    const size_t availCh = ws_size > offSch ? ws_size - offSch : 0;

    u16 *xt = RD, *yt = RD + NC;
    u16 *qkvxs = RA, *qkvys = RB;
    u16 *attx = RD, *atty = RD + NC;
    u16 *xself = RE, *yself = RE + NC;
    u16 *qkvxc = RA, *qkvyc = RB;
    u16 *attxc = RD, *attyc = RD + NC;

    auto attention = [&](const u16* qB, const u16* kB, const u16* vB, int ldq,
                         u16* att, int Mq, int hd, float scl,
                         float* S, size_t availBytes) {
      const long perHead = (long)Mq * Mq * 4;
      int nb = (int)(availBytes / perHead);
      if (nb > 8) nb = 8;
      if (nb >= 1) {
        for (int h0 = 0; h0 < 8; h0 += nb) {
          const int zc = (8 - h0 < nb) ? 8 - h0 : nb;
          G64(qB + h0 * hd, ldq, hd, 0, kB + h0 * hd, ldq, hd, 1, 0, nullptr,
              S, Mq, (long)Mq * Mq, 0, 1, scl, Mq, Mq, hd, zc);
          softmax_rows<<<dim3(Mq, zc), 256, 0, stream>>>(S, Mq, (long)Mq * Mq,
              (u16*)S, 2 * Mq, (long)Mq * 2 * Mq, Mq);
          G64((const u16*)S, 2 * Mq, (long)Mq * 2 * Mq, 0, vB + h0 * hd, ldq, hd, 0, 0,
              nullptr, att + (long)h0 * Mq * hd, hd, (long)Mq * hd, 0, 0,
              1.f, Mq, hd, Mq, zc);
        }
      } else {
        long rows = (long)(availBytes / ((size_t)Mq * 4)) & ~63L;
        if (rows < 64) rows = 64;
        if (rows > Mq) rows = Mq;
        for (int h = 0; h < 8; h++) {
          for (int m0 = 0; m0 < Mq; m0 += (int)rows) {
            const int mr = (Mq - m0 < rows) ? (int)(Mq - m0) : (int)rows;
            G64(qB + (long)m0 * ldq + h * hd, ldq, 0, 0, kB + h * hd, ldq, 0, 1, 0,
                nullptr, S, Mq, 0, 0, 1, scl, mr, Mq, hd, 1);
            softmax_rows<<<dim3(mr, 1), 256, 0, stream>>>(S, Mq, 0, (u16*)S, 2 * Mq, 0, Mq);
            G64((const u16*)S, 2 * Mq, 0, 0, vB + h * hd, ldq, 0, 0, 0, nullptr,
                att + (long)h * Mq * hd + (long)m0 * hd, hd, 0, 0, 0, 1.f, mr, hd, Mq, 1);
          }
        }
      }
    };

    transpose_in<<<dim3(N / 32, C / 32), 256, 0, stream>>>(x, xt, flag, C, N);
    transpose_in<<<dim3(N / 32, C / 32), 256, 0, stream>>>(y, yt, flag, C, N);

    G64(xt, C, 0, 0, Wqx, 3 * C, 0, 0, 1, bqx, qkvxs, 3 * C, 0, 0, 0, 1.f, N, 3 * C, C, 1);
    G64(yt, C, 0, 0, Wqy, 3 * C, 0, 0, 1, bqy, qkvys, 3 * C, 0, 0, 0, 1.f, N, 3 * C, C, 1);

    const float sscale = 1.0f / sqrtf(96.0f);
    attention(qkvxs, qkvxs + C, qkvxs + 2 * C, 3 * C, attx, N, HD, sscale, Ssp, availSp);
    attention(qkvys, qkvys + C, qkvys + 2 * C, 3 * C, atty, N, HD, sscale, Ssp, availSp);

    G64(attx, C, 0, 0, Wax, C, 0, 0, 1, bax, xself, C, 0, 0, 0, 1.f, N, C, C, 1);
    G64(atty, C, 0, 0, Way, C, 0, 0, 1, bay, yself, C, 0, 0, 0, 1.f, N, C, C, 1);

    G64(x, N, 0, 1, Wqxc, 3 * N, 0, 0, 1, bqxc, qkvxc, 3 * N, 0, 0, 0, 1.f, C, 3 * N, N, 1);
    G64(y, N, 0, 1, Wqyc, 3 * N, 0, 0, 1, bqyc, qkvyc, 3 * N, 0, 0, 0, 1.f, C, 3 * N, N, 1);

    const float cscale = 1.0f / sqrtf(288.0f);
    attention(qkvxc, qkvyc + N, qkvyc + 2 * N, 3 * N, attxc, C, HDC, cscale, Sch, availCh);
    attention(qkvyc, qkvxc + N, qkvxc + 2 * N, 3 * N, attyc, C, HDC, cscale, Sch, availCh);

    G64(attxc, N, 0, 0, Wpxc, N, 0, 0, 1, bpxc, d_out, N, 0, 0, 2, 1.f, C, N, N, 1);
    G64(attyc, N, 0, 0, Wpyc, N, 0, 0, 1, bpyc, d_out, N, 0, (long)NC, 2, 1.f, C, N, N, 1);

    transpose_add_out<<<dim3(C / 32, N / 32), 256, 0, stream>>>(xself, d_out, 0, flag, N, C);
    transpose_add_out<<<dim3(C / 32, N / 32), 256, 0, stream>>>(yself, d_out, (long)NC, flag, N, C);
  }
}